// Round 6
// baseline (315.830 us; speedup 1.0000x reference)
//
#include <hip/hip_runtime.h>
#include <hip/hip_bf16.h>
#include <math.h>

// ---------------------------------------------------------------------------
// GPT block on MI355X (gfx950). bf16 MFMA compute, fp32 accumulate.
// Workspace layout (MB = 1<<20), total 72 MB:
//   [ 0, 6)  WtQKV  bf16 [3072][1024]  (W_Q,W_K,W_V transposed, contiguous)
//   [ 6, 8)  WtO    bf16 [1024][1024]
//   [ 8,16)  Wtfc   bf16 [4096][1024]
//   [16,24)  Wtproj bf16 [1024][4096]
//   [24,32)  zn / ctx   bf16 [4096][1024]
//   [32,40)  Q / h      bf16 [4096][1024]
//   [40,48)  K          bf16 [4096][1024]
//   [48,56)  Vt         bf16 [32][64][2048]  (V transposed, kv-permuted)
//   [40,72)  ffn1       bf16 [4096][4096]  (overlaps K,Vt — dead after attn)
// d_out doubles as z2 (fp32): O-proj writes z2 = z + attn; proj does +=.
// Pipelines (GEMM + attn): 3 LDS buffers, 2-deep global_load_lds prefetch,
// raw s_barrier + COUNTED vmcnt (T4: never drain in-loop), T2 XOR swizzle,
// T1 XCD remap, T5 setprio around MFMA clusters.
// ---------------------------------------------------------------------------

typedef __bf16 bf16x8 __attribute__((ext_vector_type(8)));
typedef float  f32x4  __attribute__((ext_vector_type(4)));

#define MFMA_16x16x32_BF16(A, B, C) __builtin_amdgcn_mfma_f32_16x16x32_bf16((A), (B), (C), 0, 0, 0)

#define GLDS16(g, l) __builtin_amdgcn_global_load_lds( \
    (const __attribute__((address_space(1))) void*)(g), \
    (__attribute__((address_space(3))) void*)(l), 16, 0, 0)

// ---------------- fused transpose + fp32->bf16 convert for all 6 weights ----
__global__ __launch_bounds__(256) void transconv_all_kernel(
    const float* __restrict__ W_Q, const float* __restrict__ W_K,
    const float* __restrict__ W_V, const float* __restrict__ W_O,
    const float* __restrict__ W_fc, const float* __restrict__ W_proj,
    __bf16* __restrict__ WtQKV, __bf16* __restrict__ WtO,
    __bf16* __restrict__ Wtfc, __bf16* __restrict__ Wtproj)
{
    const int id = blockIdx.x;
    const float* src;
    __bf16* dst;
    int K, N, nx, t;
    if (id < 4096) {
        const int wsel = id >> 10;
        t = id & 1023;
        src = (wsel == 0) ? W_Q : (wsel == 1) ? W_K : (wsel == 2) ? W_V : W_O;
        dst = (wsel < 3) ? (WtQKV + (size_t)wsel * 1048576) : WtO;
        K = 1024; N = 1024; nx = 32;
    } else if (id < 8192) {
        t = id - 4096; src = W_fc; dst = Wtfc; K = 1024; N = 4096; nx = 128;
    } else {
        t = id - 8192; src = W_proj; dst = Wtproj; K = 4096; N = 1024; nx = 32;
    }
    const int n0 = (t % nx) * 32, k0 = (t / nx) * 32;

    __shared__ float tile[32][33];
    const int c = threadIdx.x & 31, r = threadIdx.x >> 5;
#pragma unroll
    for (int i = 0; i < 4; ++i)
        tile[r + 8 * i][c] = src[(size_t)(k0 + r + 8 * i) * N + n0 + c];
    __syncthreads();
#pragma unroll
    for (int i = 0; i < 4; ++i)
        dst[(size_t)(n0 + r + 8 * i) * K + k0 + c] = (__bf16)tile[c][r + 8 * i];
}

// ---------------- RMSNorm: fp32 [M][1024] -> bf16 [M][1024] -----------------
__global__ __launch_bounds__(256) void rmsnorm_kernel(
    const float* __restrict__ x, const float* __restrict__ gain,
    __bf16* __restrict__ out)
{
    const int row = blockIdx.x, t = threadIdx.x;
    const float4 v = ((const float4*)(x + (size_t)row * 1024))[t];
    float ss = v.x * v.x + v.y * v.y + v.z * v.z + v.w * v.w;
#pragma unroll
    for (int m = 1; m < 64; m <<= 1) ss += __shfl_xor(ss, m);
    __shared__ float red[4];
    const int wid = t >> 6, lane = t & 63;
    if (lane == 0) red[wid] = ss;
    __syncthreads();
    const float tot = red[0] + red[1] + red[2] + red[3];
    const float inv = rsqrtf(tot * (1.0f / 1024.0f) + 1e-5f);
    const float4 gv = ((const float4*)gain)[t];
    __bf16* o = out + (size_t)row * 1024 + t * 4;
    o[0] = (__bf16)(v.x * inv * gv.x);
    o[1] = (__bf16)(v.y * inv * gv.y);
    o[2] = (__bf16)(v.z * inv * gv.z);
    o[3] = (__bf16)(v.w * inv * gv.w);
}

// ---------------- GEMM: C[M][N] = A[M][K] * Bt[N][K]^T, bf16 MFMA ----------
// 3-buf 2-deep pipeline: [vmcnt(L); s_barrier; STAGE(t+2); ds_read(t); MFMA].
// EPI: 1 = out_f32 = res + acc; 2 = store bf16 gelu_erf(acc); 3 = out_f32 += acc
// EPI: 4 = fused QKV split: outp = Q base; K at +4M elems; Vt at +8M elems
template <int BM, int BN, int EPI>
__global__ __launch_bounds__(256) void gemm_bf16(
    const __bf16* __restrict__ A, const __bf16* __restrict__ Bt,
    void* __restrict__ outp, const float* __restrict__ res,
    int M, int N, int K)
{
    __shared__ __bf16 As[3][BM * 64];
    __shared__ __bf16 Bs[3][BN * 64];
    const int tid = threadIdx.x;

    // T1: bijective XCD-contiguous remap (all launches have nwg % 8 == 0)
    const int gx = gridDim.x, nwg = gx * gridDim.y;
    int bid = blockIdx.y * gx + blockIdx.x;
    if ((nwg & 7) == 0) bid = (bid & 7) * (nwg >> 3) + (bid >> 3);
    const int m0 = (bid / gx) * BM, n0 = (bid % gx) * BN;

    const int lane = tid & 63, w = tid >> 6;
    const int wm = w >> 1, wn = w & 1;
    const int lr = lane & 15, g = lane >> 4;
    const int srow = lane >> 3;                       // staging row-in-8
    const int scol = ((lane & 7) ^ srow) * 8;         // pre-swizzled source chunk
    const int xr8 = lr & 7;                           // read-side chunk XOR

    constexpr int MI = BM / 32, NI = BN / 32;
    constexpr int LCNT = BM / 32 + BN / 32;           // gload_lds instrs/STAGE
    f32x4 acc[MI][NI] = {};

    const __bf16* Abase = A + (size_t)m0 * K;
    const __bf16* Bbase = Bt + (size_t)n0 * K;

    auto STAGE = [&](int t) {
        const int buf = t % 3;
        const int kb = t << 6;
#pragma unroll
        for (int j = 0; j < BM / 32; ++j) {
            const int s = j * 4 + w;
            GLDS16(Abase + (size_t)(s * 8 + srow) * K + kb + scol, &As[buf][s * 512]);
        }
#pragma unroll
        for (int j = 0; j < BN / 32; ++j) {
            const int s = j * 4 + w;
            GLDS16(Bbase + (size_t)(s * 8 + srow) * K + kb + scol, &Bs[buf][s * 512]);
        }
    };

    const int nt = K >> 6;
    STAGE(0);
    if (nt > 1) STAGE(1);

    for (int t = 0; t < nt; ++t) {
        // wait for tile t's loads (allow tile t+1's LCNT to stay in flight)
        if (t + 1 < nt) asm volatile("s_waitcnt vmcnt(%0)" :: "i"(LCNT) : "memory");
        else            asm volatile("s_waitcnt vmcnt(0)" ::: "memory");
        __builtin_amdgcn_s_barrier();
        asm volatile("" ::: "memory");
        if (t + 2 < nt) STAGE(t + 2);

        const int cur = t % 3;
        bf16x8 af[2][MI], bfr[2][NI];
#pragma unroll
        for (int kk = 0; kk < 2; ++kk) {
#pragma unroll
            for (int i = 0; i < MI; ++i)
                af[kk][i] = *(const bf16x8*)
                    &As[cur][(wm * (BM / 2) + i * 16 + lr) * 64 + (((kk * 4 + g) ^ xr8) << 3)];
#pragma unroll
            for (int i = 0; i < NI; ++i)
                bfr[kk][i] = *(const bf16x8*)
                    &Bs[cur][(wn * (BN / 2) + i * 16 + lr) * 64 + (((kk * 4 + g) ^ xr8) << 3)];
        }
        __builtin_amdgcn_s_setprio(1);
#pragma unroll
        for (int kk = 0; kk < 2; ++kk)
#pragma unroll
            for (int mi = 0; mi < MI; ++mi)
#pragma unroll
                for (int ni = 0; ni < NI; ++ni)
                    acc[mi][ni] = MFMA_16x16x32_BF16(af[kk][mi], bfr[kk][ni], acc[mi][ni]);
        __builtin_amdgcn_s_setprio(0);
    }

#pragma unroll
    for (int mi = 0; mi < MI; ++mi)
#pragma unroll
        for (int ni = 0; ni < NI; ++ni) {
            const int colg = n0 + wn * (BN / 2) + ni * 16 + lr;
#pragma unroll
            for (int r = 0; r < 4; ++r) {
                const int rowg = m0 + wm * (BM / 2) + mi * 16 + 4 * g + r;
                const float v = acc[mi][ni][r];
                if constexpr (EPI == 1) {
                    const size_t idx = (size_t)rowg * N + colg;
                    ((float*)outp)[idx] = res[idx] + v;
                } else if constexpr (EPI == 2) {
                    const size_t idx = (size_t)rowg * N + colg;
                    ((__bf16*)outp)[idx] =
                        (__bf16)(0.5f * v * (1.0f + erff(v * 0.70710678118654752f)));
                } else if constexpr (EPI == 3) {
                    const size_t idx = (size_t)rowg * N + colg;
                    ((float*)outp)[idx] += v;
                } else {  // EPI == 4: QKV split
                    __bf16* base = (__bf16*)outp;
                    const int seg = colg >> 10;       // 0=Q, 1=K, 2=V
                    const int cg = colg & 1023;
                    if (seg < 2) {
                        base[(size_t)seg * 4194304 + (size_t)rowg * 1024 + cg] = (__bf16)v;
                    } else {
                        // Vt[b][h][d][t'] with within-32 t-permutation:
                        // t = 16h+4g+j (mod 32) stored at 8g+4h+j
                        const int tt = rowg & 2047;
                        const int r32 = tt & 31;
                        const int p = ((r32 & 12) << 1) | ((r32 >> 2) & 4) | (r32 & 3);
                        base[8388608 +
                             ((size_t)((rowg >> 11) * 16 + (cg >> 6)) * 64 + (cg & 63)) * 2048 +
                             ((tt & ~31) | p)] = (__bf16)v;
                    }
                }
            }
        }
}

// ---------------- Flash-style causal attention (3-buf pipelined) ------------
// Grid: blockIdx.x = qc*32 + bh. 4 waves, 16 q-rows each. KV steps of 64.
// Softmax in exp2 domain (0.125*log2e folded into Q pre-scale).
__global__ __launch_bounds__(256) void attn_kernel(
    const __bf16* __restrict__ Q, const __bf16* __restrict__ Kb,
    const __bf16* __restrict__ Vt, __bf16* __restrict__ ctx)
{
    const int Dm = 1024, T = 2048;
    const int tid = threadIdx.x;
    const int w = tid >> 6, lane = tid & 63;
    const int lr = lane & 15, g = lane >> 4;
    const int bx = blockIdx.x;
    const int qc = bx >> 5, bh = bx & 31, b = bh >> 4, h = bh & 15;
    const int qbase = qc * 64 + w * 16;
    const size_t rowoff = (size_t)b * T;
    const __bf16* Qp = Q + rowoff * Dm + h * 64;
    const __bf16* Kp = Kb + rowoff * Dm + h * 64;        // row t, stride 1024
    const __bf16* Vtp = Vt + (size_t)bh * 64 * 2048;     // row d, stride 2048

    __shared__ __bf16 Ks[3][64 * 64];
    __shared__ __bf16 Vs[3][64 * 64];

    // Q fragments pre-scaled by 0.125 * log2(e)  (scores land in log2 units)
    bf16x8 qf0 = *(const bf16x8*)&Qp[(size_t)(qbase + lr) * Dm + g * 8];
    bf16x8 qf1 = *(const bf16x8*)&Qp[(size_t)(qbase + lr) * Dm + 32 + g * 8];
    const float qsc = 0.125f * 1.44269504088896340736f;
#pragma unroll
    for (int j = 0; j < 8; ++j) {
        qf0[j] = (__bf16)((float)qf0[j] * qsc);
        qf1[j] = (__bf16)((float)qf1[j] * qsc);
    }

    const int srow = lane >> 3;
    const int schunk = (lane & 7) ^ srow;

    auto STAGE = [&](int t) {
        const int buf = t % 3;
        const int kb = t << 6;
#pragma unroll
        for (int j = 0; j < 2; ++j) {
            const int row = j * 32 + w * 8 + srow;
            GLDS16(Kp + (size_t)(kb + row) * Dm + schunk * 8, &Ks[buf][(j * 32 + w * 8) * 64]);
            GLDS16(Vtp + (size_t)row * T + kb + schunk * 8, &Vs[buf][(j * 32 + w * 8) * 64]);
        }
    };

    f32x4 acc[4] = {};
    float m_s = -__builtin_inff(), l_s = 0.0f;
    const int nsteps = qc + 1;
    const f32x4 zacc = {0.0f, 0.0f, 0.0f, 0.0f};
    const int xr = (lr & 7) << 3;
    const int qg = qbase + lr;

    STAGE(0);
    if (nsteps > 1) STAGE(1);

    for (int t = 0; t < nsteps; ++t) {
        if (t + 1 < nsteps) asm volatile("s_waitcnt vmcnt(4)" ::: "memory");
        else                asm volatile("s_waitcnt vmcnt(0)" ::: "memory");
        __builtin_amdgcn_s_barrier();
        asm volatile("" ::: "memory");
        if (t + 2 < nsteps) STAGE(t + 2);

        const int kvb = t * 64, cur = t % 3;

        // ---- QK^T: four 16-kv sub-tiles (Q pre-scaled, log2 domain) ----
        float sv[4][4];
#pragma unroll
        for (int s4 = 0; s4 < 4; ++s4) {
            const int kv0 = kvb + s4 * 16;
            if (kv0 <= qbase + 15) {
                const int row = s4 * 16 + lr;
                const bf16x8 kfa = *(const bf16x8*)&Ks[cur][row * 64 + ((g * 8) ^ xr)];
                const bf16x8 kfb = *(const bf16x8*)&Ks[cur][row * 64 + ((32 + g * 8) ^ xr)];
                __builtin_amdgcn_s_setprio(1);
                f32x4 st = MFMA_16x16x32_BF16(kfa, qf0, zacc);
                st = MFMA_16x16x32_BF16(kfb, qf1, st);
                __builtin_amdgcn_s_setprio(0);
                const bool domask = (kv0 + 15 > qbase);
#pragma unroll
                for (int r = 0; r < 4; ++r) {
                    float x = st[r];
                    if (domask && (kv0 + 4 * g + r > qg)) x = -__builtin_inff();
                    sv[s4][r] = x;
                }
            } else {
#pragma unroll
                for (int r = 0; r < 4; ++r) sv[s4][r] = -__builtin_inff();
            }
        }

        // ---- online softmax (log2 domain) with defer-rescale (THR ~ e^8) ----
        float tm = sv[0][0];
#pragma unroll
        for (int s4 = 0; s4 < 4; ++s4)
#pragma unroll
            for (int r = 0; r < 4; ++r) tm = fmaxf(tm, sv[s4][r]);
        tm = fmaxf(tm, __shfl_xor(tm, 16));
        tm = fmaxf(tm, __shfl_xor(tm, 32));

        float m_use = m_s;
        if (!__all(tm - m_s <= 11.5f)) {
            m_use = fmaxf(m_s, tm);
            const float corr = exp2f(m_s - m_use);
            l_s *= corr;
            float cr[4];
#pragma unroll
            for (int r = 0; r < 4; ++r) cr[r] = __shfl(corr, 4 * g + r);
#pragma unroll
            for (int ct = 0; ct < 4; ++ct) {
                acc[ct][0] *= cr[0]; acc[ct][1] *= cr[1];
                acc[ct][2] *= cr[2]; acc[ct][3] *= cr[3];
            }
            m_s = m_use;
        }

        float rs = 0.0f;
#pragma unroll
        for (int s4 = 0; s4 < 4; ++s4)
#pragma unroll
            for (int r = 0; r < 4; ++r) {
                sv[s4][r] = exp2f(sv[s4][r] - m_use);
                rs += sv[s4][r];
            }
        rs += __shfl_xor(rs, 16);
        rs += __shfl_xor(rs, 32);
        l_s += rs;

        // ---- PV: single 16B V fragments (kv-permuted Vt layout) ----
        bf16x8 pa0, pa1;
#pragma unroll
        for (int r = 0; r < 4; ++r) {
            pa0[r] = (__bf16)sv[0][r];
            pa0[4 + r] = (__bf16)sv[1][r];
            pa1[r] = (__bf16)sv[2][r];
            pa1[4 + r] = (__bf16)sv[3][r];
        }
        const bool liveB = (kvb + 32 <= qbase + 15);
        __builtin_amdgcn_s_setprio(1);
#pragma unroll
        for (int ct = 0; ct < 4; ++ct) {
            const __bf16* vrow = &Vs[cur][(ct * 16 + lr) * 64];
            const bf16x8 vf = *(const bf16x8*)&vrow[(8 * g) ^ xr];
            acc[ct] = MFMA_16x16x32_BF16(pa0, vf, acc[ct]);
            if (liveB) {
                const bf16x8 vf2 = *(const bf16x8*)&vrow[(32 + 8 * g) ^ xr];
                acc[ct] = MFMA_16x16x32_BF16(pa1, vf2, acc[ct]);
            }
        }
        __builtin_amdgcn_s_setprio(0);
    }

    const float il = __builtin_amdgcn_rcpf(l_s);
    float dn[4];
#pragma unroll
    for (int r = 0; r < 4; ++r) dn[r] = __shfl(il, 4 * g + r);
#pragma unroll
    for (int ct = 0; ct < 4; ++ct)
#pragma unroll
        for (int r = 0; r < 4; ++r)
            ctx[(rowoff + qbase + 4 * g + r) * Dm + h * 64 + ct * 16 + lr] =
                (__bf16)(acc[ct][r] * dn[r]);
}

// ---------------------------------------------------------------------------
extern "C" void kernel_launch(void* const* d_in, const int* in_sizes, int n_in,
                              void* d_out, int out_size, void* d_ws, size_t ws_size,
                              hipStream_t stream)
{
    (void)in_sizes; (void)n_in; (void)out_size; (void)ws_size;
    const float* z      = (const float*)d_in[0];
    const float* W_Q    = (const float*)d_in[1];
    const float* W_K    = (const float*)d_in[2];
    const float* W_V    = (const float*)d_in[3];
    const float* W_O    = (const float*)d_in[4];
    const float* W_fc   = (const float*)d_in[5];
    const float* W_proj = (const float*)d_in[6];
    const float* g1     = (const float*)d_in[7];
    const float* g2     = (const float*)d_in[8];
    float* out = (float*)d_out;

    char* ws = (char*)d_ws;
    const size_t MB = (size_t)1 << 20;
    __bf16* WtQKV  = (__bf16*)(ws + 0 * MB);   // [3072][1024]
    __bf16* WtO    = (__bf16*)(ws + 6 * MB);
    __bf16* Wtfc   = (__bf16*)(ws + 8 * MB);
    __bf16* Wtproj = (__bf16*)(ws + 16 * MB);
    __bf16* zn     = (__bf16*)(ws + 24 * MB);  // reused as ctx
    __bf16* Qb     = (__bf16*)(ws + 32 * MB);  // QKV out base; reused as h
    __bf16* Kbuf   = (__bf16*)(ws + 40 * MB);
    __bf16* Vtb    = (__bf16*)(ws + 48 * MB);
    __bf16* ffn1   = (__bf16*)(ws + 40 * MB);  // overlaps K,Vt (dead post-attn)
    __bf16* ctx    = zn;
    __bf16* hb     = Qb;

    const int Tt = 2048, Dm = 1024, Bb = 2, M = Bb * Tt, DFF = 4096;
    const dim3 blk256(256);

    // All weight transposes+converts in one launch
    transconv_all_kernel<<<12288, blk256, 0, stream>>>(
        W_Q, W_K, W_V, W_O, W_fc, W_proj, WtQKV, WtO, Wtfc, Wtproj);

    // zn = rmsnorm(z, g1)
    rmsnorm_kernel<<<M, blk256, 0, stream>>>(z, g1, zn);

    // Fused QKV: [4096][3072]; epilogue splits Q, K, and permuted-transposed Vt
    gemm_bf16<128, 64, 4><<<dim3(48, 32), blk256, 0, stream>>>(
        zn, WtQKV, Qb, nullptr, M, 3072, Dm);

    // attention -> ctx
    attn_kernel<<<1024, blk256, 0, stream>>>(Qb, Kbuf, Vtb, ctx);

    // z2 = z + ctx @ W_O  -> d_out (fp32)
    gemm_bf16<128, 64, 1><<<dim3(16, 32), blk256, 0, stream>>>(
        ctx, WtO, out, z, M, Dm, Dm);

    // h = rmsnorm(z2, g2)
    rmsnorm_kernel<<<M, blk256, 0, stream>>>(out, g2, hb);

    // ffn1 = gelu_erf(h @ W_fc)
    gemm_bf16<128, 64, 2><<<dim3(64, 32), blk256, 0, stream>>>(
        hb, Wtfc, ffn1, nullptr, M, DFF, Dm);

    // d_out += ffn1 @ W_proj
    gemm_bf16<128, 64, 3><<<dim3(16, 32), blk256, 0, stream>>>(
        ffn1, Wtproj, out, nullptr, M, Dm, DFF);
}

// Round 7
// 290.558 us; speedup vs baseline: 1.0870x; 1.0870x over previous
//
#include <hip/hip_runtime.h>
#include <hip/hip_bf16.h>
#include <math.h>

// ---------------------------------------------------------------------------
// GPT block on MI355X (gfx950). bf16 MFMA compute, fp32 accumulate.
// Workspace layout (MB = 1<<20), total 72 MB:
//   [ 0, 6)  WtQKV  bf16 [3072][1024]  (W_Q,W_K,W_V transposed, contiguous)
//   [ 6, 8)  WtO    bf16 [1024][1024]
//   [ 8,16)  Wtfc   bf16 [4096][1024]
//   [16,24)  Wtproj bf16 [1024][4096]
//   [24,32)  zn / ctx   bf16 [4096][1024]
//   [32,40)  Q / h      bf16 [4096][1024]
//   [40,48)  K          bf16 [4096][1024]
//   [48,56)  Vt         bf16 [32][64][2048]  (V transposed, kv-permuted)
//   [40,72)  ffn1       bf16 [4096][4096]  (overlaps K,Vt — dead after attn)
// d_out doubles as z2 (fp32): O-proj writes z2 = z + attn; proj does +=.
// QKV and fc use the 8-phase 256^2 template (T2+T3+T4+T5): 8 waves, 128KB
// LDS, 1 half-tile staged per phase, counted vmcnt(6) at p0/p4 only.
// O-proj / proj use the 2-phase 128x64 dbuf GEMM (best small-N config).
// ---------------------------------------------------------------------------

typedef __bf16 bf16x8 __attribute__((ext_vector_type(8)));
typedef float  f32x4  __attribute__((ext_vector_type(4)));

#define MFMA_16x16x32_BF16(A, B, C) __builtin_amdgcn_mfma_f32_16x16x32_bf16((A), (B), (C), 0, 0, 0)

#define GLDS16(g, l) __builtin_amdgcn_global_load_lds( \
    (const __attribute__((address_space(1))) void*)(g), \
    (__attribute__((address_space(3))) void*)(l), 16, 0, 0)

// ---------------- fused transpose + fp32->bf16 convert for all 6 weights ----
__global__ __launch_bounds__(256) void transconv_all_kernel(
    const float* __restrict__ W_Q, const float* __restrict__ W_K,
    const float* __restrict__ W_V, const float* __restrict__ W_O,
    const float* __restrict__ W_fc, const float* __restrict__ W_proj,
    __bf16* __restrict__ WtQKV, __bf16* __restrict__ WtO,
    __bf16* __restrict__ Wtfc, __bf16* __restrict__ Wtproj)
{
    const int id = blockIdx.x;
    const float* src;
    __bf16* dst;
    int K, N, nx, t;
    if (id < 4096) {
        const int wsel = id >> 10;
        t = id & 1023;
        src = (wsel == 0) ? W_Q : (wsel == 1) ? W_K : (wsel == 2) ? W_V : W_O;
        dst = (wsel < 3) ? (WtQKV + (size_t)wsel * 1048576) : WtO;
        K = 1024; N = 1024; nx = 32;
    } else if (id < 8192) {
        t = id - 4096; src = W_fc; dst = Wtfc; K = 1024; N = 4096; nx = 128;
    } else {
        t = id - 8192; src = W_proj; dst = Wtproj; K = 4096; N = 1024; nx = 32;
    }
    const int n0 = (t % nx) * 32, k0 = (t / nx) * 32;

    __shared__ float tile[32][33];
    const int c = threadIdx.x & 31, r = threadIdx.x >> 5;
#pragma unroll
    for (int i = 0; i < 4; ++i)
        tile[r + 8 * i][c] = src[(size_t)(k0 + r + 8 * i) * N + n0 + c];
    __syncthreads();
#pragma unroll
    for (int i = 0; i < 4; ++i)
        dst[(size_t)(n0 + r + 8 * i) * K + k0 + c] = (__bf16)tile[c][r + 8 * i];
}

// ---------------- RMSNorm: fp32 [M][1024] -> bf16 [M][1024] -----------------
__global__ __launch_bounds__(256) void rmsnorm_kernel(
    const float* __restrict__ x, const float* __restrict__ gain,
    __bf16* __restrict__ out)
{
    const int row = blockIdx.x, t = threadIdx.x;
    const float4 v = ((const float4*)(x + (size_t)row * 1024))[t];
    float ss = v.x * v.x + v.y * v.y + v.z * v.z + v.w * v.w;
#pragma unroll
    for (int m = 1; m < 64; m <<= 1) ss += __shfl_xor(ss, m);
    __shared__ float red[4];
    const int wid = t >> 6, lane = t & 63;
    if (lane == 0) red[wid] = ss;
    __syncthreads();
    const float tot = red[0] + red[1] + red[2] + red[3];
    const float inv = rsqrtf(tot * (1.0f / 1024.0f) + 1e-5f);
    const float4 gv = ((const float4*)gain)[t];
    __bf16* o = out + (size_t)row * 1024 + t * 4;
    o[0] = (__bf16)(v.x * inv * gv.x);
    o[1] = (__bf16)(v.y * inv * gv.y);
    o[2] = (__bf16)(v.z * inv * gv.z);
    o[3] = (__bf16)(v.w * inv * gv.w);
}

// ---------------- C-write helper (shared by both GEMM kernels) --------------
template <int EPI>
__device__ __forceinline__ void epi_write(
    void* outp, const float* res, int N, int rowg, int colg, float v)
{
    if constexpr (EPI == 1) {
        const size_t idx = (size_t)rowg * N + colg;
        ((float*)outp)[idx] = res[idx] + v;
    } else if constexpr (EPI == 2) {
        const size_t idx = (size_t)rowg * N + colg;
        ((__bf16*)outp)[idx] =
            (__bf16)(0.5f * v * (1.0f + erff(v * 0.70710678118654752f)));
    } else if constexpr (EPI == 3) {
        const size_t idx = (size_t)rowg * N + colg;
        ((float*)outp)[idx] += v;
    } else {  // EPI == 4: QKV split
        __bf16* base = (__bf16*)outp;
        const int seg = colg >> 10;       // 0=Q, 1=K, 2=V
        const int cg = colg & 1023;
        if (seg < 2) {
            base[(size_t)seg * 4194304 + (size_t)rowg * 1024 + cg] = (__bf16)v;
        } else {
            // Vt[b][h][d][t'] with within-32 t-permutation: 16h+4g+j -> 8g+4h+j
            const int tt = rowg & 2047;
            const int r32 = tt & 31;
            const int p = ((r32 & 12) << 1) | ((r32 >> 2) & 4) | (r32 & 3);
            base[8388608 +
                 ((size_t)((rowg >> 11) * 16 + (cg >> 6)) * 64 + (cg & 63)) * 2048 +
                 ((tt & ~31) | p)] = (__bf16)v;
        }
    }
}

// ---------------- 8-phase 256x256 GEMM (m201 template, plain HIP) -----------
// C[M][N] = A[M][K] * Bt[N][K]^T. 512 threads = 8 waves (2M x 4N), BK=64,
// 2 K-tiles per iteration, 8 phases, 1 half-tile (128x64) staged per phase,
// vmcnt(6) at p0/p4 (3 half-tiles in flight), peeled last iteration.
// Requires M%256==0, N%256==0, K%128==0, K>=256, grid nwg%8==0.
template <int EPI>
__global__ __launch_bounds__(512, 2) void gemm256(
    const __bf16* __restrict__ A, const __bf16* __restrict__ Bt,
    void* __restrict__ outp, const float* __restrict__ res,
    int M, int N, int K)
{
    __shared__ __bf16 As[2][2][128 * 64];   // [dbuf][half][row*64+elem]
    __shared__ __bf16 Bs[2][2][128 * 64];
    const int tid = threadIdx.x;

    const int gx = gridDim.x, nwg = gx * gridDim.y;
    int bid = blockIdx.y * gx + blockIdx.x;
    if ((nwg & 7) == 0) bid = (bid & 7) * (nwg >> 3) + (bid >> 3);
    const int m0 = (bid / gx) * 256, n0 = (bid % gx) * 256;

    const int lane = tid & 63, w = tid >> 6;         // 8 waves
    const int wr = w >> 2, wc = w & 3;               // 2 x 4 wave grid
    const int lr = lane & 15, g = lane >> 4;
    const int srow8 = lane >> 3, schunk = (lane & 7) ^ srow8;
    const int xk = lr & 7;
    const int wch = wc >> 1, bro = (wc & 1) * 64;    // B half / row offset

    const __bf16* Ab = A + (size_t)m0 * K;
    const __bf16* Bb = Bt + (size_t)n0 * K;

    // stage one half-tile (128 rows x 64 k): source chunk pre-swizzled by row&7
    auto STG = [&](const __bf16* gb, __bf16* lds, int kt, int half) {
        const __bf16* src = gb + (size_t)(half * 128) * K + (kt << 6);
#pragma unroll
        for (int j = 0; j < 2; ++j) {
            const int sidx = j * 8 + w;
            GLDS16(src + (size_t)(sidx * 8 + srow8) * K + schunk * 8, lds + sidx * 512);
        }
    };

    f32x4 acc[8][4] = {};
    bf16x8 af[2][4], bf[2][4];

#define LAF(BUF, QM) do {                                                       \
    _Pragma("unroll") for (int i_ = 0; i_ < 4; ++i_)                            \
    _Pragma("unroll") for (int kk_ = 0; kk_ < 2; ++kk_)                         \
        af[kk_][i_] = *(const bf16x8*)&As[BUF][wr]                              \
            [((QM) * 64 + i_ * 16 + lr) * 64 + (((kk_ * 4 + g) ^ xk) << 3)];    \
    } while (0)

#define LBF(BUF, QN) do {                                                       \
    _Pragma("unroll") for (int i_ = 0; i_ < 2; ++i_)                            \
    _Pragma("unroll") for (int kk_ = 0; kk_ < 2; ++kk_)                         \
        bf[kk_][(QN) * 2 + i_] = *(const bf16x8*)&Bs[BUF][wch]                  \
            [(bro + ((QN) * 2 + i_) * 16 + lr) * 64 + (((kk_ * 4 + g) ^ xk) << 3)]; \
    } while (0)

#define MMQ(QM, QN) do {                                                        \
    __builtin_amdgcn_s_setprio(1);                                              \
    _Pragma("unroll") for (int kk_ = 0; kk_ < 2; ++kk_)                         \
    _Pragma("unroll") for (int i_ = 0; i_ < 4; ++i_)                            \
    _Pragma("unroll") for (int n_ = 0; n_ < 2; ++n_)                            \
        acc[(QM) * 4 + i_][(QN) * 2 + n_] = MFMA_16x16x32_BF16(                 \
            af[kk_][i_], bf[kk_][(QN) * 2 + n_], acc[(QM) * 4 + i_][(QN) * 2 + n_]); \
    __builtin_amdgcn_s_setprio(0);                                              \
    } while (0)

#define BAR()  __builtin_amdgcn_s_barrier()
#define VMC(N_) asm volatile("s_waitcnt vmcnt(" #N_ ")" ::: "memory")
#define SGB0() __builtin_amdgcn_sched_barrier(0)

    const int nt = K >> 6, niter = nt >> 1;

    // prologue: tile0 fully + B halves of tile1
    STG(Ab, &As[0][0][0], 0, 0); STG(Ab, &As[0][1][0], 0, 1);
    STG(Bb, &Bs[0][0][0], 0, 0); STG(Bb, &Bs[0][1][0], 0, 1);
    STG(Bb, &Bs[1][0][0], 1, 0); STG(Bb, &Bs[1][1][0], 1, 1);

    for (int i = 0; i < niter - 1; ++i) {
        const int t1 = 2 * i + 1;
        // p0: reads tile 2i (buf0) quad(0,0); stages A0(2i+1)
        STG(Ab, &As[1][0][0], t1, 0);
        VMC(6); BAR(); SGB0();
        LAF(0, 0); LBF(0, 0); MMQ(0, 0); BAR();
        // p1
        LBF(0, 1); STG(Ab, &As[1][1][0], t1, 1); BAR(); MMQ(0, 1); BAR();
        // p2
        LAF(0, 1); STG(Bb, &Bs[0][0][0], t1 + 1, 0); BAR(); MMQ(1, 0); BAR();
        // p3
        STG(Bb, &Bs[0][1][0], t1 + 1, 1); BAR(); MMQ(1, 1); BAR();
        // p4: reads tile 2i+1 (buf1); stages A0(2i+2)
        STG(Ab, &As[0][0][0], t1 + 1, 0);
        VMC(6); BAR(); SGB0();
        LAF(1, 0); LBF(1, 0); MMQ(0, 0); BAR();
        // p5
        LBF(1, 1); STG(Ab, &As[0][1][0], t1 + 1, 1); BAR(); MMQ(0, 1); BAR();
        // p6
        LAF(1, 1); STG(Bb, &Bs[1][0][0], t1 + 2, 0); BAR(); MMQ(1, 0); BAR();
        // p7
        STG(Bb, &Bs[1][1][0], t1 + 2, 1); BAR(); MMQ(1, 1); BAR();
    }
    {   // peeled last iteration: tiles nt-2 (buf0), nt-1 (buf1)
        STG(Ab, &As[1][0][0], nt - 1, 0);
        VMC(6); BAR(); SGB0();
        LAF(0, 0); LBF(0, 0); MMQ(0, 0); BAR();
        LBF(0, 1); STG(Ab, &As[1][1][0], nt - 1, 1); BAR(); MMQ(0, 1); BAR();
        LAF(0, 1); BAR(); MMQ(1, 0); BAR();
        BAR(); MMQ(1, 1); BAR();
        VMC(0); BAR(); SGB0();
        LAF(1, 0); LBF(1, 0); MMQ(0, 0); BAR();
        LBF(1, 1); BAR(); MMQ(0, 1); BAR();
        LAF(1, 1); BAR(); MMQ(1, 0); BAR();
        BAR(); MMQ(1, 1); BAR();
    }
#undef LAF
#undef LBF
#undef MMQ
#undef BAR
#undef VMC
#undef SGB0

#pragma unroll
    for (int mi = 0; mi < 8; ++mi)
#pragma unroll
        for (int ni = 0; ni < 4; ++ni) {
            const int colg = n0 + wc * 64 + ni * 16 + lr;
#pragma unroll
            for (int r = 0; r < 4; ++r) {
                const int rowg = m0 + wr * 128 + mi * 16 + 4 * g + r;
                epi_write<EPI>(outp, res, N, rowg, colg, acc[mi][ni][r]);
            }
        }
}

// ---------------- 2-phase 128xBN dbuf GEMM (round-5 structure) --------------
template <int BM, int BN, int EPI>
__global__ __launch_bounds__(256) void gemm_bf16(
    const __bf16* __restrict__ A, const __bf16* __restrict__ Bt,
    void* __restrict__ outp, const float* __restrict__ res,
    int M, int N, int K)
{
    __shared__ __bf16 As[2][BM * 64];
    __shared__ __bf16 Bs[2][BN * 64];
    const int tid = threadIdx.x;

    const int gx = gridDim.x, nwg = gx * gridDim.y;
    int bid = blockIdx.y * gx + blockIdx.x;
    if ((nwg & 7) == 0) bid = (bid & 7) * (nwg >> 3) + (bid >> 3);
    const int m0 = (bid / gx) * BM, n0 = (bid % gx) * BN;

    const int lane = tid & 63, w = tid >> 6;
    const int wm = w >> 1, wn = w & 1;
    const int lr = lane & 15, g = lane >> 4;
    const int srow = lane >> 3;
    const int scol = ((lane & 7) ^ srow) * 8;
    const int xr8 = lr & 7;

    constexpr int MI = BM / 32, NI = BN / 32;
    f32x4 acc[MI][NI] = {};

    const __bf16* Abase = A + (size_t)m0 * K;
    const __bf16* Bbase = Bt + (size_t)n0 * K;

    auto STAGE = [&](int kb, int buf) {
#pragma unroll
        for (int j = 0; j < BM / 32; ++j) {
            const int s = j * 4 + w;
            GLDS16(Abase + (size_t)(s * 8 + srow) * K + kb + scol, &As[buf][s * 512]);
        }
#pragma unroll
        for (int j = 0; j < BN / 32; ++j) {
            const int s = j * 4 + w;
            GLDS16(Bbase + (size_t)(s * 8 + srow) * K + kb + scol, &Bs[buf][s * 512]);
        }
    };

    const int nt = K >> 6;
    STAGE(0, 0);
    __syncthreads();

    for (int t = 0; t < nt; ++t) {
        const int cur = t & 1;
        if (t + 1 < nt) STAGE((t + 1) << 6, cur ^ 1);

        bf16x8 af[2][MI], bfr[2][NI];
#pragma unroll
        for (int kk = 0; kk < 2; ++kk) {
#pragma unroll
            for (int i = 0; i < MI; ++i)
                af[kk][i] = *(const bf16x8*)
                    &As[cur][(wm * (BM / 2) + i * 16 + lr) * 64 + (((kk * 4 + g) ^ xr8) << 3)];
#pragma unroll
            for (int i = 0; i < NI; ++i)
                bfr[kk][i] = *(const bf16x8*)
                    &Bs[cur][(wn * (BN / 2) + i * 16 + lr) * 64 + (((kk * 4 + g) ^ xr8) << 3)];
        }
#pragma unroll
        for (int kk = 0; kk < 2; ++kk)
#pragma unroll
            for (int mi = 0; mi < MI; ++mi)
#pragma unroll
                for (int ni = 0; ni < NI; ++ni)
                    acc[mi][ni] = MFMA_16x16x32_BF16(af[kk][mi], bfr[kk][ni], acc[mi][ni]);
        if (t + 1 < nt) __syncthreads();
    }

#pragma unroll
    for (int mi = 0; mi < MI; ++mi)
#pragma unroll
        for (int ni = 0; ni < NI; ++ni) {
            const int colg = n0 + wn * (BN / 2) + ni * 16 + lr;
#pragma unroll
            for (int r = 0; r < 4; ++r) {
                const int rowg = m0 + wm * (BM / 2) + mi * 16 + 4 * g + r;
                epi_write<EPI>(outp, res, N, rowg, colg, acc[mi][ni][r]);
            }
        }
}

// ---------------- Flash-style causal attention (round-5 2-buf + exp2) -------
__global__ __launch_bounds__(256) void attn_kernel(
    const __bf16* __restrict__ Q, const __bf16* __restrict__ Kb,
    const __bf16* __restrict__ Vt, __bf16* __restrict__ ctx)
{
    const int Dm = 1024, T = 2048;
    const int tid = threadIdx.x;
    const int w = tid >> 6, lane = tid & 63;
    const int lr = lane & 15, g = lane >> 4;
    const int bx = blockIdx.x;
    const int qc = bx >> 5, bh = bx & 31, b = bh >> 4, h = bh & 15;
    const int qbase = qc * 64 + w * 16;
    const size_t rowoff = (size_t)b * T;
    const __bf16* Qp = Q + rowoff * Dm + h * 64;
    const __bf16* Kp = Kb + rowoff * Dm + h * 64;
    const __bf16* Vtp = Vt + (size_t)bh * 64 * 2048;

    __shared__ __bf16 Ks[2][64 * 64];
    __shared__ __bf16 Vs[2][64 * 64];

    // Q pre-scaled by 0.125*log2(e): scores land in log2 units
    bf16x8 qf0 = *(const bf16x8*)&Qp[(size_t)(qbase + lr) * Dm + g * 8];
    bf16x8 qf1 = *(const bf16x8*)&Qp[(size_t)(qbase + lr) * Dm + 32 + g * 8];
    const float qsc = 0.125f * 1.44269504088896340736f;
#pragma unroll
    for (int j = 0; j < 8; ++j) {
        qf0[j] = (__bf16)((float)qf0[j] * qsc);
        qf1[j] = (__bf16)((float)qf1[j] * qsc);
    }

    const int srow = lane >> 3;
    const int schunk = (lane & 7) ^ srow;

    f32x4 acc[4] = {};
    float m_s = -__builtin_inff(), l_s = 0.0f;
    const int nsteps = qc + 1;
    const f32x4 zacc = {0.0f, 0.0f, 0.0f, 0.0f};
    const int xr = (lr & 7) << 3;
    const int qg = qbase + lr;

#pragma unroll
    for (int j = 0; j < 2; ++j) {
        const int row = j * 32 + w * 8 + srow;
        GLDS16(Kp + (size_t)row * Dm + schunk * 8, &Ks[0][(j * 32 + w * 8) * 64]);
        GLDS16(Vtp + (size_t)row * T + schunk * 8, &Vs[0][(j * 32 + w * 8) * 64]);
    }
    __syncthreads();

    for (int t = 0; t < nsteps; ++t) {
        const int kvb = t * 64, cur = t & 1;
        if (t + 1 < nsteps) {
#pragma unroll
            for (int j = 0; j < 2; ++j) {
                const int row = j * 32 + w * 8 + srow;
                GLDS16(Kp + (size_t)(kvb + 64 + row) * Dm + schunk * 8,
                       &Ks[cur ^ 1][(j * 32 + w * 8) * 64]);
                GLDS16(Vtp + (size_t)row * T + kvb + 64 + schunk * 8,
                       &Vs[cur ^ 1][(j * 32 + w * 8) * 64]);
            }
        }

        float sv[4][4];
#pragma unroll
        for (int s4 = 0; s4 < 4; ++s4) {
            const int kv0 = kvb + s4 * 16;
            if (kv0 <= qbase + 15) {
                const int row = s4 * 16 + lr;
                const bf16x8 kfa = *(const bf16x8*)&Ks[cur][row * 64 + ((g * 8) ^ xr)];
                const bf16x8 kfb = *(const bf16x8*)&Ks[cur][row * 64 + ((32 + g * 8) ^ xr)];
                f32x4 st = MFMA_16x16x32_BF16(kfa, qf0, zacc);
                st = MFMA_16x16x32_BF16(kfb, qf1, st);
                const bool domask = (kv0 + 15 > qbase);
#pragma unroll
                for (int r = 0; r < 4; ++r) {
                    float x = st[r];
                    if (domask && (kv0 + 4 * g + r > qg)) x = -__builtin_inff();
                    sv[s4][r] = x;
                }
            } else {
#pragma unroll
                for (int r = 0; r < 4; ++r) sv[s4][r] = -__builtin_inff();
            }
        }

        float tm = sv[0][0];
#pragma unroll
        for (int s4 = 0; s4 < 4; ++s4)
#pragma unroll
            for (int r = 0; r < 4; ++r) tm = fmaxf(tm, sv[s4][r]);
        tm = fmaxf(tm, __shfl_xor(tm, 16));
        tm = fmaxf(tm, __shfl_xor(tm, 32));

        float m_use = m_s;
        if (!__all(tm - m_s <= 11.5f)) {
            m_use = fmaxf(m_s, tm);
            const float corr = exp2f(m_s - m_use);
            l_s *= corr;
            float cr[4];
#pragma unroll
            for (int r = 0; r < 4; ++r) cr[r] = __shfl(corr, 4 * g + r);
#pragma unroll
            for (int ct = 0; ct < 4; ++ct) {
                acc[ct][0] *= cr[0]; acc[ct][1] *= cr[1];
                acc[ct][2] *= cr[2]; acc[ct][3] *= cr[3];
            }
            m_s = m_use;
        }

        float rs = 0.0f;
#pragma unroll
        for (int s4 = 0; s4 < 4; ++s4)
#pragma unroll
            for (int r = 0; r < 4; ++r) {
                sv[s4][r] = exp2f(sv[s4][r] - m_use);
                rs += sv[s4][r];
            }
        rs += __shfl_xor(rs, 16);
        rs += __shfl_xor(rs, 32);
        l_s += rs;

        bf16x8 pa0, pa1;
#pragma unroll
        for (int r = 0; r < 4; ++r) {
            pa0[r] = (__bf16)sv[0][r];
            pa0[4 + r] = (__bf16)sv[1][r];
            pa1[r] = (__bf16)sv[2][r];
            pa1[4 + r] = (__bf16)sv[3][r];
        }
        const bool liveB = (kvb + 32 <= qbase + 15);
        __builtin_amdgcn_s_setprio(1);
#pragma unroll
        for (int ct = 0; ct < 4; ++ct) {
            const __bf16* vrow = &Vs[cur][(ct * 16 + lr) * 64];
            const bf16x8 vf = *(const bf16x8*)&vrow[(8 * g) ^ xr];
            acc[ct] = MFMA_16x16x32_BF16(pa0, vf, acc[ct]);
            if (liveB) {
                const bf16x8 vf2 = *(const bf16x8*)&vrow[(32 + 8 * g) ^ xr];
                acc[ct] = MFMA_16x16x32_BF16(pa1, vf2, acc[ct]);
            }
        }
        __builtin_amdgcn_s_setprio(0);
        __syncthreads();
    }

    const float il = __builtin_amdgcn_rcpf(l_s);
    float dn[4];
#pragma unroll
    for (int r = 0; r < 4; ++r) dn[r] = __shfl(il, 4 * g + r);
#pragma unroll
    for (int ct = 0; ct < 4; ++ct)
#pragma unroll
        for (int r = 0; r < 4; ++r)
            ctx[(rowoff + qbase + 4 * g + r) * Dm + h * 64 + ct * 16 + lr] =
                (__bf16)(acc[ct][r] * dn[r]);
}

// ---------------------------------------------------------------------------
extern "C" void kernel_launch(void* const* d_in, const int* in_sizes, int n_in,
                              void* d_out, int out_size, void* d_ws, size_t ws_size,
                              hipStream_t stream)
{
    (void)in_sizes; (void)n_in; (void)out_size; (void)ws_size;
    const float* z      = (const float*)d_in[0];
    const float* W_Q    = (const float*)d_in[1];
    const float* W_K    = (const float*)d_in[2];
    const float* W_V    = (const float*)d_in[3];
    const float* W_O    = (const float*)d_in[4];
    const float* W_fc   = (const float*)d_in[5];
    const float* W_proj = (const float*)d_in[6];
    const float* g1     = (const float*)d_in[7];
    const float* g2     = (const float*)d_in[8];
    float* out = (float*)d_out;

    char* ws = (char*)d_ws;
    const size_t MB = (size_t)1 << 20;
    __bf16* WtQKV  = (__bf16*)(ws + 0 * MB);   // [3072][1024]
    __bf16* WtO    = (__bf16*)(ws + 6 * MB);
    __bf16* Wtfc   = (__bf16*)(ws + 8 * MB);
    __bf16* Wtproj = (__bf16*)(ws + 16 * MB);
    __bf16* zn     = (__bf16*)(ws + 24 * MB);  // reused as ctx
    __bf16* Qb     = (__bf16*)(ws + 32 * MB);  // QKV out base; reused as h
    __bf16* Kbuf   = (__bf16*)(ws + 40 * MB);
    __bf16* Vtb    = (__bf16*)(ws + 48 * MB);
    __bf16* ffn1   = (__bf16*)(ws + 40 * MB);  // overlaps K,Vt (dead post-attn)
    __bf16* ctx    = zn;
    __bf16* hb     = Qb;

    const int Tt = 2048, Dm = 1024, Bb = 2, M = Bb * Tt, DFF = 4096;
    const dim3 blk256(256), blk512(512);

    // All weight transposes+converts in one launch
    transconv_all_kernel<<<12288, blk256, 0, stream>>>(
        W_Q, W_K, W_V, W_O, W_fc, W_proj, WtQKV, WtO, Wtfc, Wtproj);

    // zn = rmsnorm(z, g1)
    rmsnorm_kernel<<<M, blk256, 0, stream>>>(z, g1, zn);

    // Fused QKV (8-phase 256^2): [4096][3072]
    gemm256<4><<<dim3(12, 16), blk512, 0, stream>>>(
        zn, WtQKV, Qb, nullptr, M, 3072, Dm);

    // attention -> ctx
    attn_kernel<<<1024, blk256, 0, stream>>>(Qb, Kbuf, Vtb, ctx);

    // z2 = z + ctx @ W_O  -> d_out (fp32)
    gemm_bf16<128, 64, 1><<<dim3(16, 32), blk256, 0, stream>>>(
        ctx, WtO, out, z, M, Dm, Dm);

    // h = rmsnorm(z2, g2)
    rmsnorm_kernel<<<M, blk256, 0, stream>>>(out, g2, hb);

    // ffn1 = gelu_erf(h @ W_fc) (8-phase 256^2)
    gemm256<2><<<dim3(16, 16), blk512, 0, stream>>>(
        hb, Wtfc, ffn1, nullptr, M, DFF, Dm);

    // d_out += ffn1 @ W_proj
    gemm_bf16<128, 64, 3><<<dim3(16, 32), blk256, 0, stream>>>(
        ffn1, Wtproj, out, nullptr, M, Dm, DFF);
}

// Round 8
// 269.908 us; speedup vs baseline: 1.1701x; 1.0765x over previous
//
#include <hip/hip_runtime.h>
#include <hip/hip_bf16.h>
#include <math.h>

// ---------------------------------------------------------------------------
// GPT block on MI355X (gfx950). bf16 MFMA compute, fp32 accumulate.
// Workspace layout (MB = 1<<20), total 72 MB:
//   [ 0, 6)  WtQKV  bf16 [3072][1024]  (W_Q,W_K,W_V transposed, contiguous)
//   [ 6, 8)  WtO    bf16 [1024][1024]
//   [ 8,16)  Wtfc   bf16 [4096][1024]
//   [16,24)  Wtproj bf16 [1024][4096]
//   [24,32)  zn / ctx   bf16 [4096][1024]
//   [32,40)  Q / h      bf16 [4096][1024]
//   [40,48)  K          bf16 [4096][1024]
//   [48,56)  Vt         bf16 [32][64][2048]  (V transposed, kv-permuted)
//   [40,72)  ffn1       bf16 [4096][4096]  (overlaps K,Vt — dead after attn)
// d_out doubles as z2 (fp32): O-proj writes z2 = z + attn; proj does +=.
// fc uses the 8-phase 256^2 template (grid = 256 blocks = 1/CU exactly).
// QKV / O-proj / proj use the 2-phase 128x64 dbuf GEMM (multi-block/CU TLP).
// attn: 2-buf LDS staging, exp2-domain online softmax, defer-rescale,
// balanced qc permutation (per-CU resident blocks sum to equal work).
// ---------------------------------------------------------------------------

typedef __bf16 bf16x8 __attribute__((ext_vector_type(8)));
typedef float  f32x4  __attribute__((ext_vector_type(4)));

#define MFMA_16x16x32_BF16(A, B, C) __builtin_amdgcn_mfma_f32_16x16x32_bf16((A), (B), (C), 0, 0, 0)

#define GLDS16(g, l) __builtin_amdgcn_global_load_lds( \
    (const __attribute__((address_space(1))) void*)(g), \
    (__attribute__((address_space(3))) void*)(l), 16, 0, 0)

// ---------------- fused transpose + fp32->bf16 convert for all 6 weights ----
__global__ __launch_bounds__(256) void transconv_all_kernel(
    const float* __restrict__ W_Q, const float* __restrict__ W_K,
    const float* __restrict__ W_V, const float* __restrict__ W_O,
    const float* __restrict__ W_fc, const float* __restrict__ W_proj,
    __bf16* __restrict__ WtQKV, __bf16* __restrict__ WtO,
    __bf16* __restrict__ Wtfc, __bf16* __restrict__ Wtproj)
{
    const int id = blockIdx.x;
    const float* src;
    __bf16* dst;
    int K, N, nx, t;
    if (id < 4096) {
        const int wsel = id >> 10;
        t = id & 1023;
        src = (wsel == 0) ? W_Q : (wsel == 1) ? W_K : (wsel == 2) ? W_V : W_O;
        dst = (wsel < 3) ? (WtQKV + (size_t)wsel * 1048576) : WtO;
        K = 1024; N = 1024; nx = 32;
    } else if (id < 8192) {
        t = id - 4096; src = W_fc; dst = Wtfc; K = 1024; N = 4096; nx = 128;
    } else {
        t = id - 8192; src = W_proj; dst = Wtproj; K = 4096; N = 1024; nx = 32;
    }
    const int n0 = (t % nx) * 32, k0 = (t / nx) * 32;

    __shared__ float tile[32][33];
    const int c = threadIdx.x & 31, r = threadIdx.x >> 5;
#pragma unroll
    for (int i = 0; i < 4; ++i)
        tile[r + 8 * i][c] = src[(size_t)(k0 + r + 8 * i) * N + n0 + c];
    __syncthreads();
#pragma unroll
    for (int i = 0; i < 4; ++i)
        dst[(size_t)(n0 + r + 8 * i) * K + k0 + c] = (__bf16)tile[c][r + 8 * i];
}

// ---------------- RMSNorm: fp32 [M][1024] -> bf16 [M][1024] -----------------
__global__ __launch_bounds__(256) void rmsnorm_kernel(
    const float* __restrict__ x, const float* __restrict__ gain,
    __bf16* __restrict__ out)
{
    const int row = blockIdx.x, t = threadIdx.x;
    const float4 v = ((const float4*)(x + (size_t)row * 1024))[t];
    float ss = v.x * v.x + v.y * v.y + v.z * v.z + v.w * v.w;
#pragma unroll
    for (int m = 1; m < 64; m <<= 1) ss += __shfl_xor(ss, m);
    __shared__ float red[4];
    const int wid = t >> 6, lane = t & 63;
    if (lane == 0) red[wid] = ss;
    __syncthreads();
    const float tot = red[0] + red[1] + red[2] + red[3];
    const float inv = rsqrtf(tot * (1.0f / 1024.0f) + 1e-5f);
    const float4 gv = ((const float4*)gain)[t];
    __bf16* o = out + (size_t)row * 1024 + t * 4;
    o[0] = (__bf16)(v.x * inv * gv.x);
    o[1] = (__bf16)(v.y * inv * gv.y);
    o[2] = (__bf16)(v.z * inv * gv.z);
    o[3] = (__bf16)(v.w * inv * gv.w);
}

// ---------------- C-write helper (shared by both GEMM kernels) --------------
template <int EPI>
__device__ __forceinline__ void epi_write(
    void* outp, const float* res, int N, int rowg, int colg, float v)
{
    if constexpr (EPI == 1) {
        const size_t idx = (size_t)rowg * N + colg;
        ((float*)outp)[idx] = res[idx] + v;
    } else if constexpr (EPI == 2) {
        const size_t idx = (size_t)rowg * N + colg;
        ((__bf16*)outp)[idx] =
            (__bf16)(0.5f * v * (1.0f + erff(v * 0.70710678118654752f)));
    } else if constexpr (EPI == 3) {
        const size_t idx = (size_t)rowg * N + colg;
        ((float*)outp)[idx] += v;
    } else {  // EPI == 4: QKV split
        __bf16* base = (__bf16*)outp;
        const int seg = colg >> 10;       // 0=Q, 1=K, 2=V
        const int cg = colg & 1023;
        if (seg < 2) {
            base[(size_t)seg * 4194304 + (size_t)rowg * 1024 + cg] = (__bf16)v;
        } else {
            // Vt[b][h][d][t'] with within-32 t-permutation: 16h+4g+j -> 8g+4h+j
            const int tt = rowg & 2047;
            const int r32 = tt & 31;
            const int p = ((r32 & 12) << 1) | ((r32 >> 2) & 4) | (r32 & 3);
            base[8388608 +
                 ((size_t)((rowg >> 11) * 16 + (cg >> 6)) * 64 + (cg & 63)) * 2048 +
                 ((tt & ~31) | p)] = (__bf16)v;
        }
    }
}

// ---------------- 8-phase 256x256 GEMM (m201 template, plain HIP) -----------
// Used only where grid covers the machine (fc: 256 blocks). 512 thr = 8 waves.
template <int EPI>
__global__ __launch_bounds__(512, 2) void gemm256(
    const __bf16* __restrict__ A, const __bf16* __restrict__ Bt,
    void* __restrict__ outp, const float* __restrict__ res,
    int M, int N, int K)
{
    __shared__ __bf16 As[2][2][128 * 64];   // [dbuf][half][row*64+elem]
    __shared__ __bf16 Bs[2][2][128 * 64];
    const int tid = threadIdx.x;

    const int gx = gridDim.x, nwg = gx * gridDim.y;
    int bid = blockIdx.y * gx + blockIdx.x;
    if ((nwg & 7) == 0) bid = (bid & 7) * (nwg >> 3) + (bid >> 3);
    const int m0 = (bid / gx) * 256, n0 = (bid % gx) * 256;

    const int lane = tid & 63, w = tid >> 6;         // 8 waves
    const int wr = w >> 2, wc = w & 3;               // 2 x 4 wave grid
    const int lr = lane & 15, g = lane >> 4;
    const int srow8 = lane >> 3, schunk = (lane & 7) ^ srow8;
    const int xk = lr & 7;
    const int wch = wc >> 1, bro = (wc & 1) * 64;    // B half / row offset

    const __bf16* Ab = A + (size_t)m0 * K;
    const __bf16* Bb = Bt + (size_t)n0 * K;

    auto STG = [&](const __bf16* gb, __bf16* lds, int kt, int half) {
        const __bf16* src = gb + (size_t)(half * 128) * K + (kt << 6);
#pragma unroll
        for (int j = 0; j < 2; ++j) {
            const int sidx = j * 8 + w;
            GLDS16(src + (size_t)(sidx * 8 + srow8) * K + schunk * 8, lds + sidx * 512);
        }
    };

    f32x4 acc[8][4] = {};
    bf16x8 af[2][4], bf[2][4];

#define LAF(BUF, QM) do {                                                       \
    _Pragma("unroll") for (int i_ = 0; i_ < 4; ++i_)                            \
    _Pragma("unroll") for (int kk_ = 0; kk_ < 2; ++kk_)                         \
        af[kk_][i_] = *(const bf16x8*)&As[BUF][wr]                              \
            [((QM) * 64 + i_ * 16 + lr) * 64 + (((kk_ * 4 + g) ^ xk) << 3)];    \
    } while (0)

#define LBF(BUF, QN) do {                                                       \
    _Pragma("unroll") for (int i_ = 0; i_ < 2; ++i_)                            \
    _Pragma("unroll") for (int kk_ = 0; kk_ < 2; ++kk_)                         \
        bf[kk_][(QN) * 2 + i_] = *(const bf16x8*)&Bs[BUF][wch]                  \
            [(bro + ((QN) * 2 + i_) * 16 + lr) * 64 + (((kk_ * 4 + g) ^ xk) << 3)]; \
    } while (0)

#define MMQ(QM, QN) do {                                                        \
    __builtin_amdgcn_s_setprio(1);                                              \
    _Pragma("unroll") for (int kk_ = 0; kk_ < 2; ++kk_)                         \
    _Pragma("unroll") for (int i_ = 0; i_ < 4; ++i_)                            \
    _Pragma("unroll") for (int n_ = 0; n_ < 2; ++n_)                            \
        acc[(QM) * 4 + i_][(QN) * 2 + n_] = MFMA_16x16x32_BF16(                 \
            af[kk_][i_], bf[kk_][(QN) * 2 + n_], acc[(QM) * 4 + i_][(QN) * 2 + n_]); \
    __builtin_amdgcn_s_setprio(0);                                              \
    } while (0)

#define BAR()  __builtin_amdgcn_s_barrier()
#define VMC(N_) asm volatile("s_waitcnt vmcnt(" #N_ ")" ::: "memory")
#define SGB0() __builtin_amdgcn_sched_barrier(0)

    const int nt = K >> 6, niter = nt >> 1;

    // prologue: tile0 fully + B halves of tile1
    STG(Ab, &As[0][0][0], 0, 0); STG(Ab, &As[0][1][0], 0, 1);
    STG(Bb, &Bs[0][0][0], 0, 0); STG(Bb, &Bs[0][1][0], 0, 1);
    STG(Bb, &Bs[1][0][0], 1, 0); STG(Bb, &Bs[1][1][0], 1, 1);

    for (int i = 0; i < niter - 1; ++i) {
        const int t1 = 2 * i + 1;
        STG(Ab, &As[1][0][0], t1, 0);
        VMC(6); BAR(); SGB0();
        LAF(0, 0); LBF(0, 0); MMQ(0, 0); BAR();
        LBF(0, 1); STG(Ab, &As[1][1][0], t1, 1); BAR(); MMQ(0, 1); BAR();
        LAF(0, 1); STG(Bb, &Bs[0][0][0], t1 + 1, 0); BAR(); MMQ(1, 0); BAR();
        STG(Bb, &Bs[0][1][0], t1 + 1, 1); BAR(); MMQ(1, 1); BAR();
        STG(Ab, &As[0][0][0], t1 + 1, 0);
        VMC(6); BAR(); SGB0();
        LAF(1, 0); LBF(1, 0); MMQ(0, 0); BAR();
        LBF(1, 1); STG(Ab, &As[0][1][0], t1 + 1, 1); BAR(); MMQ(0, 1); BAR();
        LAF(1, 1); STG(Bb, &Bs[1][0][0], t1 + 2, 0); BAR(); MMQ(1, 0); BAR();
        STG(Bb, &Bs[1][1][0], t1 + 2, 1); BAR(); MMQ(1, 1); BAR();
    }
    {   // peeled last iteration
        STG(Ab, &As[1][0][0], nt - 1, 0);
        VMC(6); BAR(); SGB0();
        LAF(0, 0); LBF(0, 0); MMQ(0, 0); BAR();
        LBF(0, 1); STG(Ab, &As[1][1][0], nt - 1, 1); BAR(); MMQ(0, 1); BAR();
        LAF(0, 1); BAR(); MMQ(1, 0); BAR();
        BAR(); MMQ(1, 1); BAR();
        VMC(0); BAR(); SGB0();
        LAF(1, 0); LBF(1, 0); MMQ(0, 0); BAR();
        LBF(1, 1); BAR(); MMQ(0, 1); BAR();
        LAF(1, 1); BAR(); MMQ(1, 0); BAR();
        BAR(); MMQ(1, 1); BAR();
    }
#undef LAF
#undef LBF
#undef MMQ
#undef BAR
#undef VMC
#undef SGB0

#pragma unroll
    for (int mi = 0; mi < 8; ++mi)
#pragma unroll
        for (int ni = 0; ni < 4; ++ni) {
            const int colg = n0 + wc * 64 + ni * 16 + lr;
#pragma unroll
            for (int r = 0; r < 4; ++r) {
                const int rowg = m0 + wr * 128 + mi * 16 + 4 * g + r;
                epi_write<EPI>(outp, res, N, rowg, colg, acc[mi][ni][r]);
            }
        }
}

// ---------------- 2-phase 128xBN dbuf GEMM ----------------------------------
template <int BM, int BN, int EPI>
__global__ __launch_bounds__(256) void gemm_bf16(
    const __bf16* __restrict__ A, const __bf16* __restrict__ Bt,
    void* __restrict__ outp, const float* __restrict__ res,
    int M, int N, int K)
{
    __shared__ __bf16 As[2][BM * 64];
    __shared__ __bf16 Bs[2][BN * 64];
    const int tid = threadIdx.x;

    const int gx = gridDim.x, nwg = gx * gridDim.y;
    int bid = blockIdx.y * gx + blockIdx.x;
    if ((nwg & 7) == 0) bid = (bid & 7) * (nwg >> 3) + (bid >> 3);
    const int m0 = (bid / gx) * BM, n0 = (bid % gx) * BN;

    const int lane = tid & 63, w = tid >> 6;
    const int wm = w >> 1, wn = w & 1;
    const int lr = lane & 15, g = lane >> 4;
    const int srow = lane >> 3;
    const int scol = ((lane & 7) ^ srow) * 8;
    const int xr8 = lr & 7;

    constexpr int MI = BM / 32, NI = BN / 32;
    f32x4 acc[MI][NI] = {};

    const __bf16* Abase = A + (size_t)m0 * K;
    const __bf16* Bbase = Bt + (size_t)n0 * K;

    auto STAGE = [&](int kb, int buf) {
#pragma unroll
        for (int j = 0; j < BM / 32; ++j) {
            const int s = j * 4 + w;
            GLDS16(Abase + (size_t)(s * 8 + srow) * K + kb + scol, &As[buf][s * 512]);
        }
#pragma unroll
        for (int j = 0; j < BN / 32; ++j) {
            const int s = j * 4 + w;
            GLDS16(Bbase + (size_t)(s * 8 + srow) * K + kb + scol, &Bs[buf][s * 512]);
        }
    };

    const int nt = K >> 6;
    STAGE(0, 0);
    __syncthreads();

    for (int t = 0; t < nt; ++t) {
        const int cur = t & 1;
        if (t + 1 < nt) STAGE((t + 1) << 6, cur ^ 1);

        bf16x8 af[2][MI], bfr[2][NI];
#pragma unroll
        for (int kk = 0; kk < 2; ++kk) {
#pragma unroll
            for (int i = 0; i < MI; ++i)
                af[kk][i] = *(const bf16x8*)
                    &As[cur][(wm * (BM / 2) + i * 16 + lr) * 64 + (((kk * 4 + g) ^ xr8) << 3)];
#pragma unroll
            for (int i = 0; i < NI; ++i)
                bfr[kk][i] = *(const bf16x8*)
                    &Bs[cur][(wn * (BN / 2) + i * 16 + lr) * 64 + (((kk * 4 + g) ^ xr8) << 3)];
        }
#pragma unroll
        for (int kk = 0; kk < 2; ++kk)
#pragma unroll
            for (int mi = 0; mi < MI; ++mi)
#pragma unroll
                for (int ni = 0; ni < NI; ++ni)
                    acc[mi][ni] = MFMA_16x16x32_BF16(af[kk][mi], bfr[kk][ni], acc[mi][ni]);
        if (t + 1 < nt) __syncthreads();
    }

#pragma unroll
    for (int mi = 0; mi < MI; ++mi)
#pragma unroll
        for (int ni = 0; ni < NI; ++ni) {
            const int colg = n0 + wn * (BN / 2) + ni * 16 + lr;
#pragma unroll
            for (int r = 0; r < 4; ++r) {
                const int rowg = m0 + wm * (BM / 2) + mi * 16 + 4 * g + r;
                epi_write<EPI>(outp, res, N, rowg, colg, acc[mi][ni][r]);
            }
        }
}

// ---------------- Flash-style causal attention (2-buf + exp2, balanced) -----
// Grid: blockIdx.x = j*32 + bh; qc = sigma(j) where sigma pairs octants
// {j, 31-j} so each CU's 4 resident blocks (stride-256 round-robin) sum to
// the same number of kv steps (66). No setprio (lockstep block — m190 null).
__global__ __launch_bounds__(256) void attn_kernel(
    const __bf16* __restrict__ Q, const __bf16* __restrict__ Kb,
    const __bf16* __restrict__ Vt, __bf16* __restrict__ ctx)
{
    const int Dm = 1024, T = 2048;
    const int tid = threadIdx.x;
    const int w = tid >> 6, lane = tid & 63;
    const int lr = lane & 15, g = lane >> 4;
    const int bx = blockIdx.x;
    const int j = bx >> 5, bh = bx & 31, b = bh >> 4, h = bh & 15;
    // balanced bijection: octants map to {0..7},{31..24},{8..15},{23..16}
    const int qc = (j < 8) ? j : (j < 16) ? 39 - j : (j < 24) ? j - 8 : 47 - j;
    const int qbase = qc * 64 + w * 16;
    const size_t rowoff = (size_t)b * T;
    const __bf16* Qp = Q + rowoff * Dm + h * 64;
    const __bf16* Kp = Kb + rowoff * Dm + h * 64;
    const __bf16* Vtp = Vt + (size_t)bh * 64 * 2048;

    __shared__ __bf16 Ks[2][64 * 64];
    __shared__ __bf16 Vs[2][64 * 64];

    // Q pre-scaled by 0.125*log2(e): scores land in log2 units
    bf16x8 qf0 = *(const bf16x8*)&Qp[(size_t)(qbase + lr) * Dm + g * 8];
    bf16x8 qf1 = *(const bf16x8*)&Qp[(size_t)(qbase + lr) * Dm + 32 + g * 8];
    const float qsc = 0.125f * 1.44269504088896340736f;
#pragma unroll
    for (int jj = 0; jj < 8; ++jj) {
        qf0[jj] = (__bf16)((float)qf0[jj] * qsc);
        qf1[jj] = (__bf16)((float)qf1[jj] * qsc);
    }

    const int srow = lane >> 3;
    const int schunk = (lane & 7) ^ srow;

    f32x4 acc[4] = {};
    float m_s = -__builtin_inff(), l_s = 0.0f;
    const int nsteps = qc + 1;
    const f32x4 zacc = {0.0f, 0.0f, 0.0f, 0.0f};
    const int xr = (lr & 7) << 3;
    const int qg = qbase + lr;

#pragma unroll
    for (int jj = 0; jj < 2; ++jj) {
        const int row = jj * 32 + w * 8 + srow;
        GLDS16(Kp + (size_t)row * Dm + schunk * 8, &Ks[0][(jj * 32 + w * 8) * 64]);
        GLDS16(Vtp + (size_t)row * T + schunk * 8, &Vs[0][(jj * 32 + w * 8) * 64]);
    }
    __syncthreads();

    for (int t = 0; t < nsteps; ++t) {
        const int kvb = t * 64, cur = t & 1;
        if (t + 1 < nsteps) {
#pragma unroll
            for (int jj = 0; jj < 2; ++jj) {
                const int row = jj * 32 + w * 8 + srow;
                GLDS16(Kp + (size_t)(kvb + 64 + row) * Dm + schunk * 8,
                       &Ks[cur ^ 1][(jj * 32 + w * 8) * 64]);
                GLDS16(Vtp + (size_t)row * T + kvb + 64 + schunk * 8,
                       &Vs[cur ^ 1][(jj * 32 + w * 8) * 64]);
            }
        }

        float sv[4][4];
#pragma unroll
        for (int s4 = 0; s4 < 4; ++s4) {
            const int kv0 = kvb + s4 * 16;
            if (kv0 <= qbase + 15) {
                const int row = s4 * 16 + lr;
                const bf16x8 kfa = *(const bf16x8*)&Ks[cur][row * 64 + ((g * 8) ^ xr)];
                const bf16x8 kfb = *(const bf16x8*)&Ks[cur][row * 64 + ((32 + g * 8) ^ xr)];
                f32x4 st = MFMA_16x16x32_BF16(kfa, qf0, zacc);
                st = MFMA_16x16x32_BF16(kfb, qf1, st);
                const bool domask = (kv0 + 15 > qbase);
#pragma unroll
                for (int r = 0; r < 4; ++r) {
                    float x = st[r];
                    if (domask && (kv0 + 4 * g + r > qg)) x = -__builtin_inff();
                    sv[s4][r] = x;
                }
            } else {
#pragma unroll
                for (int r = 0; r < 4; ++r) sv[s4][r] = -__builtin_inff();
            }
        }

        float tm = sv[0][0];
#pragma unroll
        for (int s4 = 0; s4 < 4; ++s4)
#pragma unroll
            for (int r = 0; r < 4; ++r) tm = fmaxf(tm, sv[s4][r]);
        tm = fmaxf(tm, __shfl_xor(tm, 16));
        tm = fmaxf(tm, __shfl_xor(tm, 32));

        float m_use = m_s;
        if (!__all(tm - m_s <= 11.5f)) {
            m_use = fmaxf(m_s, tm);
            const float corr = exp2f(m_s - m_use);
            l_s *= corr;
            float cr[4];
#pragma unroll
            for (int r = 0; r < 4; ++r) cr[r] = __shfl(corr, 4 * g + r);
#pragma unroll
            for (int ct = 0; ct < 4; ++ct) {
                acc[ct][0] *= cr[0]; acc[ct][1] *= cr[1];
                acc[ct][2] *= cr[2]; acc[ct][3] *= cr[3];
            }
            m_s = m_use;
        }

        float rs = 0.0f;
#pragma unroll
        for (int s4 = 0; s4 < 4; ++s4)
#pragma unroll
            for (int r = 0; r < 4; ++r) {
                sv[s4][r] = exp2f(sv[s4][r] - m_use);
                rs += sv[s4][r];
            }
        rs += __shfl_xor(rs, 16);
        rs += __shfl_xor(rs, 32);
        l_s += rs;

        bf16x8 pa0, pa1;
#pragma unroll
        for (int r = 0; r < 4; ++r) {
            pa0[r] = (__bf16)sv[0][r];
            pa0[4 + r] = (__bf16)sv[1][r];
            pa1[r] = (__bf16)sv[2][r];
            pa1[4 + r] = (__bf16)sv[3][r];
        }
        const bool liveB = (kvb + 32 <= qbase + 15);
#pragma unroll
        for (int ct = 0; ct < 4; ++ct) {
            const __bf16* vrow = &Vs[cur][(ct * 16 + lr) * 64];
            const bf16x8 vf = *(const bf16x8*)&vrow[(8 * g) ^ xr];
            acc[ct] = MFMA_16x16x32_BF16(pa0, vf, acc[ct]);
            if (liveB) {
                const bf16x8 vf2 = *(const bf16x8*)&vrow[(32 + 8 * g) ^ xr];
                acc[ct] = MFMA_16x16x32_BF16(pa1, vf2, acc[ct]);
            }
        }
        __syncthreads();
    }

    const float il = __builtin_amdgcn_rcpf(l_s);
    float dn[4];
#pragma unroll
    for (int r = 0; r < 4; ++r) dn[r] = __shfl(il, 4 * g + r);
#pragma unroll
    for (int ct = 0; ct < 4; ++ct)
#pragma unroll
        for (int r = 0; r < 4; ++r)
            ctx[(rowoff + qbase + 4 * g + r) * Dm + h * 64 + ct * 16 + lr] =
                (__bf16)(acc[ct][r] * dn[r]);
}

// ---------------------------------------------------------------------------
extern "C" void kernel_launch(void* const* d_in, const int* in_sizes, int n_in,
                              void* d_out, int out_size, void* d_ws, size_t ws_size,
                              hipStream_t stream)
{
    (void)in_sizes; (void)n_in; (void)out_size; (void)ws_size;
    const float* z      = (const float*)d_in[0];
    const float* W_Q    = (const float*)d_in[1];
    const float* W_K    = (const float*)d_in[2];
    const float* W_V    = (const float*)d_in[3];
    const float* W_O    = (const float*)d_in[4];
    const float* W_fc   = (const float*)d_in[5];
    const float* W_proj = (const float*)d_in[6];
    const float* g1     = (const float*)d_in[7];
    const float* g2     = (const float*)d_in[8];
    float* out = (float*)d_out;

    char* ws = (char*)d_ws;
    const size_t MB = (size_t)1 << 20;
    __bf16* WtQKV  = (__bf16*)(ws + 0 * MB);   // [3072][1024]
    __bf16* WtO    = (__bf16*)(ws + 6 * MB);
    __bf16* Wtfc   = (__bf16*)(ws + 8 * MB);
    __bf16* Wtproj = (__bf16*)(ws + 16 * MB);
    __bf16* zn     = (__bf16*)(ws + 24 * MB);  // reused as ctx
    __bf16* Qb     = (__bf16*)(ws + 32 * MB);  // QKV out base; reused as h
    __bf16* Kbuf   = (__bf16*)(ws + 40 * MB);
    __bf16* Vtb    = (__bf16*)(ws + 48 * MB);
    __bf16* ffn1   = (__bf16*)(ws + 40 * MB);  // overlaps K,Vt (dead post-attn)
    __bf16* ctx    = zn;
    __bf16* hb     = Qb;

    const int Tt = 2048, Dm = 1024, Bb = 2, M = Bb * Tt, DFF = 4096;
    const dim3 blk256(256), blk512(512);

    // All weight transposes+converts in one launch
    transconv_all_kernel<<<12288, blk256, 0, stream>>>(
        W_Q, W_K, W_V, W_O, W_fc, W_proj, WtQKV, WtO, Wtfc, Wtproj);

    // zn = rmsnorm(z, g1)
    rmsnorm_kernel<<<M, blk256, 0, stream>>>(z, g1, zn);

    // Fused QKV (2-phase 128x64, 1536 blocks -> 3/CU TLP): [4096][3072]
    gemm_bf16<128, 64, 4><<<dim3(48, 32), blk256, 0, stream>>>(
        zn, WtQKV, Qb, nullptr, M, 3072, Dm);

    // attention -> ctx
    attn_kernel<<<1024, blk256, 0, stream>>>(Qb, Kbuf, Vtb, ctx);

    // z2 = z + ctx @ W_O  -> d_out (fp32)
    gemm_bf16<128, 64, 1><<<dim3(16, 32), blk256, 0, stream>>>(
        ctx, WtO, out, z, M, Dm, Dm);

    // h = rmsnorm(z2, g2)
    rmsnorm_kernel<<<M, blk256, 0, stream>>>(out, g2, hb);

    // ffn1 = gelu_erf(h @ W_fc) (8-phase 256^2, 256 blocks = 1/CU exactly)
    gemm256<2><<<dim3(16, 16), blk512, 0, stream>>>(
        hb, Wtfc, ffn1, nullptr, M, DFF, Dm);

    // d_out += ffn1 @ W_proj
    gemm_bf16<128, 64, 3><<<dim3(16, 32), blk256, 0, stream>>>(
        ffn1, Wtproj, out, nullptr, M, Dm, DFF);
}

// Round 9
// 258.799 us; speedup vs baseline: 1.2204x; 1.0429x over previous
//
#include <hip/hip_runtime.h>
#include <hip/hip_bf16.h>
#include <math.h>

// ---------------------------------------------------------------------------
// GPT block on MI355X (gfx950). bf16 MFMA compute, fp32 accumulate.
// Workspace layout (MB = 1<<20), total 72 MB:
//   [ 0, 6)  WtQKV  bf16 [3072][1024]   -- dead after QKV; reused as partial0
//   [ 6, 8)  WtO    bf16 [1024][1024]   -- dead after O-proj   (part of p0)
//   [ 8,16)  Wtfc   bf16 [4096][1024]   -- dead after fc       (part of p0)
//   [16,24)  Wtproj bf16 [1024][4096]
//   [24,32)  zn / ctx   bf16            -- dead after O-proj; partial1 start
//   [32,40)  Q / h      bf16            -- dead after fc       (part of p1)
//   [40,48)  K          bf16
//   [48,56)  Vt         bf16 [32][64][2048]  (V transposed, kv-permuted)
//   [40,72)  ffn1       bf16 [4096][4096]  (overlaps K,Vt — dead after attn)
// partial0 = ws+0 (fp32 16MB), partial1 = ws+24MB (fp32 16MB): proj split-K
// parts; reduce kernel does out += p0 + p1 (out already holds z2).
// fc uses the 8-phase 256^2 template (grid = 256 blocks = 1/CU exactly).
// QKV / proj parts use 2-phase 128x128; O-proj 2-phase 128x64.
// ---------------------------------------------------------------------------

typedef __bf16 bf16x8 __attribute__((ext_vector_type(8)));
typedef float  f32x4  __attribute__((ext_vector_type(4)));

#define MFMA_16x16x32_BF16(A, B, C) __builtin_amdgcn_mfma_f32_16x16x32_bf16((A), (B), (C), 0, 0, 0)

#define GLDS16(g, l) __builtin_amdgcn_global_load_lds( \
    (const __attribute__((address_space(1))) void*)(g), \
    (__attribute__((address_space(3))) void*)(l), 16, 0, 0)

// ---------------- fused transpose + fp32->bf16 convert for all 6 weights ----
__global__ __launch_bounds__(256) void transconv_all_kernel(
    const float* __restrict__ W_Q, const float* __restrict__ W_K,
    const float* __restrict__ W_V, const float* __restrict__ W_O,
    const float* __restrict__ W_fc, const float* __restrict__ W_proj,
    __bf16* __restrict__ WtQKV, __bf16* __restrict__ WtO,
    __bf16* __restrict__ Wtfc, __bf16* __restrict__ Wtproj)
{
    const int id = blockIdx.x;
    const float* src;
    __bf16* dst;
    int K, N, nx, t;
    if (id < 4096) {
        const int wsel = id >> 10;
        t = id & 1023;
        src = (wsel == 0) ? W_Q : (wsel == 1) ? W_K : (wsel == 2) ? W_V : W_O;
        dst = (wsel < 3) ? (WtQKV + (size_t)wsel * 1048576) : WtO;
        K = 1024; N = 1024; nx = 32;
    } else if (id < 8192) {
        t = id - 4096; src = W_fc; dst = Wtfc; K = 1024; N = 4096; nx = 128;
    } else {
        t = id - 8192; src = W_proj; dst = Wtproj; K = 4096; N = 1024; nx = 32;
    }
    const int n0 = (t % nx) * 32, k0 = (t / nx) * 32;

    __shared__ float tile[32][33];
    const int c = threadIdx.x & 31, r = threadIdx.x >> 5;
#pragma unroll
    for (int i = 0; i < 4; ++i)
        tile[r + 8 * i][c] = src[(size_t)(k0 + r + 8 * i) * N + n0 + c];
    __syncthreads();
#pragma unroll
    for (int i = 0; i < 4; ++i)
        dst[(size_t)(n0 + r + 8 * i) * K + k0 + c] = (__bf16)tile[c][r + 8 * i];
}

// ---------------- RMSNorm: fp32 [M][1024] -> bf16 [M][1024] -----------------
__global__ __launch_bounds__(256) void rmsnorm_kernel(
    const float* __restrict__ x, const float* __restrict__ gain,
    __bf16* __restrict__ out)
{
    const int row = blockIdx.x, t = threadIdx.x;
    const float4 v = ((const float4*)(x + (size_t)row * 1024))[t];
    float ss = v.x * v.x + v.y * v.y + v.z * v.z + v.w * v.w;
#pragma unroll
    for (int m = 1; m < 64; m <<= 1) ss += __shfl_xor(ss, m);
    __shared__ float red[4];
    const int wid = t >> 6, lane = t & 63;
    if (lane == 0) red[wid] = ss;
    __syncthreads();
    const float tot = red[0] + red[1] + red[2] + red[3];
    const float inv = rsqrtf(tot * (1.0f / 1024.0f) + 1e-5f);
    const float4 gv = ((const float4*)gain)[t];
    __bf16* o = out + (size_t)row * 1024 + t * 4;
    o[0] = (__bf16)(v.x * inv * gv.x);
    o[1] = (__bf16)(v.y * inv * gv.y);
    o[2] = (__bf16)(v.z * inv * gv.z);
    o[3] = (__bf16)(v.w * inv * gv.w);
}

// ---------------- reduce: out += p0 + p1 (fp32, float4 grid-stride) ---------
__global__ __launch_bounds__(256) void reduce_add_kernel(
    float* __restrict__ out, const float* __restrict__ p0,
    const float* __restrict__ p1, int n4)
{
    for (int i = blockIdx.x * 256 + threadIdx.x; i < n4; i += gridDim.x * 256) {
        const float4 a = ((const float4*)p0)[i];
        const float4 b = ((const float4*)p1)[i];
        float4 o = ((float4*)out)[i];
        o.x += a.x + b.x; o.y += a.y + b.y;
        o.z += a.z + b.z; o.w += a.w + b.w;
        ((float4*)out)[i] = o;
    }
}

// ---------------- C-write helper --------------------------------------------
template <int EPI>
__device__ __forceinline__ void epi_write(
    void* outp, const float* res, int N, int rowg, int colg, float v)
{
    if constexpr (EPI == 1) {
        const size_t idx = (size_t)rowg * N + colg;
        ((float*)outp)[idx] = res[idx] + v;
    } else if constexpr (EPI == 2) {
        const size_t idx = (size_t)rowg * N + colg;
        ((__bf16*)outp)[idx] =
            (__bf16)(0.5f * v * (1.0f + erff(v * 0.70710678118654752f)));
    } else if constexpr (EPI == 3) {
        const size_t idx = (size_t)rowg * N + colg;
        ((float*)outp)[idx] += v;
    } else {  // EPI == 4: QKV split
        __bf16* base = (__bf16*)outp;
        const int seg = colg >> 10;       // 0=Q, 1=K, 2=V
        const int cg = colg & 1023;
        if (seg < 2) {
            base[(size_t)seg * 4194304 + (size_t)rowg * 1024 + cg] = (__bf16)v;
        } else {
            // Vt[b][h][d][t'] with within-32 t-permutation: 16h+4g+j -> 8g+4h+j
            const int tt = rowg & 2047;
            const int r32 = tt & 31;
            const int p = ((r32 & 12) << 1) | ((r32 >> 2) & 4) | (r32 & 3);
            base[8388608 +
                 ((size_t)((rowg >> 11) * 16 + (cg >> 6)) * 64 + (cg & 63)) * 2048 +
                 ((tt & ~31) | p)] = (__bf16)v;
        }
    }
}

// ---------------- 8-phase 256x256 GEMM (m201 template) ----------------------
template <int EPI>
__global__ __launch_bounds__(512, 2) void gemm256(
    const __bf16* __restrict__ A, const __bf16* __restrict__ Bt,
    void* __restrict__ outp, const float* __restrict__ res,
    int M, int N, int K)
{
    __shared__ __bf16 As[2][2][128 * 64];   // [dbuf][half][row*64+elem]
    __shared__ __bf16 Bs[2][2][128 * 64];
    const int tid = threadIdx.x;

    const int gx = gridDim.x, nwg = gx * gridDim.y;
    int bid = blockIdx.y * gx + blockIdx.x;
    if ((nwg & 7) == 0) bid = (bid & 7) * (nwg >> 3) + (bid >> 3);
    const int m0 = (bid / gx) * 256, n0 = (bid % gx) * 256;

    const int lane = tid & 63, w = tid >> 6;         // 8 waves
    const int wr = w >> 2, wc = w & 3;               // 2 x 4 wave grid
    const int lr = lane & 15, g = lane >> 4;
    const int srow8 = lane >> 3, schunk = (lane & 7) ^ srow8;
    const int xk = lr & 7;
    const int wch = wc >> 1, bro = (wc & 1) * 64;    // B half / row offset

    const __bf16* Ab = A + (size_t)m0 * K;
    const __bf16* Bb = Bt + (size_t)n0 * K;

    auto STG = [&](const __bf16* gb, __bf16* lds, int kt, int half) {
        const __bf16* src = gb + (size_t)(half * 128) * K + (kt << 6);
#pragma unroll
        for (int j = 0; j < 2; ++j) {
            const int sidx = j * 8 + w;
            GLDS16(src + (size_t)(sidx * 8 + srow8) * K + schunk * 8, lds + sidx * 512);
        }
    };

    f32x4 acc[8][4] = {};
    bf16x8 af[2][4], bf[2][4];

#define LAF(BUF, QM) do {                                                       \
    _Pragma("unroll") for (int i_ = 0; i_ < 4; ++i_)                            \
    _Pragma("unroll") for (int kk_ = 0; kk_ < 2; ++kk_)                         \
        af[kk_][i_] = *(const bf16x8*)&As[BUF][wr]                              \
            [((QM) * 64 + i_ * 16 + lr) * 64 + (((kk_ * 4 + g) ^ xk) << 3)];    \
    } while (0)

#define LBF(BUF, QN) do {                                                       \
    _Pragma("unroll") for (int i_ = 0; i_ < 2; ++i_)                            \
    _Pragma("unroll") for (int kk_ = 0; kk_ < 2; ++kk_)                         \
        bf[kk_][(QN) * 2 + i_] = *(const bf16x8*)&Bs[BUF][wch]                  \
            [(bro + ((QN) * 2 + i_) * 16 + lr) * 64 + (((kk_ * 4 + g) ^ xk) << 3)]; \
    } while (0)

#define MMQ(QM, QN) do {                                                        \
    __builtin_amdgcn_s_setprio(1);                                              \
    _Pragma("unroll") for (int kk_ = 0; kk_ < 2; ++kk_)                         \
    _Pragma("unroll") for (int i_ = 0; i_ < 4; ++i_)                            \
    _Pragma("unroll") for (int n_ = 0; n_ < 2; ++n_)                            \
        acc[(QM) * 4 + i_][(QN) * 2 + n_] = MFMA_16x16x32_BF16(                 \
            af[kk_][i_], bf[kk_][(QN) * 2 + n_], acc[(QM) * 4 + i_][(QN) * 2 + n_]); \
    __builtin_amdgcn_s_setprio(0);                                              \
    } while (0)

#define BAR()  __builtin_amdgcn_s_barrier()
#define VMC(N_) asm volatile("s_waitcnt vmcnt(" #N_ ")" ::: "memory")
#define SGB0() __builtin_amdgcn_sched_barrier(0)

    const int nt = K >> 6, niter = nt >> 1;

    STG(Ab, &As[0][0][0], 0, 0); STG(Ab, &As[0][1][0], 0, 1);
    STG(Bb, &Bs[0][0][0], 0, 0); STG(Bb, &Bs[0][1][0], 0, 1);
    STG(Bb, &Bs[1][0][0], 1, 0); STG(Bb, &Bs[1][1][0], 1, 1);

    for (int i = 0; i < niter - 1; ++i) {
        const int t1 = 2 * i + 1;
        STG(Ab, &As[1][0][0], t1, 0);
        VMC(6); BAR(); SGB0();
        LAF(0, 0); LBF(0, 0); MMQ(0, 0); BAR();
        LBF(0, 1); STG(Ab, &As[1][1][0], t1, 1); BAR(); MMQ(0, 1); BAR();
        LAF(0, 1); STG(Bb, &Bs[0][0][0], t1 + 1, 0); BAR(); MMQ(1, 0); BAR();
        STG(Bb, &Bs[0][1][0], t1 + 1, 1); BAR(); MMQ(1, 1); BAR();
        STG(Ab, &As[0][0][0], t1 + 1, 0);
        VMC(6); BAR(); SGB0();
        LAF(1, 0); LBF(1, 0); MMQ(0, 0); BAR();
        LBF(1, 1); STG(Ab, &As[0][1][0], t1 + 1, 1); BAR(); MMQ(0, 1); BAR();
        LAF(1, 1); STG(Bb, &Bs[1][0][0], t1 + 2, 0); BAR(); MMQ(1, 0); BAR();
        STG(Bb, &Bs[1][1][0], t1 + 2, 1); BAR(); MMQ(1, 1); BAR();
    }
    {   // peeled last iteration
        STG(Ab, &As[1][0][0], nt - 1, 0);
        VMC(6); BAR(); SGB0();
        LAF(0, 0); LBF(0, 0); MMQ(0, 0); BAR();
        LBF(0, 1); STG(Ab, &As[1][1][0], nt - 1, 1); BAR(); MMQ(0, 1); BAR();
        LAF(0, 1); BAR(); MMQ(1, 0); BAR();
        BAR(); MMQ(1, 1); BAR();
        VMC(0); BAR(); SGB0();
        LAF(1, 0); LBF(1, 0); MMQ(0, 0); BAR();
        LBF(1, 1); BAR(); MMQ(0, 1); BAR();
        LAF(1, 1); BAR(); MMQ(1, 0); BAR();
        BAR(); MMQ(1, 1); BAR();
    }
#undef LAF
#undef LBF
#undef MMQ
#undef BAR
#undef VMC
#undef SGB0

#pragma unroll
    for (int mi = 0; mi < 8; ++mi)
#pragma unroll
        for (int ni = 0; ni < 4; ++ni) {
            const int colg = n0 + wc * 64 + ni * 16 + lr;
#pragma unroll
            for (int r = 0; r < 4; ++r) {
                const int rowg = m0 + wr * 128 + mi * 16 + 4 * g + r;
                epi_write<EPI>(outp, res, N, rowg, colg, acc[mi][ni][r]);
            }
        }
}

// ---------------- 2-phase 128xBN dbuf GEMM (split-K capable) ----------------
// K = loop extent per part; Kld = row stride. blockIdx.z = split-K part.
// EPI 5: store fp32 partial (part 0 -> outp, part 1 -> res cast).
template <int BM, int BN, int EPI>
__global__ __launch_bounds__(256) void gemm_bf16(
    const __bf16* __restrict__ A, const __bf16* __restrict__ Bt,
    void* __restrict__ outp, const float* __restrict__ res,
    int M, int N, int K, int Kld)
{
    __shared__ __bf16 As[2][BM * 64];
    __shared__ __bf16 Bs[2][BN * 64];
    const int tid = threadIdx.x;

    const int gx = gridDim.x, nwg = gx * gridDim.y;
    int bid = blockIdx.y * gx + blockIdx.x;
    if ((nwg & 7) == 0) bid = (bid & 7) * (nwg >> 3) + (bid >> 3);
    const int m0 = (bid / gx) * BM, n0 = (bid % gx) * BN;

    const int lane = tid & 63, w = tid >> 6;
    const int wm = w >> 1, wn = w & 1;
    const int lr = lane & 15, g = lane >> 4;
    const int srow = lane >> 3;
    const int scol = ((lane & 7) ^ srow) * 8;
    const int xr8 = lr & 7;

    constexpr int MI = BM / 32, NI = BN / 32;
    f32x4 acc[MI][NI] = {};

    const __bf16* Abase = A + (size_t)m0 * Kld + blockIdx.z * K;
    const __bf16* Bbase = Bt + (size_t)n0 * Kld + blockIdx.z * K;

    auto STAGE = [&](int kb, int buf) {
#pragma unroll
        for (int j = 0; j < BM / 32; ++j) {
            const int s = j * 4 + w;
            GLDS16(Abase + (size_t)(s * 8 + srow) * Kld + kb + scol, &As[buf][s * 512]);
        }
#pragma unroll
        for (int j = 0; j < BN / 32; ++j) {
            const int s = j * 4 + w;
            GLDS16(Bbase + (size_t)(s * 8 + srow) * Kld + kb + scol, &Bs[buf][s * 512]);
        }
    };

    const int nt = K >> 6;
    STAGE(0, 0);
    __syncthreads();

    for (int t = 0; t < nt; ++t) {
        const int cur = t & 1;
        if (t + 1 < nt) STAGE((t + 1) << 6, cur ^ 1);

        bf16x8 af[2][MI], bfr[2][NI];
#pragma unroll
        for (int kk = 0; kk < 2; ++kk) {
#pragma unroll
            for (int i = 0; i < MI; ++i)
                af[kk][i] = *(const bf16x8*)
                    &As[cur][(wm * (BM / 2) + i * 16 + lr) * 64 + (((kk * 4 + g) ^ xr8) << 3)];
#pragma unroll
            for (int i = 0; i < NI; ++i)
                bfr[kk][i] = *(const bf16x8*)
                    &Bs[cur][(wn * (BN / 2) + i * 16 + lr) * 64 + (((kk * 4 + g) ^ xr8) << 3)];
        }
#pragma unroll
        for (int kk = 0; kk < 2; ++kk)
#pragma unroll
            for (int mi = 0; mi < MI; ++mi)
#pragma unroll
                for (int ni = 0; ni < NI; ++ni)
                    acc[mi][ni] = MFMA_16x16x32_BF16(af[kk][mi], bfr[kk][ni], acc[mi][ni]);
        if (t + 1 < nt) __syncthreads();
    }

#pragma unroll
    for (int mi = 0; mi < MI; ++mi)
#pragma unroll
        for (int ni = 0; ni < NI; ++ni) {
            const int colg = n0 + wn * (BN / 2) + ni * 16 + lr;
#pragma unroll
            for (int r = 0; r < 4; ++r) {
                const int rowg = m0 + wm * (BM / 2) + mi * 16 + 4 * g + r;
                const float v = acc[mi][ni][r];
                if constexpr (EPI == 5) {
                    float* pout = (blockIdx.z == 0) ? (float*)outp : (float*)(void*)res;
                    pout[(size_t)rowg * N + colg] = v;
                } else {
                    epi_write<EPI>(outp, res, N, rowg, colg, v);
                }
            }
        }
}

// ---------------- Flash-style causal attention (2-buf + exp2, balanced) -----
__global__ __launch_bounds__(256) void attn_kernel(
    const __bf16* __restrict__ Q, const __bf16* __restrict__ Kb,
    const __bf16* __restrict__ Vt, __bf16* __restrict__ ctx)
{
    const int Dm = 1024, T = 2048;
    const int tid = threadIdx.x;
    const int w = tid >> 6, lane = tid & 63;
    const int lr = lane & 15, g = lane >> 4;
    const int bx = blockIdx.x;
    const int j = bx >> 5, bh = bx & 31, b = bh >> 4, h = bh & 15;
    const int qc = (j < 8) ? j : (j < 16) ? 39 - j : (j < 24) ? j - 8 : 47 - j;
    const int qbase = qc * 64 + w * 16;
    const size_t rowoff = (size_t)b * T;
    const __bf16* Qp = Q + rowoff * Dm + h * 64;
    const __bf16* Kp = Kb + rowoff * Dm + h * 64;
    const __bf16* Vtp = Vt + (size_t)bh * 64 * 2048;

    __shared__ __bf16 Ks[2][64 * 64];
    __shared__ __bf16 Vs[2][64 * 64];

    bf16x8 qf0 = *(const bf16x8*)&Qp[(size_t)(qbase + lr) * Dm + g * 8];
    bf16x8 qf1 = *(const bf16x8*)&Qp[(size_t)(qbase + lr) * Dm + 32 + g * 8];
    const float qsc = 0.125f * 1.44269504088896340736f;
#pragma unroll
    for (int jj = 0; jj < 8; ++jj) {
        qf0[jj] = (__bf16)((float)qf0[jj] * qsc);
        qf1[jj] = (__bf16)((float)qf1[jj] * qsc);
    }

    const int srow = lane >> 3;
    const int schunk = (lane & 7) ^ srow;

    f32x4 acc[4] = {};
    float m_s = -__builtin_inff(), l_s = 0.0f;
    const int nsteps = qc + 1;
    const f32x4 zacc = {0.0f, 0.0f, 0.0f, 0.0f};
    const int xr = (lr & 7) << 3;
    const int qg = qbase + lr;

#pragma unroll
    for (int jj = 0; jj < 2; ++jj) {
        const int row = jj * 32 + w * 8 + srow;
        GLDS16(Kp + (size_t)row * Dm + schunk * 8, &Ks[0][(jj * 32 + w * 8) * 64]);
        GLDS16(Vtp + (size_t)row * T + schunk * 8, &Vs[0][(jj * 32 + w * 8) * 64]);
    }
    __syncthreads();

    for (int t = 0; t < nsteps; ++t) {
        const int kvb = t * 64, cur = t & 1;
        if (t + 1 < nsteps) {
#pragma unroll
            for (int jj = 0; jj < 2; ++jj) {
                const int row = jj * 32 + w * 8 + srow;
                GLDS16(Kp + (size_t)(kvb + 64 + row) * Dm + schunk * 8,
                       &Ks[cur ^ 1][(jj * 32 + w * 8) * 64]);
                GLDS16(Vtp + (size_t)row * T + kvb + 64 + schunk * 8,
                       &Vs[cur ^ 1][(jj * 32 + w * 8) * 64]);
            }
        }

        float sv[4][4];
#pragma unroll
        for (int s4 = 0; s4 < 4; ++s4) {
            const int kv0 = kvb + s4 * 16;
            if (kv0 <= qbase + 15) {
                const int row = s4 * 16 + lr;
                const bf16x8 kfa = *(const bf16x8*)&Ks[cur][row * 64 + ((g * 8) ^ xr)];
                const bf16x8 kfb = *(const bf16x8*)&Ks[cur][row * 64 + ((32 + g * 8) ^ xr)];
                f32x4 st = MFMA_16x16x32_BF16(kfa, qf0, zacc);
                st = MFMA_16x16x32_BF16(kfb, qf1, st);
                const bool domask = (kv0 + 15 > qbase);
#pragma unroll
                for (int r = 0; r < 4; ++r) {
                    float x = st[r];
                    if (domask && (kv0 + 4 * g + r > qg)) x = -__builtin_inff();
                    sv[s4][r] = x;
                }
            } else {
#pragma unroll
                for (int r = 0; r < 4; ++r) sv[s4][r] = -__builtin_inff();
            }
        }

        float tm = sv[0][0];
#pragma unroll
        for (int s4 = 0; s4 < 4; ++s4)
#pragma unroll
            for (int r = 0; r < 4; ++r) tm = fmaxf(tm, sv[s4][r]);
        tm = fmaxf(tm, __shfl_xor(tm, 16));
        tm = fmaxf(tm, __shfl_xor(tm, 32));

        float m_use = m_s;
        if (!__all(tm - m_s <= 11.5f)) {
            m_use = fmaxf(m_s, tm);
            const float corr = exp2f(m_s - m_use);
            l_s *= corr;
            float cr[4];
#pragma unroll
            for (int r = 0; r < 4; ++r) cr[r] = __shfl(corr, 4 * g + r);
#pragma unroll
            for (int ct = 0; ct < 4; ++ct) {
                acc[ct][0] *= cr[0]; acc[ct][1] *= cr[1];
                acc[ct][2] *= cr[2]; acc[ct][3] *= cr[3];
            }
            m_s = m_use;
        }

        float rs = 0.0f;
#pragma unroll
        for (int s4 = 0; s4 < 4; ++s4)
#pragma unroll
            for (int r = 0; r < 4; ++r) {
                sv[s4][r] = exp2f(sv[s4][r] - m_use);
                rs += sv[s4][r];
            }
        rs += __shfl_xor(rs, 16);
        rs += __shfl_xor(rs, 32);
        l_s += rs;

        bf16x8 pa0, pa1;
#pragma unroll
        for (int r = 0; r < 4; ++r) {
            pa0[r] = (__bf16)sv[0][r];
            pa0[4 + r] = (__bf16)sv[1][r];
            pa1[r] = (__bf16)sv[2][r];
            pa1[4 + r] = (__bf16)sv[3][r];
        }
        const bool liveB = (kvb + 32 <= qbase + 15);
#pragma unroll
        for (int ct = 0; ct < 4; ++ct) {
            const __bf16* vrow = &Vs[cur][(ct * 16 + lr) * 64];
            const bf16x8 vf = *(const bf16x8*)&vrow[(8 * g) ^ xr];
            acc[ct] = MFMA_16x16x32_BF16(pa0, vf, acc[ct]);
            if (liveB) {
                const bf16x8 vf2 = *(const bf16x8*)&vrow[(32 + 8 * g) ^ xr];
                acc[ct] = MFMA_16x16x32_BF16(pa1, vf2, acc[ct]);
            }
        }
        __syncthreads();
    }

    const float il = __builtin_amdgcn_rcpf(l_s);
    float dn[4];
#pragma unroll
    for (int r = 0; r < 4; ++r) dn[r] = __shfl(il, 4 * g + r);
#pragma unroll
    for (int ct = 0; ct < 4; ++ct)
#pragma unroll
        for (int r = 0; r < 4; ++r)
            ctx[(rowoff + qbase + 4 * g + r) * Dm + h * 64 + ct * 16 + lr] =
                (__bf16)(acc[ct][r] * dn[r]);
}

// ---------------------------------------------------------------------------
extern "C" void kernel_launch(void* const* d_in, const int* in_sizes, int n_in,
                              void* d_out, int out_size, void* d_ws, size_t ws_size,
                              hipStream_t stream)
{
    (void)in_sizes; (void)n_in; (void)out_size; (void)ws_size;
    const float* z      = (const float*)d_in[0];
    const float* W_Q    = (const float*)d_in[1];
    const float* W_K    = (const float*)d_in[2];
    const float* W_V    = (const float*)d_in[3];
    const float* W_O    = (const float*)d_in[4];
    const float* W_fc   = (const float*)d_in[5];
    const float* W_proj = (const float*)d_in[6];
    const float* g1     = (const float*)d_in[7];
    const float* g2     = (const float*)d_in[8];
    float* out = (float*)d_out;

    char* ws = (char*)d_ws;
    const size_t MB = (size_t)1 << 20;
    __bf16* WtQKV  = (__bf16*)(ws + 0 * MB);   // [3072][1024]
    __bf16* WtO    = (__bf16*)(ws + 6 * MB);
    __bf16* Wtfc   = (__bf16*)(ws + 8 * MB);
    __bf16* Wtproj = (__bf16*)(ws + 16 * MB);
    __bf16* zn     = (__bf16*)(ws + 24 * MB);  // reused as ctx
    __bf16* Qb     = (__bf16*)(ws + 32 * MB);  // QKV out base; reused as h
    __bf16* Kbuf   = (__bf16*)(ws + 40 * MB);
    __bf16* Vtb    = (__bf16*)(ws + 48 * MB);
    __bf16* ffn1   = (__bf16*)(ws + 40 * MB);  // overlaps K,Vt (dead post-attn)
    float*  part0  = (float*)(ws + 0 * MB);    // 16MB: over dead WtQKV/WtO/Wtfc
    float*  part1  = (float*)(ws + 24 * MB);   // 16MB: over dead ctx + h
    __bf16* ctx    = zn;
    __bf16* hb     = Qb;

    const int Tt = 2048, Dm = 1024, Bb = 2, M = Bb * Tt, DFF = 4096;
    const dim3 blk256(256), blk512(512);

    // All weight transposes+converts in one launch
    transconv_all_kernel<<<12288, blk256, 0, stream>>>(
        W_Q, W_K, W_V, W_O, W_fc, W_proj, WtQKV, WtO, Wtfc, Wtproj);

    // zn = rmsnorm(z, g1)
    rmsnorm_kernel<<<M, blk256, 0, stream>>>(z, g1, zn);

    // Fused QKV (2-phase 128x128, 768 blocks): [4096][3072]
    gemm_bf16<128, 128, 4><<<dim3(24, 32), blk256, 0, stream>>>(
        zn, WtQKV, Qb, nullptr, M, 3072, Dm, Dm);

    // attention -> ctx
    attn_kernel<<<1024, blk256, 0, stream>>>(Qb, Kbuf, Vtb, ctx);

    // z2 = z + ctx @ W_O  -> d_out (fp32)
    gemm_bf16<128, 64, 1><<<dim3(16, 32), blk256, 0, stream>>>(
        ctx, WtO, out, z, M, Dm, Dm, Dm);

    // h = rmsnorm(z2, g2)
    rmsnorm_kernel<<<M, blk256, 0, stream>>>(out, g2, hb);

    // ffn1 = gelu_erf(h @ W_fc) (8-phase 256^2, 256 blocks = 1/CU exactly)
    gemm256<2><<<dim3(16, 16), blk512, 0, stream>>>(
        hb, Wtfc, ffn1, nullptr, M, DFF, Dm);

    // proj split-K=2 (128x128, 512 blocks): partials p0/p1
    gemm_bf16<128, 128, 5><<<dim3(8, 32, 2), blk256, 0, stream>>>(
        ffn1, Wtproj, part0, (const float*)part1, M, Dm, DFF / 2, DFF);

    // d_out += p0 + p1
    reduce_add_kernel<<<2048, blk256, 0, stream>>>(out, part0, part1, M * Dm / 4);
}

// Round 10
// 250.401 us; speedup vs baseline: 1.2613x; 1.0335x over previous
//
#include <hip/hip_runtime.h>
#include <hip/hip_bf16.h>
#include <math.h>

// ---------------------------------------------------------------------------
// GPT block on MI355X (gfx950). bf16 MFMA compute, fp32 accumulate.
// Workspace layout (MB = 1<<20), total 72 MB:
//   [ 0, 6)  WtQKV  bf16 [3072][1024]   -- dead after QKV; reused as partial0
//   [ 6, 8)  WtO    bf16 [1024][1024]
//   [ 8,16)  Wtfc   bf16 [4096][1024]
//   [16,24)  Wtproj bf16 [1024][4096]
//   [24,32)  zn / ctx   bf16            -- dead after O-proj; partial1
//   [32,40)  Q / h      bf16
//   [40,48)  K          bf16
//   [48,56)  Vt         bf16 [32][64][2048]  (V transposed, kv-permuted)
//   [40,72)  ffn1       bf16 [4096][4096]  (overlaps K,Vt — dead after attn)
// fc: 8-phase 256^2 template (reads hoisted above phase barriers).
// proj: split-K=2 into fp32 partials + reduce. attn: 8-wave shared-LDS blocks.
// ---------------------------------------------------------------------------

typedef __bf16 bf16x8 __attribute__((ext_vector_type(8)));
typedef float  f32x4  __attribute__((ext_vector_type(4)));

#define MFMA_16x16x32_BF16(A, B, C) __builtin_amdgcn_mfma_f32_16x16x32_bf16((A), (B), (C), 0, 0, 0)

#define GLDS16(g, l) __builtin_amdgcn_global_load_lds( \
    (const __attribute__((address_space(1))) void*)(g), \
    (__attribute__((address_space(3))) void*)(l), 16, 0, 0)

// ---------------- fused head: 6 weight transposes + rmsnorm(z,g1) -----------
// blocks [0,12288): transconv 32x32 tiles; [12288,16384): rmsnorm rows.
__global__ __launch_bounds__(256) void fused_head_kernel(
    const float* __restrict__ W_Q, const float* __restrict__ W_K,
    const float* __restrict__ W_V, const float* __restrict__ W_O,
    const float* __restrict__ W_fc, const float* __restrict__ W_proj,
    __bf16* __restrict__ WtQKV, __bf16* __restrict__ WtO,
    __bf16* __restrict__ Wtfc, __bf16* __restrict__ Wtproj,
    const float* __restrict__ z, const float* __restrict__ g1,
    __bf16* __restrict__ zn)
{
    const int id = blockIdx.x;
    if (id >= 12288) {
        const int row = id - 12288, t = threadIdx.x;
        const float4 v = ((const float4*)(z + (size_t)row * 1024))[t];
        float ss = v.x * v.x + v.y * v.y + v.z * v.z + v.w * v.w;
#pragma unroll
        for (int m = 1; m < 64; m <<= 1) ss += __shfl_xor(ss, m);
        __shared__ float red[4];
        const int wid = t >> 6, lane = t & 63;
        if (lane == 0) red[wid] = ss;
        __syncthreads();
        const float tot = red[0] + red[1] + red[2] + red[3];
        const float inv = rsqrtf(tot * (1.0f / 1024.0f) + 1e-5f);
        const float4 gv = ((const float4*)g1)[t];
        __bf16* o = zn + (size_t)row * 1024 + t * 4;
        o[0] = (__bf16)(v.x * inv * gv.x);
        o[1] = (__bf16)(v.y * inv * gv.y);
        o[2] = (__bf16)(v.z * inv * gv.z);
        o[3] = (__bf16)(v.w * inv * gv.w);
        return;
    }
    const float* src;
    __bf16* dst;
    int K, N, nx, t;
    if (id < 4096) {
        const int wsel = id >> 10;
        t = id & 1023;
        src = (wsel == 0) ? W_Q : (wsel == 1) ? W_K : (wsel == 2) ? W_V : W_O;
        dst = (wsel < 3) ? (WtQKV + (size_t)wsel * 1048576) : WtO;
        K = 1024; N = 1024; nx = 32;
    } else if (id < 8192) {
        t = id - 4096; src = W_fc; dst = Wtfc; K = 1024; N = 4096; nx = 128;
    } else {
        t = id - 8192; src = W_proj; dst = Wtproj; K = 4096; N = 1024; nx = 32;
    }
    const int n0 = (t % nx) * 32, k0 = (t / nx) * 32;

    __shared__ float tile[32][33];
    const int c = threadIdx.x & 31, r = threadIdx.x >> 5;
#pragma unroll
    for (int i = 0; i < 4; ++i)
        tile[r + 8 * i][c] = src[(size_t)(k0 + r + 8 * i) * N + n0 + c];
    __syncthreads();
#pragma unroll
    for (int i = 0; i < 4; ++i)
        dst[(size_t)(n0 + r + 8 * i) * K + k0 + c] = (__bf16)tile[c][r + 8 * i];
}

// ---------------- RMSNorm: fp32 [M][1024] -> bf16 [M][1024] -----------------
__global__ __launch_bounds__(256) void rmsnorm_kernel(
    const float* __restrict__ x, const float* __restrict__ gain,
    __bf16* __restrict__ out)
{
    const int row = blockIdx.x, t = threadIdx.x;
    const float4 v = ((const float4*)(x + (size_t)row * 1024))[t];
    float ss = v.x * v.x + v.y * v.y + v.z * v.z + v.w * v.w;
#pragma unroll
    for (int m = 1; m < 64; m <<= 1) ss += __shfl_xor(ss, m);
    __shared__ float red[4];
    const int wid = t >> 6, lane = t & 63;
    if (lane == 0) red[wid] = ss;
    __syncthreads();
    const float tot = red[0] + red[1] + red[2] + red[3];
    const float inv = rsqrtf(tot * (1.0f / 1024.0f) + 1e-5f);
    const float4 gv = ((const float4*)gain)[t];
    __bf16* o = out + (size_t)row * 1024 + t * 4;
    o[0] = (__bf16)(v.x * inv * gv.x);
    o[1] = (__bf16)(v.y * inv * gv.y);
    o[2] = (__bf16)(v.z * inv * gv.z);
    o[3] = (__bf16)(v.w * inv * gv.w);
}

// ---------------- reduce: out += p0 + p1 (fp32, float4 grid-stride) ---------
__global__ __launch_bounds__(256) void reduce_add_kernel(
    float* __restrict__ out, const float* __restrict__ p0,
    const float* __restrict__ p1, int n4)
{
    for (int i = blockIdx.x * 256 + threadIdx.x; i < n4; i += gridDim.x * 256) {
        const float4 a = ((const float4*)p0)[i];
        const float4 b = ((const float4*)p1)[i];
        float4 o = ((float4*)out)[i];
        o.x += a.x + b.x; o.y += a.y + b.y;
        o.z += a.z + b.z; o.w += a.w + b.w;
        ((float4*)out)[i] = o;
    }
}

// ---------------- C-write helper --------------------------------------------
template <int EPI>
__device__ __forceinline__ void epi_write(
    void* outp, const float* res, int N, int rowg, int colg, float v)
{
    if constexpr (EPI == 1) {
        const size_t idx = (size_t)rowg * N + colg;
        ((float*)outp)[idx] = res[idx] + v;
    } else if constexpr (EPI == 2) {
        // gelu, tanh form via exp2 (|diff vs erf-gelu| <~1e-3, << bf16 eps here)
        const size_t idx = (size_t)rowg * N + colg;
        const float u = v * (1.0f + 0.044715f * v * v) * 2.3022585093f;
        const float r = __builtin_amdgcn_rcpf(1.0f + exp2f(u));
        ((__bf16*)outp)[idx] = (__bf16)(v - v * r);
    } else if constexpr (EPI == 3) {
        const size_t idx = (size_t)rowg * N + colg;
        ((float*)outp)[idx] += v;
    } else {  // EPI == 4: QKV split
        __bf16* base = (__bf16*)outp;
        const int seg = colg >> 10;       // 0=Q, 1=K, 2=V
        const int cg = colg & 1023;
        if (seg < 2) {
            base[(size_t)seg * 4194304 + (size_t)rowg * 1024 + cg] = (__bf16)v;
        } else {
            // Vt[b][h][d][t'] with within-32 t-permutation: 16h+4g+j -> 8g+4h+j
            const int tt = rowg & 2047;
            const int r32 = tt & 31;
            const int p = ((r32 & 12) << 1) | ((r32 >> 2) & 4) | (r32 & 3);
            base[8388608 +
                 ((size_t)((rowg >> 11) * 16 + (cg >> 6)) * 64 + (cg & 63)) * 2048 +
                 ((tt & ~31) | p)] = (__bf16)v;
        }
    }
}

// ---------------- 8-phase 256x256 GEMM (m201 template) ----------------------
// reads hoisted above the phase-entry barrier where their data was drained
// by an earlier phase's vmcnt+barrier (p1/p2/p5/p6).
template <int EPI>
__global__ __launch_bounds__(512, 2) void gemm256(
    const __bf16* __restrict__ A, const __bf16* __restrict__ Bt,
    void* __restrict__ outp, const float* __restrict__ res,
    int M, int N, int K)
{
    __shared__ __bf16 As[2][2][128 * 64];   // [dbuf][half][row*64+elem]
    __shared__ __bf16 Bs[2][2][128 * 64];
    const int tid = threadIdx.x;

    const int gx = gridDim.x, nwg = gx * gridDim.y;
    int bid = blockIdx.y * gx + blockIdx.x;
    if ((nwg & 7) == 0) bid = (bid & 7) * (nwg >> 3) + (bid >> 3);
    const int m0 = (bid / gx) * 256, n0 = (bid % gx) * 256;

    const int lane = tid & 63, w = tid >> 6;         // 8 waves
    const int wr = w >> 2, wc = w & 3;               // 2 x 4 wave grid
    const int lr = lane & 15, g = lane >> 4;
    const int srow8 = lane >> 3, schunk = (lane & 7) ^ srow8;
    const int xk = lr & 7;
    const int wch = wc >> 1, bro = (wc & 1) * 64;    // B half / row offset

    const __bf16* Ab = A + (size_t)m0 * K;
    const __bf16* Bb = Bt + (size_t)n0 * K;

    auto STG = [&](const __bf16* gb, __bf16* lds, int kt, int half) {
        const __bf16* src = gb + (size_t)(half * 128) * K + (kt << 6);
#pragma unroll
        for (int j = 0; j < 2; ++j) {
            const int sidx = j * 8 + w;
            GLDS16(src + (size_t)(sidx * 8 + srow8) * K + schunk * 8, lds + sidx * 512);
        }
    };

    f32x4 acc[8][4] = {};
    bf16x8 af[2][4], bf[2][4];

#define LAF(BUF, QM) do {                                                       \
    _Pragma("unroll") for (int i_ = 0; i_ < 4; ++i_)                            \
    _Pragma("unroll") for (int kk_ = 0; kk_ < 2; ++kk_)                         \
        af[kk_][i_] = *(const bf16x8*)&As[BUF][wr]                              \
            [((QM) * 64 + i_ * 16 + lr) * 64 + (((kk_ * 4 + g) ^ xk) << 3)];    \
    } while (0)

#define LBF(BUF, QN) do {                                                       \
    _Pragma("unroll") for (int i_ = 0; i_ < 2; ++i_)                            \
    _Pragma("unroll") for (int kk_ = 0; kk_ < 2; ++kk_)                         \
        bf[kk_][(QN) * 2 + i_] = *(const bf16x8*)&Bs[BUF][wch]                  \
            [(bro + ((QN) * 2 + i_) * 16 + lr) * 64 + (((kk_ * 4 + g) ^ xk) << 3)]; \
    } while (0)

#define MMQ(QM, QN) do {                                                        \
    __builtin_amdgcn_s_setprio(1);                                              \
    _Pragma("unroll") for (int kk_ = 0; kk_ < 2; ++kk_)                         \
    _Pragma("unroll") for (int i_ = 0; i_ < 4; ++i_)                            \
    _Pragma("unroll") for (int n_ = 0; n_ < 2; ++n_)                            \
        acc[(QM) * 4 + i_][(QN) * 2 + n_] = MFMA_16x16x32_BF16(                 \
            af[kk_][i_], bf[kk_][(QN) * 2 + n_], acc[(QM) * 4 + i_][(QN) * 2 + n_]); \
    __builtin_amdgcn_s_setprio(0);                                              \
    } while (0)

#define BAR()  __builtin_amdgcn_s_barrier()
#define VMC(N_) asm volatile("s_waitcnt vmcnt(" #N_ ")" ::: "memory")
#define SGB0() __builtin_amdgcn_sched_barrier(0)

    const int nt = K >> 6, niter = nt >> 1;

    STG(Ab, &As[0][0][0], 0, 0); STG(Ab, &As[0][1][0], 0, 1);
    STG(Bb, &Bs[0][0][0], 0, 0); STG(Bb, &Bs[0][1][0], 0, 1);
    STG(Bb, &Bs[1][0][0], 1, 0); STG(Bb, &Bs[1][1][0], 1, 1);

    for (int i = 0; i < niter - 1; ++i) {
        const int t1 = 2 * i + 1;
        // p0 (reads must follow the vmcnt barrier: fresh drain)
        STG(Ab, &As[1][0][0], t1, 0);
        VMC(6); BAR(); SGB0();
        LAF(0, 0); LBF(0, 0); MMQ(0, 0); BAR();
        // p1 (reads pre-barrier: data drained at p0)
        LBF(0, 1); STG(Ab, &As[1][1][0], t1, 1); BAR(); MMQ(0, 1); BAR();
        // p2
        LAF(0, 1); STG(Bb, &Bs[0][0][0], t1 + 1, 0); BAR(); MMQ(1, 0); BAR();
        // p3
        STG(Bb, &Bs[0][1][0], t1 + 1, 1); BAR(); MMQ(1, 1); BAR();
        // p4
        STG(Ab, &As[0][0][0], t1 + 1, 0);
        VMC(6); BAR(); SGB0();
        LAF(1, 0); LBF(1, 0); MMQ(0, 0); BAR();
        // p5
        LBF(1, 1); STG(Ab, &As[0][1][0], t1 + 1, 1); BAR(); MMQ(0, 1); BAR();
        // p6
        LAF(1, 1); STG(Bb, &Bs[1][0][0], t1 + 2, 0); BAR(); MMQ(1, 0); BAR();
        // p7
        STG(Bb, &Bs[1][1][0], t1 + 2, 1); BAR(); MMQ(1, 1); BAR();
    }
    {   // peeled last iteration
        STG(Ab, &As[1][0][0], nt - 1, 0);
        VMC(6); BAR(); SGB0();
        LAF(0, 0); LBF(0, 0); MMQ(0, 0); BAR();
        LBF(0, 1); STG(Ab, &As[1][1][0], nt - 1, 1); BAR(); MMQ(0, 1); BAR();
        LAF(0, 1); BAR(); MMQ(1, 0); BAR();
        BAR(); MMQ(1, 1); BAR();
        VMC(0); BAR(); SGB0();
        LAF(1, 0); LBF(1, 0); MMQ(0, 0); BAR();
        LBF(1, 1); BAR(); MMQ(0, 1); BAR();
        LAF(1, 1); BAR(); MMQ(1, 0); BAR();
        BAR(); MMQ(1, 1); BAR();
    }
#undef LAF
#undef LBF
#undef MMQ
#undef BAR
#undef VMC
#undef SGB0

#pragma unroll
    for (int mi = 0; mi < 8; ++mi)
#pragma unroll
        for (int ni = 0; ni < 4; ++ni) {
            const int colg = n0 + wc * 64 + ni * 16 + lr;
#pragma unroll
            for (int r = 0; r < 4; ++r) {
                const int rowg = m0 + wr * 128 + mi * 16 + 4 * g + r;
                epi_write<EPI>(outp, res, N, rowg, colg, acc[mi][ni][r]);
            }
        }
}

// ---------------- 2-phase 128xBN dbuf GEMM (split-K capable) ----------------
template <int BM, int BN, int EPI>
__global__ __launch_bounds__(256) void gemm_bf16(
    const __bf16* __restrict__ A, const __bf16* __restrict__ Bt,
    void* __restrict__ outp, const float* __restrict__ res,
    int M, int N, int K, int Kld)
{
    __shared__ __bf16 As[2][BM * 64];
    __shared__ __bf16 Bs[2][BN * 64];
    const int tid = threadIdx.x;

    const int gx = gridDim.x, nwg = gx * gridDim.y;
    int bid = blockIdx.y * gx + blockIdx.x;
    if ((nwg & 7) == 0) bid = (bid & 7) * (nwg >> 3) + (bid >> 3);
    const int m0 = (bid / gx) * BM, n0 = (bid % gx) * BN;

    const int lane = tid & 63, w = tid >> 6;
    const int wm = w >> 1, wn = w & 1;
    const int lr = lane & 15, g = lane >> 4;
    const int srow = lane >> 3;
    const int scol = ((lane & 7) ^ srow) * 8;
    const int xr8 = lr & 7;

    constexpr int MI = BM / 32, NI = BN / 32;
    f32x4 acc[MI][NI] = {};

    const __bf16* Abase = A + (size_t)m0 * Kld + blockIdx.z * K;
    const __bf16* Bbase = Bt + (size_t)n0 * Kld + blockIdx.z * K;

    auto STAGE = [&](int kb, int buf) {
#pragma unroll
        for (int j = 0; j < BM / 32; ++j) {
            const int s = j * 4 + w;
            GLDS16(Abase + (size_t)(s * 8 + srow) * Kld + kb + scol, &As[buf][s * 512]);
        }
#pragma unroll
        for (int j = 0; j < BN / 32; ++j) {
            const int s = j * 4 + w;
            GLDS16(Bbase + (size_t)(s * 8 + srow) * Kld + kb + scol, &Bs[buf][s * 512]);
        }
    };

    const int nt = K >> 6;
    STAGE(0, 0);
    __syncthreads();

    for (int t = 0; t < nt; ++t) {
        const int cur = t & 1;
        if (t + 1 < nt) STAGE((t + 1) << 6, cur ^ 1);

        bf16x8 af[2][MI], bfr[2][NI];
#pragma unroll
        for (int kk = 0; kk < 2; ++kk) {
#pragma unroll
            for (int i = 0; i < MI; ++i)
                af[kk][i] = *(const bf16x8*)
                    &As[cur][(wm * (BM / 2) + i * 16 + lr) * 64 + (((kk * 4 + g) ^ xr8) << 3)];
#pragma unroll
            for (int i = 0; i < NI; ++i)
                bfr[kk][i] = *(const bf16x8*)
                    &Bs[cur][(wn * (BN / 2) + i * 16 + lr) * 64 + (((kk * 4 + g) ^ xr8) << 3)];
        }
#pragma unroll
        for (int kk = 0; kk < 2; ++kk)
#pragma unroll
            for (int mi = 0; mi < MI; ++mi)
#pragma unroll
                for (int ni = 0; ni < NI; ++ni)
                    acc[mi][ni] = MFMA_16x16x32_BF16(af[kk][mi], bfr[kk][ni], acc[mi][ni]);
        if (t + 1 < nt) __syncthreads();
    }

#pragma unroll
    for (int mi = 0; mi < MI; ++mi)
#pragma unroll
        for (int ni = 0; ni < NI; ++ni) {
            const int colg = n0 + wn * (BN / 2) + ni * 16 + lr;
#pragma unroll
            for (int r = 0; r < 4; ++r) {
                const int rowg = m0 + wm * (BM / 2) + mi * 16 + 4 * g + r;
                const float v = acc[mi][ni][r];
                if constexpr (EPI == 5) {
                    float* pout = (blockIdx.z == 0) ? (float*)outp : (float*)(void*)res;
                    pout[(size_t)rowg * N + colg] = v;
                } else {
                    epi_write<EPI>(outp, res, N, rowg, colg, v);
                }
            }
        }
}

// ---------------- Flash-style causal attention (8-wave shared-LDS) ----------
// Grid: 512 blocks = j*32 + bh, j in [0,16). qc = j<8 ? j : 23-j so the two
// blocks resident per CU (stride 256) have qc summing to 15 (steps sum 34).
// Block: 8 waves x 16 q-rows = 128 q-rows; one shared K/V 64-step tile.
__global__ __launch_bounds__(512) void attn_kernel(
    const __bf16* __restrict__ Q, const __bf16* __restrict__ Kb,
    const __bf16* __restrict__ Vt, __bf16* __restrict__ ctx)
{
    const int Dm = 1024, T = 2048;
    const int tid = threadIdx.x;
    const int w = tid >> 6, lane = tid & 63;
    const int lr = lane & 15, g = lane >> 4;
    const int bx = blockIdx.x;
    const int j = bx >> 5, bh = bx & 31, b = bh >> 4, h = bh & 15;
    const int qc = (j < 8) ? j : 23 - j;            // balanced bijection 0..15
    const int qbase = qc * 128 + w * 16;
    const size_t rowoff = (size_t)b * T;
    const __bf16* Qp = Q + rowoff * Dm + h * 64;
    const __bf16* Kp = Kb + rowoff * Dm + h * 64;
    const __bf16* Vtp = Vt + (size_t)bh * 64 * 2048;

    __shared__ __bf16 Ks[2][64 * 64];
    __shared__ __bf16 Vs[2][64 * 64];

    bf16x8 qf0 = *(const bf16x8*)&Qp[(size_t)(qbase + lr) * Dm + g * 8];
    bf16x8 qf1 = *(const bf16x8*)&Qp[(size_t)(qbase + lr) * Dm + 32 + g * 8];
    const float qsc = 0.125f * 1.44269504088896340736f;
#pragma unroll
    for (int jj = 0; jj < 8; ++jj) {
        qf0[jj] = (__bf16)((float)qf0[jj] * qsc);
        qf1[jj] = (__bf16)((float)qf1[jj] * qsc);
    }

    const int srow = lane >> 3;
    const int schunk = (lane & 7) ^ srow;
    const int wrow = w * 8 + srow;                  // wave w stages rows 8w..8w+7

    f32x4 acc[4] = {};
    float m_s = -__builtin_inff(), l_s = 0.0f;
    const int nsteps = 2 * qc + 2;
    const f32x4 zacc = {0.0f, 0.0f, 0.0f, 0.0f};
    const int xr = (lr & 7) << 3;
    const int qg = qbase + lr;

    GLDS16(Kp + (size_t)wrow * Dm + schunk * 8, &Ks[0][(w * 8) * 64]);
    GLDS16(Vtp + (size_t)wrow * T + schunk * 8, &Vs[0][(w * 8) * 64]);
    __syncthreads();

    for (int t = 0; t < nsteps; ++t) {
        const int kvb = t * 64, cur = t & 1;
        if (t + 1 < nsteps) {
            GLDS16(Kp + (size_t)(kvb + 64 + wrow) * Dm + schunk * 8,
                   &Ks[cur ^ 1][(w * 8) * 64]);
            GLDS16(Vtp + (size_t)wrow * T + kvb + 64 + schunk * 8,
                   &Vs[cur ^ 1][(w * 8) * 64]);
        }

        if (kvb <= qbase + 15) {  // wave-uniform: any live kv in this step
            float sv[4][4];
#pragma unroll
            for (int s4 = 0; s4 < 4; ++s4) {
                const int kv0 = kvb + s4 * 16;
                if (kv0 <= qbase + 15) {
                    const int row = s4 * 16 + lr;
                    const bf16x8 kfa = *(const bf16x8*)&Ks[cur][row * 64 + ((g * 8) ^ xr)];
                    const bf16x8 kfb = *(const bf16x8*)&Ks[cur][row * 64 + ((32 + g * 8) ^ xr)];
                    f32x4 st = MFMA_16x16x32_BF16(kfa, qf0, zacc);
                    st = MFMA_16x16x32_BF16(kfb, qf1, st);
                    const bool domask = (kv0 + 15 > qbase);
#pragma unroll
                    for (int r = 0; r < 4; ++r) {
                        float x = st[r];
                        if (domask && (kv0 + 4 * g + r > qg)) x = -__builtin_inff();
                        sv[s4][r] = x;
                    }
                } else {
#pragma unroll
                    for (int r = 0; r < 4; ++r) sv[s4][r] = -__builtin_inff();
                }
            }

            float tm = sv[0][0];
#pragma unroll
            for (int s4 = 0; s4 < 4; ++s4)
#pragma unroll
                for (int r = 0; r < 4; ++r) tm = fmaxf(tm, sv[s4][r]);
            tm = fmaxf(tm, __shfl_xor(tm, 16));
            tm = fmaxf(tm, __shfl_xor(tm, 32));

            float m_use = m_s;
            if (!__all(tm - m_s <= 11.5f)) {
                m_use = fmaxf(m_s, tm);
                const float corr = exp2f(m_s - m_use);
                l_s *= corr;
                float cr[4];
#pragma unroll
                for (int r = 0; r < 4; ++r) cr[r] = __shfl(corr, 4 * g + r);
#pragma unroll
                for (int ct = 0; ct < 4; ++ct) {
                    acc[ct][0] *= cr[0]; acc[ct][1] *= cr[1];
                    acc[ct][2] *= cr[2]; acc[ct][3] *= cr[3];
                }
                m_s = m_use;
            }

            float rs = 0.0f;
#pragma unroll
            for (int s4 = 0; s4 < 4; ++s4)
#pragma unroll
                for (int r = 0; r < 4; ++r) {
                    sv[s4][r] = exp2f(sv[s4][r] - m_use);
                    rs += sv[s4][r];
                }
            rs += __shfl_xor(rs, 16);
            rs += __shfl_xor(rs, 32);
            l_s += rs;

            bf16x8 pa0, pa1;
#pragma unroll
            for (int r = 0; r < 4; ++r) {
                pa0[r] = (__bf16)sv[0][r];
                pa0[4 + r] = (__bf16)sv[1][r];
                pa1[r] = (__bf16)sv[2][r];
                pa1[4 + r] = (__bf16)sv[3][r];
            }
            const bool liveB = (kvb + 32 <= qbase + 15);
#pragma unroll
            for (int ct = 0; ct < 4; ++ct) {
                const __bf16* vrow = &Vs[cur][(ct * 16 + lr) * 64];
                const bf16x8 vf = *(const bf16x8*)&vrow[(8 * g) ^ xr];
                acc[ct] = MFMA_16x16x32_BF16(pa0, vf, acc[ct]);
                if (liveB) {
                    const bf16x8 vf2 = *(const bf16x8*)&vrow[(32 + 8 * g) ^ xr];
                    acc[ct] = MFMA_16x16x32_BF16(pa1, vf2, acc[ct]);
                }
            }
        }
        __syncthreads();
    }

    const float il = __builtin_amdgcn_rcpf(l_s);
    float dn[4];
#pragma unroll
    for (int r = 0; r < 4; ++r) dn[r] = __shfl(il, 4 * g + r);
#pragma unroll
    for (int ct = 0; ct < 4; ++ct)
#pragma unroll
        for (int r = 0; r < 4; ++r)
            ctx[(rowoff + qbase + 4 * g + r) * Dm + h * 64 + ct * 16 + lr] =
                (__bf16)(acc[ct][r] * dn[r]);
}

// ---------------------------------------------------------------------------
extern "C" void kernel_launch(void* const* d_in, const int* in_sizes, int n_in,
                              void* d_out, int out_size, void* d_ws, size_t ws_size,
                              hipStream_t stream)
{
    (void)in_sizes; (void)n_in; (void)out_size; (void)ws_size;
    const float* z      = (const float*)d_in[0];
    const float* W_Q    = (const float*)d_in[1];
    const float* W_K    = (const float*)d_in[2];
    const float* W_V    = (const float*)d_in[3];
    const float* W_O    = (const float*)d_in[4];
    const float* W_fc   = (const float*)d_in[5];
    const float* W_proj = (const float*)d_in[6];
    const float* g1     = (const float*)d_in[7];
    const float* g2     = (const float*)d_in[8];
    float* out = (float*)d_out;

    char* ws = (char*)d_ws;
    const size_t MB = (size_t)1 << 20;
    __bf16* WtQKV  = (__bf16*)(ws + 0 * MB);   // [3072][1024]
    __bf16* WtO    = (__bf16*)(ws + 6 * MB);
    __bf16* Wtfc   = (__bf16*)(ws + 8 * MB);
    __bf16* Wtproj = (__bf16*)(ws + 16 * MB);
    __bf16* zn     = (__bf16*)(ws + 24 * MB);  // reused as ctx
    __bf16* Qb     = (__bf16*)(ws + 32 * MB);  // QKV out base; reused as h
    __bf16* Kbuf   = (__bf16*)(ws + 40 * MB);
    __bf16* Vtb    = (__bf16*)(ws + 48 * MB);
    __bf16* ffn1   = (__bf16*)(ws + 40 * MB);  // overlaps K,Vt (dead post-attn)
    float*  part0  = (float*)(ws + 0 * MB);    // 16MB: over dead WtQKV/WtO/Wtfc
    float*  part1  = (float*)(ws + 24 * MB);   // 16MB: over dead ctx + h
    __bf16* ctx    = zn;
    __bf16* hb     = Qb;

    const int Tt = 2048, Dm = 1024, Bb = 2, M = Bb * Tt, DFF = 4096;
    const dim3 blk256(256), blk512(512);

    // fused: weight transposes + rmsnorm(z, g1) -> zn
    fused_head_kernel<<<16384, blk256, 0, stream>>>(
        W_Q, W_K, W_V, W_O, W_fc, W_proj, WtQKV, WtO, Wtfc, Wtproj, z, g1, zn);

    // Fused QKV (2-phase 128x128, 768 blocks): [4096][3072]
    gemm_bf16<128, 128, 4><<<dim3(24, 32), blk256, 0, stream>>>(
        zn, WtQKV, Qb, nullptr, M, 3072, Dm, Dm);

    // attention -> ctx (8-wave blocks)
    attn_kernel<<<512, blk512, 0, stream>>>(Qb, Kbuf, Vtb, ctx);

    // z2 = z + ctx @ W_O  -> d_out (fp32)
    gemm_bf16<128, 64, 1><<<dim3(16, 32), blk256, 0, stream>>>(
        ctx, WtO, out, z, M, Dm, Dm, Dm);

    // h = rmsnorm(z2, g2)
    rmsnorm_kernel<<<M, blk256, 0, stream>>>(out, g2, hb);

    // ffn1 = gelu(h @ W_fc) (8-phase 256^2, 256 blocks = 1/CU exactly)
    gemm256<2><<<dim3(16, 16), blk512, 0, stream>>>(
        hb, Wtfc, ffn1, nullptr, M, DFF, Dm);

    // proj split-K=2 (128x128, 512 blocks): partials p0/p1
    gemm_bf16<128, 128, 5><<<dim3(8, 32, 2), blk256, 0, stream>>>(
        ffn1, Wtproj, part0, (const float*)part1, M, Dm, DFF / 2, DFF);

    // d_out += p0 + p1
    reduce_add_kernel<<<2048, blk256, 0, stream>>>(out, part0, part1, M * Dm / 4);
}

// Round 11
// 246.352 us; speedup vs baseline: 1.2820x; 1.0164x over previous
//
#include <hip/hip_runtime.h>
#include <hip/hip_bf16.h>
#include <math.h>

// ---------------------------------------------------------------------------
// GPT block on MI355X (gfx950). bf16 MFMA compute, fp32 accumulate.
// Workspace layout (MB = 1<<20), total 72 MB:
//   [ 0, 6)  WtQKV  bf16 [3072][1024]   -- dead after QKV; reused as partial0
//   [ 6, 8)  WtO    bf16 [1024][1024]
//   [ 8,16)  Wtfc   bf16 [4096][1024]
//   [16,24)  Wtproj bf16 [1024][4096]
//   [24,32)  zn / ctx   bf16            -- dead after O-proj; partial1
//   [32,40)  Q / h      bf16
//   [40,48)  K          bf16
//   [48,56)  Vt         bf16 [32][64][2048]  (V transposed, kv-permuted)
//   [40,72)  ffn1       bf16 [4096][4096]  (overlaps K,Vt — dead after attn)
// fc: 8-phase 256^2 template. proj: split-K=2 + reduce.
// attn: 8-wave blocks, KVBLK=128 (halved barrier/drain + reduce overhead).
// ---------------------------------------------------------------------------

typedef __bf16 bf16x8 __attribute__((ext_vector_type(8)));
typedef float  f32x4  __attribute__((ext_vector_type(4)));

#define MFMA_16x16x32_BF16(A, B, C) __builtin_amdgcn_mfma_f32_16x16x32_bf16((A), (B), (C), 0, 0, 0)

#define GLDS16(g, l) __builtin_amdgcn_global_load_lds( \
    (const __attribute__((address_space(1))) void*)(g), \
    (__attribute__((address_space(3))) void*)(l), 16, 0, 0)

// ---------------- fused head: 6 weight transposes + rmsnorm(z,g1) -----------
__global__ __launch_bounds__(256) void fused_head_kernel(
    const float* __restrict__ W_Q, const float* __restrict__ W_K,
    const float* __restrict__ W_V, const float* __restrict__ W_O,
    const float* __restrict__ W_fc, const float* __restrict__ W_proj,
    __bf16* __restrict__ WtQKV, __bf16* __restrict__ WtO,
    __bf16* __restrict__ Wtfc, __bf16* __restrict__ Wtproj,
    const float* __restrict__ z, const float* __restrict__ g1,
    __bf16* __restrict__ zn)
{
    const int id = blockIdx.x;
    if (id >= 12288) {
        const int row = id - 12288, t = threadIdx.x;
        const float4 v = ((const float4*)(z + (size_t)row * 1024))[t];
        float ss = v.x * v.x + v.y * v.y + v.z * v.z + v.w * v.w;
#pragma unroll
        for (int m = 1; m < 64; m <<= 1) ss += __shfl_xor(ss, m);
        __shared__ float red[4];
        const int wid = t >> 6, lane = t & 63;
        if (lane == 0) red[wid] = ss;
        __syncthreads();
        const float tot = red[0] + red[1] + red[2] + red[3];
        const float inv = rsqrtf(tot * (1.0f / 1024.0f) + 1e-5f);
        const float4 gv = ((const float4*)g1)[t];
        __bf16* o = zn + (size_t)row * 1024 + t * 4;
        o[0] = (__bf16)(v.x * inv * gv.x);
        o[1] = (__bf16)(v.y * inv * gv.y);
        o[2] = (__bf16)(v.z * inv * gv.z);
        o[3] = (__bf16)(v.w * inv * gv.w);
        return;
    }
    const float* src;
    __bf16* dst;
    int K, N, nx, t;
    if (id < 4096) {
        const int wsel = id >> 10;
        t = id & 1023;
        src = (wsel == 0) ? W_Q : (wsel == 1) ? W_K : (wsel == 2) ? W_V : W_O;
        dst = (wsel < 3) ? (WtQKV + (size_t)wsel * 1048576) : WtO;
        K = 1024; N = 1024; nx = 32;
    } else if (id < 8192) {
        t = id - 4096; src = W_fc; dst = Wtfc; K = 1024; N = 4096; nx = 128;
    } else {
        t = id - 8192; src = W_proj; dst = Wtproj; K = 4096; N = 1024; nx = 32;
    }
    const int n0 = (t % nx) * 32, k0 = (t / nx) * 32;

    __shared__ float tile[32][33];
    const int c = threadIdx.x & 31, r = threadIdx.x >> 5;
#pragma unroll
    for (int i = 0; i < 4; ++i)
        tile[r + 8 * i][c] = src[(size_t)(k0 + r + 8 * i) * N + n0 + c];
    __syncthreads();
#pragma unroll
    for (int i = 0; i < 4; ++i)
        dst[(size_t)(n0 + r + 8 * i) * K + k0 + c] = (__bf16)tile[c][r + 8 * i];
}

// ---------------- RMSNorm: fp32 [M][1024] -> bf16 [M][1024] -----------------
__global__ __launch_bounds__(256) void rmsnorm_kernel(
    const float* __restrict__ x, const float* __restrict__ gain,
    __bf16* __restrict__ out)
{
    const int row = blockIdx.x, t = threadIdx.x;
    const float4 v = ((const float4*)(x + (size_t)row * 1024))[t];
    float ss = v.x * v.x + v.y * v.y + v.z * v.z + v.w * v.w;
#pragma unroll
    for (int m = 1; m < 64; m <<= 1) ss += __shfl_xor(ss, m);
    __shared__ float red[4];
    const int wid = t >> 6, lane = t & 63;
    if (lane == 0) red[wid] = ss;
    __syncthreads();
    const float tot = red[0] + red[1] + red[2] + red[3];
    const float inv = rsqrtf(tot * (1.0f / 1024.0f) + 1e-5f);
    const float4 gv = ((const float4*)gain)[t];
    __bf16* o = out + (size_t)row * 1024 + t * 4;
    o[0] = (__bf16)(v.x * inv * gv.x);
    o[1] = (__bf16)(v.y * inv * gv.y);
    o[2] = (__bf16)(v.z * inv * gv.z);
    o[3] = (__bf16)(v.w * inv * gv.w);
}

// ---------------- reduce: out += p0 + p1 (fp32, float4 grid-stride) ---------
__global__ __launch_bounds__(256) void reduce_add_kernel(
    float* __restrict__ out, const float* __restrict__ p0,
    const float* __restrict__ p1, int n4)
{
    for (int i = blockIdx.x * 256 + threadIdx.x; i < n4; i += gridDim.x * 256) {
        const float4 a = ((const float4*)p0)[i];
        const float4 b = ((const float4*)p1)[i];
        float4 o = ((float4*)out)[i];
        o.x += a.x + b.x; o.y += a.y + b.y;
        o.z += a.z + b.z; o.w += a.w + b.w;
        ((float4*)out)[i] = o;
    }
}

// ---------------- C-write helper --------------------------------------------
template <int EPI>
__device__ __forceinline__ void epi_write(
    void* outp, const float* res, int N, int rowg, int colg, float v)
{
    if constexpr (EPI == 1) {
        const size_t idx = (size_t)rowg * N + colg;
        ((float*)outp)[idx] = res[idx] + v;
    } else if constexpr (EPI == 2) {
        // gelu, tanh form via exp2 (|diff vs erf-gelu| <~1e-3, << bf16 eps here)
        const size_t idx = (size_t)rowg * N + colg;
        const float u = v * (1.0f + 0.044715f * v * v) * 2.3022585093f;
        const float r = __builtin_amdgcn_rcpf(1.0f + exp2f(u));
        ((__bf16*)outp)[idx] = (__bf16)(v - v * r);
    } else if constexpr (EPI == 3) {
        const size_t idx = (size_t)rowg * N + colg;
        ((float*)outp)[idx] += v;
    } else {  // EPI == 4: QKV split
        __bf16* base = (__bf16*)outp;
        const int seg = colg >> 10;       // 0=Q, 1=K, 2=V
        const int cg = colg & 1023;
        if (seg < 2) {
            base[(size_t)seg * 4194304 + (size_t)rowg * 1024 + cg] = (__bf16)v;
        } else {
            // Vt[b][h][d][t'] with within-32 t-permutation: 16h+4g+j -> 8g+4h+j
            const int tt = rowg & 2047;
            const int r32 = tt & 31;
            const int p = ((r32 & 12) << 1) | ((r32 >> 2) & 4) | (r32 & 3);
            base[8388608 +
                 ((size_t)((rowg >> 11) * 16 + (cg >> 6)) * 64 + (cg & 63)) * 2048 +
                 ((tt & ~31) | p)] = (__bf16)v;
        }
    }
}

// ---------------- 8-phase 256x256 GEMM (m201 template) ----------------------
template <int EPI>
__global__ __launch_bounds__(512, 2) void gemm256(
    const __bf16* __restrict__ A, const __bf16* __restrict__ Bt,
    void* __restrict__ outp, const float* __restrict__ res,
    int M, int N, int K)
{
    __shared__ __bf16 As[2][2][128 * 64];   // [dbuf][half][row*64+elem]
    __shared__ __bf16 Bs[2][2][128 * 64];
    const int tid = threadIdx.x;

    const int gx = gridDim.x, nwg = gx * gridDim.y;
    int bid = blockIdx.y * gx + blockIdx.x;
    if ((nwg & 7) == 0) bid = (bid & 7) * (nwg >> 3) + (bid >> 3);
    const int m0 = (bid / gx) * 256, n0 = (bid % gx) * 256;

    const int lane = tid & 63, w = tid >> 6;         // 8 waves
    const int wr = w >> 2, wc = w & 3;               // 2 x 4 wave grid
    const int lr = lane & 15, g = lane >> 4;
    const int srow8 = lane >> 3, schunk = (lane & 7) ^ srow8;
    const int xk = lr & 7;
    const int wch = wc >> 1, bro = (wc & 1) * 64;    // B half / row offset

    const __bf16* Ab = A + (size_t)m0 * K;
    const __bf16* Bb = Bt + (size_t)n0 * K;

    auto STG = [&](const __bf16* gb, __bf16* lds, int kt, int half) {
        const __bf16* src = gb + (size_t)(half * 128) * K + (kt << 6);
#pragma unroll
        for (int j = 0; j < 2; ++j) {
            const int sidx = j * 8 + w;
            GLDS16(src + (size_t)(sidx * 8 + srow8) * K + schunk * 8, lds + sidx * 512);
        }
    };

    f32x4 acc[8][4] = {};
    bf16x8 af[2][4], bf[2][4];

#define LAF(BUF, QM) do {                                                       \
    _Pragma("unroll") for (int i_ = 0; i_ < 4; ++i_)                            \
    _Pragma("unroll") for (int kk_ = 0; kk_ < 2; ++kk_)                         \
        af[kk_][i_] = *(const bf16x8*)&As[BUF][wr]                              \
            [((QM) * 64 + i_ * 16 + lr) * 64 + (((kk_ * 4 + g) ^ xk) << 3)];    \
    } while (0)

#define LBF(BUF, QN) do {                                                       \
    _Pragma("unroll") for (int i_ = 0; i_ < 2; ++i_)                            \
    _Pragma("unroll") for (int kk_ = 0; kk_ < 2; ++kk_)                         \
        bf[kk_][(QN) * 2 + i_] = *(const bf16x8*)&Bs[BUF][wch]                  \
            [(bro + ((QN) * 2 + i_) * 16 + lr) * 64 + (((kk_ * 4 + g) ^ xk) << 3)]; \
    } while (0)

#define MMQ(QM, QN) do {                                                        \
    __builtin_amdgcn_s_setprio(1);                                              \
    _Pragma("unroll") for (int kk_ = 0; kk_ < 2; ++kk_)                         \
    _Pragma("unroll") for (int i_ = 0; i_ < 4; ++i_)                            \
    _Pragma("unroll") for (int n_ = 0; n_ < 2; ++n_)                            \
        acc[(QM) * 4 + i_][(QN) * 2 + n_] = MFMA_16x16x32_BF16(                 \
            af[kk_][i_], bf[kk_][(QN) * 2 + n_], acc[(QM) * 4 + i_][(QN) * 2 + n_]); \
    __builtin_amdgcn_s_setprio(0);                                              \
    } while (0)

#define BAR()  __builtin_amdgcn_s_barrier()
#define VMC(N_) asm volatile("s_waitcnt vmcnt(" #N_ ")" ::: "memory")
#define SGB0() __builtin_amdgcn_sched_barrier(0)

    const int nt = K >> 6, niter = nt >> 1;

    STG(Ab, &As[0][0][0], 0, 0); STG(Ab, &As[0][1][0], 0, 1);
    STG(Bb, &Bs[0][0][0], 0, 0); STG(Bb, &Bs[0][1][0], 0, 1);
    STG(Bb, &Bs[1][0][0], 1, 0); STG(Bb, &Bs[1][1][0], 1, 1);

    for (int i = 0; i < niter - 1; ++i) {
        const int t1 = 2 * i + 1;
        STG(Ab, &As[1][0][0], t1, 0);
        VMC(6); BAR(); SGB0();
        LAF(0, 0); LBF(0, 0); MMQ(0, 0); BAR();
        LBF(0, 1); STG(Ab, &As[1][1][0], t1, 1); BAR(); MMQ(0, 1); BAR();
        LAF(0, 1); STG(Bb, &Bs[0][0][0], t1 + 1, 0); BAR(); MMQ(1, 0); BAR();
        STG(Bb, &Bs[0][1][0], t1 + 1, 1); BAR(); MMQ(1, 1); BAR();
        STG(Ab, &As[0][0][0], t1 + 1, 0);
        VMC(6); BAR(); SGB0();
        LAF(1, 0); LBF(1, 0); MMQ(0, 0); BAR();
        LBF(1, 1); STG(Ab, &As[0][1][0], t1 + 1, 1); BAR(); MMQ(0, 1); BAR();
        LAF(1, 1); STG(Bb, &Bs[1][0][0], t1 + 2, 0); BAR(); MMQ(1, 0); BAR();
        STG(Bb, &Bs[1][1][0], t1 + 2, 1); BAR(); MMQ(1, 1); BAR();
    }
    {   // peeled last iteration
        STG(Ab, &As[1][0][0], nt - 1, 0);
        VMC(6); BAR(); SGB0();
        LAF(0, 0); LBF(0, 0); MMQ(0, 0); BAR();
        LBF(0, 1); STG(Ab, &As[1][1][0], nt - 1, 1); BAR(); MMQ(0, 1); BAR();
        LAF(0, 1); BAR(); MMQ(1, 0); BAR();
        BAR(); MMQ(1, 1); BAR();
        VMC(0); BAR(); SGB0();
        LAF(1, 0); LBF(1, 0); MMQ(0, 0); BAR();
        LBF(1, 1); BAR(); MMQ(0, 1); BAR();
        LAF(1, 1); BAR(); MMQ(1, 0); BAR();
        BAR(); MMQ(1, 1); BAR();
    }
#undef LAF
#undef LBF
#undef MMQ
#undef BAR
#undef VMC
#undef SGB0

#pragma unroll
    for (int mi = 0; mi < 8; ++mi)
#pragma unroll
        for (int ni = 0; ni < 4; ++ni) {
            const int colg = n0 + wc * 64 + ni * 16 + lr;
#pragma unroll
            for (int r = 0; r < 4; ++r) {
                const int rowg = m0 + wr * 128 + mi * 16 + 4 * g + r;
                epi_write<EPI>(outp, res, N, rowg, colg, acc[mi][ni][r]);
            }
        }
}

// ---------------- 2-phase 128xBN dbuf GEMM (split-K capable) ----------------
template <int BM, int BN, int EPI>
__global__ __launch_bounds__(256) void gemm_bf16(
    const __bf16* __restrict__ A, const __bf16* __restrict__ Bt,
    void* __restrict__ outp, const float* __restrict__ res,
    int M, int N, int K, int Kld)
{
    __shared__ __bf16 As[2][BM * 64];
    __shared__ __bf16 Bs[2][BN * 64];
    const int tid = threadIdx.x;

    const int gx = gridDim.x, nwg = gx * gridDim.y;
    int bid = blockIdx.y * gx + blockIdx.x;
    if ((nwg & 7) == 0) bid = (bid & 7) * (nwg >> 3) + (bid >> 3);
    const int m0 = (bid / gx) * BM, n0 = (bid % gx) * BN;

    const int lane = tid & 63, w = tid >> 6;
    const int wm = w >> 1, wn = w & 1;
    const int lr = lane & 15, g = lane >> 4;
    const int srow = lane >> 3;
    const int scol = ((lane & 7) ^ srow) * 8;
    const int xr8 = lr & 7;

    constexpr int MI = BM / 32, NI = BN / 32;
    f32x4 acc[MI][NI] = {};

    const __bf16* Abase = A + (size_t)m0 * Kld + blockIdx.z * K;
    const __bf16* Bbase = Bt + (size_t)n0 * Kld + blockIdx.z * K;

    auto STAGE = [&](int kb, int buf) {
#pragma unroll
        for (int j = 0; j < BM / 32; ++j) {
            const int s = j * 4 + w;
            GLDS16(Abase + (size_t)(s * 8 + srow) * Kld + kb + scol, &As[buf][s * 512]);
        }
#pragma unroll
        for (int j = 0; j < BN / 32; ++j) {
            const int s = j * 4 + w;
            GLDS16(Bbase + (size_t)(s * 8 + srow) * Kld + kb + scol, &Bs[buf][s * 512]);
        }
    };

    const int nt = K >> 6;
    STAGE(0, 0);
    __syncthreads();

    for (int t = 0; t < nt; ++t) {
        const int cur = t & 1;
        if (t + 1 < nt) STAGE((t + 1) << 6, cur ^ 1);

        bf16x8 af[2][MI], bfr[2][NI];
#pragma unroll
        for (int kk = 0; kk < 2; ++kk) {
#pragma unroll
            for (int i = 0; i < MI; ++i)
                af[kk][i] = *(const bf16x8*)
                    &As[cur][(wm * (BM / 2) + i * 16 + lr) * 64 + (((kk * 4 + g) ^ xr8) << 3)];
#pragma unroll
            for (int i = 0; i < NI; ++i)
                bfr[kk][i] = *(const bf16x8*)
                    &Bs[cur][(wn * (BN / 2) + i * 16 + lr) * 64 + (((kk * 4 + g) ^ xr8) << 3)];
        }
#pragma unroll
        for (int kk = 0; kk < 2; ++kk)
#pragma unroll
            for (int mi = 0; mi < MI; ++mi)
#pragma unroll
                for (int ni = 0; ni < NI; ++ni)
                    acc[mi][ni] = MFMA_16x16x32_BF16(af[kk][mi], bfr[kk][ni], acc[mi][ni]);
        if (t + 1 < nt) __syncthreads();
    }

#pragma unroll
    for (int mi = 0; mi < MI; ++mi)
#pragma unroll
        for (int ni = 0; ni < NI; ++ni) {
            const int colg = n0 + wn * (BN / 2) + ni * 16 + lr;
#pragma unroll
            for (int r = 0; r < 4; ++r) {
                const int rowg = m0 + wm * (BM / 2) + mi * 16 + 4 * g + r;
                const float v = acc[mi][ni][r];
                if constexpr (EPI == 5) {
                    float* pout = (blockIdx.z == 0) ? (float*)outp : (float*)(void*)res;
                    pout[(size_t)rowg * N + colg] = v;
                } else {
                    epi_write<EPI>(outp, res, N, rowg, colg, v);
                }
            }
        }
}

// ---------------- Flash-style causal attention (8-wave, KVBLK=128) ----------
// Grid: 512 blocks = j*32 + bh, j in [0,16). qc = j<8 ? j : 23-j (balanced).
// Block: 8 waves x 16 q-rows = 128 q-rows; KV steps of 128 (2-buf, 64KB LDS).
// K tile [128 t][64 d] w/ 8-chunk XOR swizzle; V tile [64 d][128 t] w/
// 16-chunk XOR swizzle (read rows = lr -> <=2-way bank aliasing, free).
__global__ __launch_bounds__(512) void attn_kernel(
    const __bf16* __restrict__ Q, const __bf16* __restrict__ Kb,
    const __bf16* __restrict__ Vt, __bf16* __restrict__ ctx)
{
    const int Dm = 1024, T = 2048;
    const int tid = threadIdx.x;
    const int w = tid >> 6, lane = tid & 63;
    const int lr = lane & 15, g = lane >> 4;
    const int bx = blockIdx.x;
    const int j = bx >> 5, bh = bx & 31, b = bh >> 4, h = bh & 15;
    const int qc = (j < 8) ? j : 23 - j;            // balanced bijection 0..15
    const int qbase = qc * 128 + w * 16;
    const size_t rowoff = (size_t)b * T;
    const __bf16* Qp = Q + rowoff * Dm + h * 64;
    const __bf16* Kp = Kb + rowoff * Dm + h * 64;
    const __bf16* Vtp = Vt + (size_t)bh * 64 * 2048;

    __shared__ __bf16 Ks[2][128 * 64];
    __shared__ __bf16 Vs[2][64 * 128];

    bf16x8 qf0 = *(const bf16x8*)&Qp[(size_t)(qbase + lr) * Dm + g * 8];
    bf16x8 qf1 = *(const bf16x8*)&Qp[(size_t)(qbase + lr) * Dm + 32 + g * 8];
    const float qsc = 0.125f * 1.44269504088896340736f;
#pragma unroll
    for (int jj = 0; jj < 8; ++jj) {
        qf0[jj] = (__bf16)((float)qf0[jj] * qsc);
        qf1[jj] = (__bf16)((float)qf1[jj] * qsc);
    }

    // K staging: wave w stages rows w*16 + j8*8 (+ lane>>3); chunk8 XOR row&7
    const int ksrow = lane >> 3;
    const int kschunk = (lane & 7) ^ ksrow;
    // V staging: wave w stages rows w*8 + j4*4 (+ lane>>4); chunk16 XOR row&15
    const int vsrow = lane >> 4;                    // 0..3

    f32x4 acc[4] = {};
    float m_s = -__builtin_inff(), l_s = 0.0f;
    const int nsteps = qc + 1;
    const f32x4 zacc = {0.0f, 0.0f, 0.0f, 0.0f};
    const int x8 = lr & 7;                          // K read chunk XOR
    const int qg = qbase + lr;

    auto STAGE = [&](int kvb, int buf) {
#pragma unroll
        for (int jj = 0; jj < 2; ++jj) {
            const int krow = w * 16 + jj * 8;
            GLDS16(Kp + (size_t)(kvb + krow + ksrow) * Dm + kschunk * 8,
                   &Ks[buf][krow * 64]);
            const int vrow = w * 8 + jj * 4;
            const int vchunk = (lane & 15) ^ ((vrow + vsrow) & 15);
            GLDS16(Vtp + (size_t)(vrow + vsrow) * T + kvb + vchunk * 8,
                   &Vs[buf][vrow * 128]);
        }
    };

    STAGE(0, 0);
    __syncthreads();

    for (int t = 0; t < nsteps; ++t) {
        const int kvb = t * 128, cur = t & 1;
        if (t + 1 < nsteps) STAGE(kvb + 128, cur ^ 1);

        // ---- QK^T: eight 16-kv sub-tiles (Q pre-scaled, log2 domain) ----
        float sv[8][4];
#pragma unroll
        for (int s4 = 0; s4 < 8; ++s4) {
            const int kv0 = kvb + s4 * 16;
            if (kv0 <= qbase + 15) {
                const int row = s4 * 16 + lr;
                const bf16x8 kfa = *(const bf16x8*)&Ks[cur][row * 64 + ((g ^ x8) << 3)];
                const bf16x8 kfb = *(const bf16x8*)&Ks[cur][row * 64 + (((4 + g) ^ x8) << 3)];
                f32x4 st = MFMA_16x16x32_BF16(kfa, qf0, zacc);
                st = MFMA_16x16x32_BF16(kfb, qf1, st);
                const bool domask = (kv0 + 15 > qbase);
#pragma unroll
                for (int r = 0; r < 4; ++r) {
                    float x = st[r];
                    if (domask && (kv0 + 4 * g + r > qg)) x = -__builtin_inff();
                    sv[s4][r] = x;
                }
            } else {
#pragma unroll
                for (int r = 0; r < 4; ++r) sv[s4][r] = -__builtin_inff();
            }
        }

        // ---- online softmax (log2 domain) with defer-rescale ----
        float tm = sv[0][0];
#pragma unroll
        for (int s4 = 0; s4 < 8; ++s4)
#pragma unroll
            for (int r = 0; r < 4; ++r) tm = fmaxf(tm, sv[s4][r]);
        tm = fmaxf(tm, __shfl_xor(tm, 16));
        tm = fmaxf(tm, __shfl_xor(tm, 32));

        float m_use = m_s;
        if (!__all(tm - m_s <= 11.5f)) {
            m_use = fmaxf(m_s, tm);
            const float corr = exp2f(m_s - m_use);
            l_s *= corr;
            float cr[4];
#pragma unroll
            for (int r = 0; r < 4; ++r) cr[r] = __shfl(corr, 4 * g + r);
#pragma unroll
            for (int ct = 0; ct < 4; ++ct) {
                acc[ct][0] *= cr[0]; acc[ct][1] *= cr[1];
                acc[ct][2] *= cr[2]; acc[ct][3] *= cr[3];
            }
            m_s = m_use;
        }

        float rs = 0.0f;
#pragma unroll
        for (int s4 = 0; s4 < 8; ++s4)
#pragma unroll
            for (int r = 0; r < 4; ++r) {
                sv[s4][r] = exp2f(sv[s4][r] - m_use);
                rs += sv[s4][r];
            }
        rs += __shfl_xor(rs, 16);
        rs += __shfl_xor(rs, 32);
        l_s += rs;

        // ---- PV: 4 sub-32 groups, single 16B V fragments ----
        bf16x8 pa[4];
#pragma unroll
        for (int s = 0; s < 4; ++s)
#pragma unroll
            for (int r = 0; r < 4; ++r) {
                pa[s][r] = (__bf16)sv[2 * s][r];
                pa[s][4 + r] = (__bf16)sv[2 * s + 1][r];
            }
#pragma unroll
        for (int ct = 0; ct < 4; ++ct) {
            const __bf16* vrow = &Vs[cur][(ct * 16 + lr) * 128];
#pragma unroll
            for (int s = 0; s < 4; ++s) {
                if (kvb + s * 32 <= qbase + 15) {
                    const bf16x8 vf =
                        *(const bf16x8*)&vrow[(((s * 4 + g) ^ lr) << 3)];
                    acc[ct] = MFMA_16x16x32_BF16(pa[s], vf, acc[ct]);
                }
            }
        }
        __syncthreads();
    }

    const float il = __builtin_amdgcn_rcpf(l_s);
    float dn[4];
#pragma unroll
    for (int r = 0; r < 4; ++r) dn[r] = __shfl(il, 4 * g + r);
#pragma unroll
    for (int ct = 0; ct < 4; ++ct)
#pragma unroll
        for (int r = 0; r < 4; ++r)
            ctx[(rowoff + qbase + 4 * g + r) * Dm + h * 64 + ct * 16 + lr] =
                (__bf16)(acc[ct][r] * dn[r]);
}

// ---------------------------------------------------------------------------
extern "C" void kernel_launch(void* const* d_in, const int* in_sizes, int n_in,
                              void* d_out, int out_size, void* d_ws, size_t ws_size,
                              hipStream_t stream)
{
    (void)in_sizes; (void)n_in; (void)out_size; (void)ws_size;
    const float* z      = (const float*)d_in[0];
    const float* W_Q    = (const float*)d_in[1];
    const float* W_K    = (const float*)d_in[2];
    const float* W_V    = (const float*)d_in[3];
    const float* W_O    = (const float*)d_in[4];
    const float* W_fc   = (const float*)d_in[5];
    const float* W_proj = (const float*)d_in[6];
    const float* g1     = (const float*)d_in[7];
    const float* g2     = (const float*)d_in[8];
    float* out = (float*)d_out;

    char* ws = (char*)d_ws;
    const size_t MB = (size_t)1 << 20;
    __bf16* WtQKV  = (__bf16*)(ws + 0 * MB);   // [3072][1024]
    __bf16* WtO    = (__bf16*)(ws + 6 * MB);
    __bf16* Wtfc   = (__bf16*)(ws + 8 * MB);
    __bf16* Wtproj = (__bf16*)(ws + 16 * MB);
    __bf16* zn     = (__bf16*)(ws + 24 * MB);  // reused as ctx
    __bf16* Qb     = (__bf16*)(ws + 32 * MB);  // QKV out base; reused as h
    __bf16* Kbuf   = (__bf16*)(ws + 40 * MB);
    __bf16* Vtb    = (__bf16*)(ws + 48 * MB);
    __bf16* ffn1   = (__bf16*)(ws + 40 * MB);  // overlaps K,Vt (dead post-attn)
    float*  part0  = (float*)(ws + 0 * MB);    // 16MB: over dead WtQKV/WtO/Wtfc
    float*  part1  = (float*)(ws + 24 * MB);   // 16MB: over dead ctx + h
    __bf16* ctx    = zn;
    __bf16* hb     = Qb;

    const int Tt = 2048, Dm = 1024, Bb = 2, M = Bb * Tt, DFF = 4096;
    const dim3 blk256(256), blk512(512);

    // fused: weight transposes + rmsnorm(z, g1) -> zn
    fused_head_kernel<<<16384, blk256, 0, stream>>>(
        W_Q, W_K, W_V, W_O, W_fc, W_proj, WtQKV, WtO, Wtfc, Wtproj, z, g1, zn);

    // Fused QKV (2-phase 128x128, 768 blocks): [4096][3072]
    gemm_bf16<128, 128, 4><<<dim3(24, 32), blk256, 0, stream>>>(
        zn, WtQKV, Qb, nullptr, M, 3072, Dm, Dm);

    // attention -> ctx (8-wave blocks, KVBLK=128)
    attn_kernel<<<512, blk512, 0, stream>>>(Qb, Kbuf, Vtb, ctx);

    // z2 = z + ctx @ W_O  -> d_out (fp32)
    gemm_bf16<128, 64, 1><<<dim3(16, 32), blk256, 0, stream>>>(
        ctx, WtO, out, z, M, Dm, Dm, Dm);

    // h = rmsnorm(z2, g2)
    rmsnorm_kernel<<<M, blk256, 0, stream>>>(out, g2, hb);

    // ffn1 = gelu(h @ W_fc) (8-phase 256^2, 256 blocks = 1/CU exactly)
    gemm256<2><<<dim3(16, 16), blk512, 0, stream>>>(
        hb, Wtfc, ffn1, nullptr, M, DFF, Dm);

    // proj split-K=2 (128x128, 512 blocks): partials p0/p1
    gemm_bf16<128, 128, 5><<<dim3(8, 32, 2), blk256, 0, stream>>>(
        ffn1, Wtproj, part0, (const float*)part1, M, Dm, DFF / 2, DFF);

    // d_out += p0 + p1
    reduce_add_kernel<<<2048, blk256, 0, stream>>>(out, part0, part1, M * Dm / 4);
}

// Round 12
// 246.060 us; speedup vs baseline: 1.2835x; 1.0012x over previous
//
#include <hip/hip_runtime.h>
#include <hip/hip_bf16.h>
#include <math.h>

// ---------------------------------------------------------------------------
// GPT block on MI355X (gfx950). bf16 MFMA compute, fp32 accumulate.
// Workspace layout (MB = 1<<20), total 72 MB:
//   [ 0, 6)  WtQKV  bf16 [3072][1024]
//   [ 6, 8)  WtO    bf16 [1024][1024]
//   [ 8,16)  Wtfc   bf16 [4096][1024]
//   [16,24)  Wtproj bf16 [1024][4096]
//   [24,32)  zn / ctx   bf16
//   [32,40)  Q / h      bf16
//   [40,48)  K          bf16
//   [48,56)  Vt         bf16 [32][64][2048]  (V transposed, kv-permuted)
//   [40,72)  ffn1       bf16 [4096][4096]  (overlaps K,Vt — dead after attn)
// fc: 8-phase 256^2 template. proj: split-K=2, parts atomicAdd into out
// (out = z2 rewritten by O-proj each launch -> replay-safe).
// attn: 8-wave blocks, KVBLK=128, block-uniform FULL fast path for t<qc.
// ---------------------------------------------------------------------------

typedef __bf16 bf16x8 __attribute__((ext_vector_type(8)));
typedef float  f32x4  __attribute__((ext_vector_type(4)));

#define MFMA_16x16x32_BF16(A, B, C) __builtin_amdgcn_mfma_f32_16x16x32_bf16((A), (B), (C), 0, 0, 0)

#define GLDS16(g, l) __builtin_amdgcn_global_load_lds( \
    (const __attribute__((address_space(1))) void*)(g), \
    (__attribute__((address_space(3))) void*)(l), 16, 0, 0)

// ---------------- fused head: 6 weight transposes + rmsnorm(z,g1) -----------
__global__ __launch_bounds__(256) void fused_head_kernel(
    const float* __restrict__ W_Q, const float* __restrict__ W_K,
    const float* __restrict__ W_V, const float* __restrict__ W_O,
    const float* __restrict__ W_fc, const float* __restrict__ W_proj,
    __bf16* __restrict__ WtQKV, __bf16* __restrict__ WtO,
    __bf16* __restrict__ Wtfc, __bf16* __restrict__ Wtproj,
    const float* __restrict__ z, const float* __restrict__ g1,
    __bf16* __restrict__ zn)
{
    const int id = blockIdx.x;
    if (id >= 12288) {
        const int row = id - 12288, t = threadIdx.x;
        const float4 v = ((const float4*)(z + (size_t)row * 1024))[t];
        float ss = v.x * v.x + v.y * v.y + v.z * v.z + v.w * v.w;
#pragma unroll
        for (int m = 1; m < 64; m <<= 1) ss += __shfl_xor(ss, m);
        __shared__ float red[4];
        const int wid = t >> 6, lane = t & 63;
        if (lane == 0) red[wid] = ss;
        __syncthreads();
        const float tot = red[0] + red[1] + red[2] + red[3];
        const float inv = rsqrtf(tot * (1.0f / 1024.0f) + 1e-5f);
        const float4 gv = ((const float4*)g1)[t];
        __bf16* o = zn + (size_t)row * 1024 + t * 4;
        o[0] = (__bf16)(v.x * inv * gv.x);
        o[1] = (__bf16)(v.y * inv * gv.y);
        o[2] = (__bf16)(v.z * inv * gv.z);
        o[3] = (__bf16)(v.w * inv * gv.w);
        return;
    }
    const float* src;
    __bf16* dst;
    int K, N, nx, t;
    if (id < 4096) {
        const int wsel = id >> 10;
        t = id & 1023;
        src = (wsel == 0) ? W_Q : (wsel == 1) ? W_K : (wsel == 2) ? W_V : W_O;
        dst = (wsel < 3) ? (WtQKV + (size_t)wsel * 1048576) : WtO;
        K = 1024; N = 1024; nx = 32;
    } else if (id < 8192) {
        t = id - 4096; src = W_fc; dst = Wtfc; K = 1024; N = 4096; nx = 128;
    } else {
        t = id - 8192; src = W_proj; dst = Wtproj; K = 4096; N = 1024; nx = 32;
    }
    const int n0 = (t % nx) * 32, k0 = (t / nx) * 32;

    __shared__ float tile[32][33];
    const int c = threadIdx.x & 31, r = threadIdx.x >> 5;
#pragma unroll
    for (int i = 0; i < 4; ++i)
        tile[r + 8 * i][c] = src[(size_t)(k0 + r + 8 * i) * N + n0 + c];
    __syncthreads();
#pragma unroll
    for (int i = 0; i < 4; ++i)
        dst[(size_t)(n0 + r + 8 * i) * K + k0 + c] = (__bf16)tile[c][r + 8 * i];
}

// ---------------- RMSNorm: fp32 [M][1024] -> bf16 [M][1024] -----------------
__global__ __launch_bounds__(256) void rmsnorm_kernel(
    const float* __restrict__ x, const float* __restrict__ gain,
    __bf16* __restrict__ out)
{
    const int row = blockIdx.x, t = threadIdx.x;
    const float4 v = ((const float4*)(x + (size_t)row * 1024))[t];
    float ss = v.x * v.x + v.y * v.y + v.z * v.z + v.w * v.w;
#pragma unroll
    for (int m = 1; m < 64; m <<= 1) ss += __shfl_xor(ss, m);
    __shared__ float red[4];
    const int wid = t >> 6, lane = t & 63;
    if (lane == 0) red[wid] = ss;
    __syncthreads();
    const float tot = red[0] + red[1] + red[2] + red[3];
    const float inv = rsqrtf(tot * (1.0f / 1024.0f) + 1e-5f);
    const float4 gv = ((const float4*)gain)[t];
    __bf16* o = out + (size_t)row * 1024 + t * 4;
    o[0] = (__bf16)(v.x * inv * gv.x);
    o[1] = (__bf16)(v.y * inv * gv.y);
    o[2] = (__bf16)(v.z * inv * gv.z);
    o[3] = (__bf16)(v.w * inv * gv.w);
}

// ---------------- C-write helper --------------------------------------------
template <int EPI>
__device__ __forceinline__ void epi_write(
    void* outp, const float* res, int N, int rowg, int colg, float v)
{
    if constexpr (EPI == 1) {
        const size_t idx = (size_t)rowg * N + colg;
        ((float*)outp)[idx] = res[idx] + v;
    } else if constexpr (EPI == 2) {
        // gelu, tanh form via exp2 (|diff vs erf-gelu| <~1e-3, << bf16 eps here)
        const size_t idx = (size_t)rowg * N + colg;
        const float u = v * (1.0f + 0.044715f * v * v) * 2.3022585093f;
        const float r = __builtin_amdgcn_rcpf(1.0f + exp2f(u));
        ((__bf16*)outp)[idx] = (__bf16)(v - v * r);
    } else if constexpr (EPI == 6) {
        // split-K part: accumulate into out (holds z2, rewritten each launch)
        unsafeAtomicAdd(&((float*)outp)[(size_t)rowg * N + colg], v);
    } else {  // EPI == 4: QKV split
        __bf16* base = (__bf16*)outp;
        const int seg = colg >> 10;       // 0=Q, 1=K, 2=V
        const int cg = colg & 1023;
        if (seg < 2) {
            base[(size_t)seg * 4194304 + (size_t)rowg * 1024 + cg] = (__bf16)v;
        } else {
            // Vt[b][h][d][t'] with within-32 t-permutation: 16h+4g+j -> 8g+4h+j
            const int tt = rowg & 2047;
            const int r32 = tt & 31;
            const int p = ((r32 & 12) << 1) | ((r32 >> 2) & 4) | (r32 & 3);
            base[8388608 +
                 ((size_t)((rowg >> 11) * 16 + (cg >> 6)) * 64 + (cg & 63)) * 2048 +
                 ((tt & ~31) | p)] = (__bf16)v;
        }
    }
}

// ---------------- 8-phase 256x256 GEMM (m201 template) ----------------------
template <int EPI>
__global__ __launch_bounds__(512, 2) void gemm256(
    const __bf16* __restrict__ A, const __bf16* __restrict__ Bt,
    void* __restrict__ outp, const float* __restrict__ res,
    int M, int N, int K)
{
    __shared__ __bf16 As[2][2][128 * 64];   // [dbuf][half][row*64+elem]
    __shared__ __bf16 Bs[2][2][128 * 64];
    const int tid = threadIdx.x;

    const int gx = gridDim.x, nwg = gx * gridDim.y;
    int bid = blockIdx.y * gx + blockIdx.x;
    if ((nwg & 7) == 0) bid = (bid & 7) * (nwg >> 3) + (bid >> 3);
    const int m0 = (bid / gx) * 256, n0 = (bid % gx) * 256;

    const int lane = tid & 63, w = tid >> 6;         // 8 waves
    const int wr = w >> 2, wc = w & 3;               // 2 x 4 wave grid
    const int lr = lane & 15, g = lane >> 4;
    const int srow8 = lane >> 3, schunk = (lane & 7) ^ srow8;
    const int xk = lr & 7;
    const int wch = wc >> 1, bro = (wc & 1) * 64;    // B half / row offset

    const __bf16* Ab = A + (size_t)m0 * K;
    const __bf16* Bb = Bt + (size_t)n0 * K;

    auto STG = [&](const __bf16* gb, __bf16* lds, int kt, int half) {
        const __bf16* src = gb + (size_t)(half * 128) * K + (kt << 6);
#pragma unroll
        for (int j = 0; j < 2; ++j) {
            const int sidx = j * 8 + w;
            GLDS16(src + (size_t)(sidx * 8 + srow8) * K + schunk * 8, lds + sidx * 512);
        }
    };

    f32x4 acc[8][4] = {};
    bf16x8 af[2][4], bf[2][4];

#define LAF(BUF, QM) do {                                                       \
    _Pragma("unroll") for (int i_ = 0; i_ < 4; ++i_)                            \
    _Pragma("unroll") for (int kk_ = 0; kk_ < 2; ++kk_)                         \
        af[kk_][i_] = *(const bf16x8*)&As[BUF][wr]                              \
            [((QM) * 64 + i_ * 16 + lr) * 64 + (((kk_ * 4 + g) ^ xk) << 3)];    \
    } while (0)

#define LBF(BUF, QN) do {                                                       \
    _Pragma("unroll") for (int i_ = 0; i_ < 2; ++i_)                            \
    _Pragma("unroll") for (int kk_ = 0; kk_ < 2; ++kk_)                         \
        bf[kk_][(QN) * 2 + i_] = *(const bf16x8*)&Bs[BUF][wch]                  \
            [(bro + ((QN) * 2 + i_) * 16 + lr) * 64 + (((kk_ * 4 + g) ^ xk) << 3)]; \
    } while (0)

#define MMQ(QM, QN) do {                                                        \
    __builtin_amdgcn_s_setprio(1);                                              \
    _Pragma("unroll") for (int kk_ = 0; kk_ < 2; ++kk_)                         \
    _Pragma("unroll") for (int i_ = 0; i_ < 4; ++i_)                            \
    _Pragma("unroll") for (int n_ = 0; n_ < 2; ++n_)                            \
        acc[(QM) * 4 + i_][(QN) * 2 + n_] = MFMA_16x16x32_BF16(                 \
            af[kk_][i_], bf[kk_][(QN) * 2 + n_], acc[(QM) * 4 + i_][(QN) * 2 + n_]); \
    __builtin_amdgcn_s_setprio(0);                                              \
    } while (0)

#define BAR()  __builtin_amdgcn_s_barrier()
#define VMC(N_) asm volatile("s_waitcnt vmcnt(" #N_ ")" ::: "memory")
#define SGB0() __builtin_amdgcn_sched_barrier(0)

    const int nt = K >> 6, niter = nt >> 1;

    STG(Ab, &As[0][0][0], 0, 0); STG(Ab, &As[0][1][0], 0, 1);
    STG(Bb, &Bs[0][0][0], 0, 0); STG(Bb, &Bs[0][1][0], 0, 1);
    STG(Bb, &Bs[1][0][0], 1, 0); STG(Bb, &Bs[1][1][0], 1, 1);

    for (int i = 0; i < niter - 1; ++i) {
        const int t1 = 2 * i + 1;
        STG(Ab, &As[1][0][0], t1, 0);
        VMC(6); BAR(); SGB0();
        LAF(0, 0); LBF(0, 0); MMQ(0, 0); BAR();
        LBF(0, 1); STG(Ab, &As[1][1][0], t1, 1); BAR(); MMQ(0, 1); BAR();
        LAF(0, 1); STG(Bb, &Bs[0][0][0], t1 + 1, 0); BAR(); MMQ(1, 0); BAR();
        STG(Bb, &Bs[0][1][0], t1 + 1, 1); BAR(); MMQ(1, 1); BAR();
        STG(Ab, &As[0][0][0], t1 + 1, 0);
        VMC(6); BAR(); SGB0();
        LAF(1, 0); LBF(1, 0); MMQ(0, 0); BAR();
        LBF(1, 1); STG(Ab, &As[0][1][0], t1 + 1, 1); BAR(); MMQ(0, 1); BAR();
        LAF(1, 1); STG(Bb, &Bs[1][0][0], t1 + 2, 0); BAR(); MMQ(1, 0); BAR();
        STG(Bb, &Bs[1][1][0], t1 + 2, 1); BAR(); MMQ(1, 1); BAR();
    }
    {   // peeled last iteration
        STG(Ab, &As[1][0][0], nt - 1, 0);
        VMC(6); BAR(); SGB0();
        LAF(0, 0); LBF(0, 0); MMQ(0, 0); BAR();
        LBF(0, 1); STG(Ab, &As[1][1][0], nt - 1, 1); BAR(); MMQ(0, 1); BAR();
        LAF(0, 1); BAR(); MMQ(1, 0); BAR();
        BAR(); MMQ(1, 1); BAR();
        VMC(0); BAR(); SGB0();
        LAF(1, 0); LBF(1, 0); MMQ(0, 0); BAR();
        LBF(1, 1); BAR(); MMQ(0, 1); BAR();
        LAF(1, 1); BAR(); MMQ(1, 0); BAR();
        BAR(); MMQ(1, 1); BAR();
    }
#undef LAF
#undef LBF
#undef MMQ
#undef BAR
#undef VMC
#undef SGB0

#pragma unroll
    for (int mi = 0; mi < 8; ++mi)
#pragma unroll
        for (int ni = 0; ni < 4; ++ni) {
            const int colg = n0 + wc * 64 + ni * 16 + lr;
#pragma unroll
            for (int r = 0; r < 4; ++r) {
                const int rowg = m0 + wr * 128 + mi * 16 + 4 * g + r;
                epi_write<EPI>(outp, res, N, rowg, colg, acc[mi][ni][r]);
            }
        }
}

// ---------------- 2-phase 128xBN dbuf GEMM (split-K capable) ----------------
template <int BM, int BN, int EPI>
__global__ __launch_bounds__(256) void gemm_bf16(
    const __bf16* __restrict__ A, const __bf16* __restrict__ Bt,
    void* __restrict__ outp, const float* __restrict__ res,
    int M, int N, int K, int Kld)
{
    __shared__ __bf16 As[2][BM * 64];
    __shared__ __bf16 Bs[2][BN * 64];
    const int tid = threadIdx.x;

    const int gx = gridDim.x, nwg = gx * gridDim.y;
    int bid = blockIdx.y * gx + blockIdx.x;
    if ((nwg & 7) == 0) bid = (bid & 7) * (nwg >> 3) + (bid >> 3);
    const int m0 = (bid / gx) * BM, n0 = (bid % gx) * BN;

    const int lane = tid & 63, w = tid >> 6;
    const int wm = w >> 1, wn = w & 1;
    const int lr = lane & 15, g = lane >> 4;
    const int srow = lane >> 3;
    const int scol = ((lane & 7) ^ srow) * 8;
    const int xr8 = lr & 7;

    constexpr int MI = BM / 32, NI = BN / 32;
    f32x4 acc[MI][NI] = {};

    const __bf16* Abase = A + (size_t)m0 * Kld + blockIdx.z * K;
    const __bf16* Bbase = Bt + (size_t)n0 * Kld + blockIdx.z * K;

    auto STAGE = [&](int kb, int buf) {
#pragma unroll
        for (int j = 0; j < BM / 32; ++j) {
            const int s = j * 4 + w;
            GLDS16(Abase + (size_t)(s * 8 + srow) * Kld + kb + scol, &As[buf][s * 512]);
        }
#pragma unroll
        for (int j = 0; j < BN / 32; ++j) {
            const int s = j * 4 + w;
            GLDS16(Bbase + (size_t)(s * 8 + srow) * Kld + kb + scol, &Bs[buf][s * 512]);
        }
    };

    const int nt = K >> 6;
    STAGE(0, 0);
    __syncthreads();

    for (int t = 0; t < nt; ++t) {
        const int cur = t & 1;
        if (t + 1 < nt) STAGE((t + 1) << 6, cur ^ 1);

        bf16x8 af[2][MI], bfr[2][NI];
#pragma unroll
        for (int kk = 0; kk < 2; ++kk) {
#pragma unroll
            for (int i = 0; i < MI; ++i)
                af[kk][i] = *(const bf16x8*)
                    &As[cur][(wm * (BM / 2) + i * 16 + lr) * 64 + (((kk * 4 + g) ^ xr8) << 3)];
#pragma unroll
            for (int i = 0; i < NI; ++i)
                bfr[kk][i] = *(const bf16x8*)
                    &Bs[cur][(wn * (BN / 2) + i * 16 + lr) * 64 + (((kk * 4 + g) ^ xr8) << 3)];
        }
#pragma unroll
        for (int kk = 0; kk < 2; ++kk)
#pragma unroll
            for (int mi = 0; mi < MI; ++mi)
#pragma unroll
                for (int ni = 0; ni < NI; ++ni)
                    acc[mi][ni] = MFMA_16x16x32_BF16(af[kk][mi], bfr[kk][ni], acc[mi][ni]);
        if (t + 1 < nt) __syncthreads();
    }

#pragma unroll
    for (int mi = 0; mi < MI; ++mi)
#pragma unroll
        for (int ni = 0; ni < NI; ++ni) {
            const int colg = n0 + wn * (BN / 2) + ni * 16 + lr;
#pragma unroll
            for (int r = 0; r < 4; ++r) {
                const int rowg = m0 + wm * (BM / 2) + mi * 16 + 4 * g + r;
                epi_write<EPI>(outp, res, N, rowg, colg, acc[mi][ni][r]);
            }
        }
}

// ---------------- Flash-style causal attention (8-wave, KVBLK=128) ----------
// Grid: 512 blocks = j*32 + bh, j in [0,16). qc = j<8 ? j : 23-j (balanced).
// Block-uniform FULL fast path for t<qc (no mask logic, all PV groups live).
__global__ __launch_bounds__(512) void attn_kernel(
    const __bf16* __restrict__ Q, const __bf16* __restrict__ Kb,
    const __bf16* __restrict__ Vt, __bf16* __restrict__ ctx)
{
    const int Dm = 1024, T = 2048;
    const int tid = threadIdx.x;
    const int w = tid >> 6, lane = tid & 63;
    const int lr = lane & 15, g = lane >> 4;
    const int bx = blockIdx.x;
    const int j = bx >> 5, bh = bx & 31, b = bh >> 4, h = bh & 15;
    const int qc = (j < 8) ? j : 23 - j;            // balanced bijection 0..15
    const int qbase = qc * 128 + w * 16;
    const size_t rowoff = (size_t)b * T;
    const __bf16* Qp = Q + rowoff * Dm + h * 64;
    const __bf16* Kp = Kb + rowoff * Dm + h * 64;
    const __bf16* Vtp = Vt + (size_t)bh * 64 * 2048;

    __shared__ __bf16 Ks[2][128 * 64];
    __shared__ __bf16 Vs[2][64 * 128];

    bf16x8 qf0 = *(const bf16x8*)&Qp[(size_t)(qbase + lr) * Dm + g * 8];
    bf16x8 qf1 = *(const bf16x8*)&Qp[(size_t)(qbase + lr) * Dm + 32 + g * 8];
    const float qsc = 0.125f * 1.44269504088896340736f;
#pragma unroll
    for (int jj = 0; jj < 8; ++jj) {
        qf0[jj] = (__bf16)((float)qf0[jj] * qsc);
        qf1[jj] = (__bf16)((float)qf1[jj] * qsc);
    }

    const int ksrow = lane >> 3;
    const int kschunk = (lane & 7) ^ ksrow;
    const int vsrow = lane >> 4;                    // 0..3

    f32x4 acc[4] = {};
    float m_s = -__builtin_inff(), l_s = 0.0f;
    const int nsteps = qc + 1;
    const f32x4 zacc = {0.0f, 0.0f, 0.0f, 0.0f};
    const int x8 = lr & 7;                          // K read chunk XOR
    const int qg = qbase + lr;

    auto STAGE = [&](int kvb, int buf) {
#pragma unroll
        for (int jj = 0; jj < 2; ++jj) {
            const int krow = w * 16 + jj * 8;
            GLDS16(Kp + (size_t)(kvb + krow + ksrow) * Dm + kschunk * 8,
                   &Ks[buf][krow * 64]);
            const int vrow = w * 8 + jj * 4;
            const int vchunk = (lane & 15) ^ ((vrow + vsrow) & 15);
            GLDS16(Vtp + (size_t)(vrow + vsrow) * T + kvb + vchunk * 8,
                   &Vs[buf][vrow * 128]);
        }
    };

    STAGE(0, 0);
    __syncthreads();

    for (int t = 0; t < nsteps; ++t) {
        const int kvb = t * 128, cur = t & 1;
        if (t + 1 < nsteps) STAGE(kvb + 128, cur ^ 1);

        float sv[8][4];
        if (t < qc) {
            // ---- FULL fast path: whole 128-kv tile live, no mask logic ----
#pragma unroll
            for (int s4 = 0; s4 < 8; ++s4) {
                const int row = s4 * 16 + lr;
                const bf16x8 kfa = *(const bf16x8*)&Ks[cur][row * 64 + ((g ^ x8) << 3)];
                const bf16x8 kfb = *(const bf16x8*)&Ks[cur][row * 64 + (((4 + g) ^ x8) << 3)];
                f32x4 st = MFMA_16x16x32_BF16(kfa, qf0, zacc);
                st = MFMA_16x16x32_BF16(kfb, qf1, st);
#pragma unroll
                for (int r = 0; r < 4; ++r) sv[s4][r] = st[r];
            }
        } else {
            // ---- diagonal step: per-subtile guards + causal mask ----
#pragma unroll
            for (int s4 = 0; s4 < 8; ++s4) {
                const int kv0 = kvb + s4 * 16;
                if (kv0 <= qbase + 15) {
                    const int row = s4 * 16 + lr;
                    const bf16x8 kfa = *(const bf16x8*)&Ks[cur][row * 64 + ((g ^ x8) << 3)];
                    const bf16x8 kfb = *(const bf16x8*)&Ks[cur][row * 64 + (((4 + g) ^ x8) << 3)];
                    f32x4 st = MFMA_16x16x32_BF16(kfa, qf0, zacc);
                    st = MFMA_16x16x32_BF16(kfb, qf1, st);
                    const bool domask = (kv0 + 15 > qbase);
#pragma unroll
                    for (int r = 0; r < 4; ++r) {
                        float x = st[r];
                        if (domask && (kv0 + 4 * g + r > qg)) x = -__builtin_inff();
                        sv[s4][r] = x;
                    }
                } else {
#pragma unroll
                    for (int r = 0; r < 4; ++r) sv[s4][r] = -__builtin_inff();
                }
            }
        }

        // ---- online softmax (log2 domain) with defer-rescale ----
        float tm = sv[0][0];
#pragma unroll
        for (int s4 = 0; s4 < 8; ++s4)
#pragma unroll
            for (int r = 0; r < 4; ++r) tm = fmaxf(tm, sv[s4][r]);
        tm = fmaxf(tm, __shfl_xor(tm, 16));
        tm = fmaxf(tm, __shfl_xor(tm, 32));

        float m_use = m_s;
        if (!__all(tm - m_s <= 11.5f)) {
            m_use = fmaxf(m_s, tm);
            const float corr = exp2f(m_s - m_use);
            l_s *= corr;
            float cr[4];
#pragma unroll
            for (int r = 0; r < 4; ++r) cr[r] = __shfl(corr, 4 * g + r);
#pragma unroll
            for (int ct = 0; ct < 4; ++ct) {
                acc[ct][0] *= cr[0]; acc[ct][1] *= cr[1];
                acc[ct][2] *= cr[2]; acc[ct][3] *= cr[3];
            }
            m_s = m_use;
        }

        float rs = 0.0f;
#pragma unroll
        for (int s4 = 0; s4 < 8; ++s4)
#pragma unroll
            for (int r = 0; r < 4; ++r) {
                sv[s4][r] = exp2f(sv[s4][r] - m_use);
                rs += sv[s4][r];
            }
        rs += __shfl_xor(rs, 16);
        rs += __shfl_xor(rs, 32);
        l_s += rs;

        // ---- PV ----
        bf16x8 pa[4];
#pragma unroll
        for (int s = 0; s < 4; ++s)
#pragma unroll
            for (int r = 0; r < 4; ++r) {
                pa[s][r] = (__bf16)sv[2 * s][r];
                pa[s][4 + r] = (__bf16)sv[2 * s + 1][r];
            }
        if (t < qc) {
#pragma unroll
            for (int ct = 0; ct < 4; ++ct) {
                const __bf16* vrow = &Vs[cur][(ct * 16 + lr) * 128];
#pragma unroll
                for (int s = 0; s < 4; ++s) {
                    const bf16x8 vf = *(const bf16x8*)&vrow[(((s * 4 + g) ^ lr) << 3)];
                    acc[ct] = MFMA_16x16x32_BF16(pa[s], vf, acc[ct]);
                }
            }
        } else {
#pragma unroll
            for (int ct = 0; ct < 4; ++ct) {
                const __bf16* vrow = &Vs[cur][(ct * 16 + lr) * 128];
#pragma unroll
                for (int s = 0; s < 4; ++s) {
                    if (kvb + s * 32 <= qbase + 15) {
                        const bf16x8 vf = *(const bf16x8*)&vrow[(((s * 4 + g) ^ lr) << 3)];
                        acc[ct] = MFMA_16x16x32_BF16(pa[s], vf, acc[ct]);
                    }
                }
            }
        }
        __syncthreads();
    }

    const float il = __builtin_amdgcn_rcpf(l_s);
    float dn[4];
#pragma unroll
    for (int r = 0; r < 4; ++r) dn[r] = __shfl(il, 4 * g + r);
#pragma unroll
    for (int ct = 0; ct < 4; ++ct)
#pragma unroll
        for (int r = 0; r < 4; ++r)
            ctx[(rowoff + qbase + 4 * g + r) * Dm + h * 64 + ct * 16 + lr] =
                (__bf16)(acc[ct][r] * dn[r]);
}

// ---------------------------------------------------------------------------
extern "C" void kernel_launch(void* const* d_in, const int* in_sizes, int n_in,
                              void* d_out, int out_size, void* d_ws, size_t ws_size,
                              hipStream_t stream)
{
    (void)in_sizes; (void)n_in; (void)out_size; (void)ws_size;
    const float* z      = (const float*)d_in[0];
    const float* W_Q    = (const float*)d_in[1];
    const float* W_K    = (const float*)d_in[2];
    const float* W_V    = (const float*)d_in[3];
    const float* W_O    = (const float*)d_in[4];
    const float* W_fc   = (const float*)d_in[5];
    const float* W_proj = (const float*)d_in[6];
    const float* g1     = (const float*)d_in[7];
    const float* g2     = (const float*)d_in[8];
    float* out = (float*)d_out;

    char* ws = (char*)d_ws;
    const size_t MB = (size_t)1 << 20;
    __bf16* WtQKV  = (__bf16*)(ws + 0 * MB);   // [3072][1024]
    __bf16* WtO    = (__bf16*)(ws + 6 * MB);
    __bf16* Wtfc   = (__bf16*)(ws + 8 * MB);
    __bf16* Wtproj = (__bf16*)(ws + 16 * MB);
    __bf16* zn     = (__bf16*)(ws + 24 * MB);  // reused as ctx
    __bf16* Qb     = (__bf16*)(ws + 32 * MB);  // QKV out base; reused as h
    __bf16* Kbuf   = (__bf16*)(ws + 40 * MB);
    __bf16* Vtb    = (__bf16*)(ws + 48 * MB);
    __bf16* ffn1   = (__bf16*)(ws + 40 * MB);  // overlaps K,Vt (dead post-attn)
    __bf16* ctx    = zn;
    __bf16* hb     = Qb;

    const int Tt = 2048, Dm = 1024, Bb = 2, M = Bb * Tt, DFF = 4096;
    const dim3 blk256(256), blk512(512);

    // fused: weight transposes + rmsnorm(z, g1) -> zn
    fused_head_kernel<<<16384, blk256, 0, stream>>>(
        W_Q, W_K, W_V, W_O, W_fc, W_proj, WtQKV, WtO, Wtfc, Wtproj, z, g1, zn);

    // Fused QKV (2-phase 128x128, 768 blocks): [4096][3072]
    gemm_bf16<128, 128, 4><<<dim3(24, 32), blk256, 0, stream>>>(
        zn, WtQKV, Qb, nullptr, M, 3072, Dm, Dm);

    // attention -> ctx (8-wave blocks, KVBLK=128)
    attn_kernel<<<512, blk512, 0, stream>>>(Qb, Kbuf, Vtb, ctx);

    // z2 = z + ctx @ W_O  -> d_out (fp32)
    gemm_bf16<128, 64, 1><<<dim3(16, 32), blk256, 0, stream>>>(
        ctx, WtO, out, z, M, Dm, Dm, Dm);

    // h = rmsnorm(z2, g2)
    rmsnorm_kernel<<<M, blk256, 0, stream>>>(out, g2, hb);

    // ffn1 = gelu(h @ W_fc) (8-phase 256^2, 256 blocks = 1/CU exactly)
    gemm256<2><<<dim3(16, 16), blk512, 0, stream>>>(
        hb, Wtfc, ffn1, nullptr, M, DFF, Dm);

    // proj split-K=2 (128x128, 512 blocks): both parts atomicAdd into out
    gemm_bf16<128, 128, 6><<<dim3(8, 32, 2), blk256, 0, stream>>>(
        ffn1, Wtproj, out, nullptr, M, Dm, DFF / 2, DFF);
}

// Round 13
// 237.861 us; speedup vs baseline: 1.3278x; 1.0345x over previous
//
#include <hip/hip_runtime.h>
#include <hip/hip_bf16.h>
#include <math.h>

// ---------------------------------------------------------------------------
// GPT block on MI355X (gfx950). bf16 MFMA compute, fp32 accumulate.
// Workspace layout (MB = 1<<20), total 72 MB:
//   [ 0, 6)  WtQKV  bf16 [3072][1024]   -- dead after QKV; reused as partial0
//   [ 6, 8)  WtO    bf16 [1024][1024]   -- dead after O-proj  (part of p0)
//   [ 8,16)  Wtfc   bf16 [4096][1024]   -- dead after fc      (part of p0)
//   [16,24)  Wtproj bf16 [1024][4096]
//   [24,32)  zn / ctx   bf16            -- dead after O-proj; partial1
//   [32,40)  Q / h      bf16            -- dead after fc      (part of p1)
//   [40,48)  K          bf16
//   [48,56)  Vt         bf16 [32][64][2048]  (V transposed, kv-permuted)
//   [40,72)  ffn1       bf16 [4096][4096]  (overlaps K,Vt — dead after attn)
// fc: 8-phase 256^2 template. proj: split-K=2 fp32 partials + reduce pass
// (atomicAdd variant measured SLOWER: HBM RMW + 2-part line contention, r12).
// attn: 8-wave blocks, KVBLK=128, block-uniform FULL fast path for t<qc.
// ---------------------------------------------------------------------------

typedef __bf16 bf16x8 __attribute__((ext_vector_type(8)));
typedef float  f32x4  __attribute__((ext_vector_type(4)));

#define MFMA_16x16x32_BF16(A, B, C) __builtin_amdgcn_mfma_f32_16x16x32_bf16((A), (B), (C), 0, 0, 0)

#define GLDS16(g, l) __builtin_amdgcn_global_load_lds( \
    (const __attribute__((address_space(1))) void*)(g), \
    (__attribute__((address_space(3))) void*)(l), 16, 0, 0)

// ---------------- fused head: 6 weight transposes + rmsnorm(z,g1) -----------
__global__ __launch_bounds__(256) void fused_head_kernel(
    const float* __restrict__ W_Q, const float* __restrict__ W_K,
    const float* __restrict__ W_V, const float* __restrict__ W_O,
    const float* __restrict__ W_fc, const float* __restrict__ W_proj,
    __bf16* __restrict__ WtQKV, __bf16* __restrict__ WtO,
    __bf16* __restrict__ Wtfc, __bf16* __restrict__ Wtproj,
    const float* __restrict__ z, const float* __restrict__ g1,
    __bf16* __restrict__ zn)
{
    const int id = blockIdx.x;
    if (id >= 12288) {
        const int row = id - 12288, t = threadIdx.x;
        const float4 v = ((const float4*)(z + (size_t)row * 1024))[t];
        float ss = v.x * v.x + v.y * v.y + v.z * v.z + v.w * v.w;
#pragma unroll
        for (int m = 1; m < 64; m <<= 1) ss += __shfl_xor(ss, m);
        __shared__ float red[4];
        const int wid = t >> 6, lane = t & 63;
        if (lane == 0) red[wid] = ss;
        __syncthreads();
        const float tot = red[0] + red[1] + red[2] + red[3];
        const float inv = rsqrtf(tot * (1.0f / 1024.0f) + 1e-5f);
        const float4 gv = ((const float4*)g1)[t];
        __bf16* o = zn + (size_t)row * 1024 + t * 4;
        o[0] = (__bf16)(v.x * inv * gv.x);
        o[1] = (__bf16)(v.y * inv * gv.y);
        o[2] = (__bf16)(v.z * inv * gv.z);
        o[3] = (__bf16)(v.w * inv * gv.w);
        return;
    }
    const float* src;
    __bf16* dst;
    int K, N, nx, t;
    if (id < 4096) {
        const int wsel = id >> 10;
        t = id & 1023;
        src = (wsel == 0) ? W_Q : (wsel == 1) ? W_K : (wsel == 2) ? W_V : W_O;
        dst = (wsel < 3) ? (WtQKV + (size_t)wsel * 1048576) : WtO;
        K = 1024; N = 1024; nx = 32;
    } else if (id < 8192) {
        t = id - 4096; src = W_fc; dst = Wtfc; K = 1024; N = 4096; nx = 128;
    } else {
        t = id - 8192; src = W_proj; dst = Wtproj; K = 4096; N = 1024; nx = 32;
    }
    const int n0 = (t % nx) * 32, k0 = (t / nx) * 32;

    __shared__ float tile[32][33];
    const int c = threadIdx.x & 31, r = threadIdx.x >> 5;
#pragma unroll
    for (int i = 0; i < 4; ++i)
        tile[r + 8 * i][c] = src[(size_t)(k0 + r + 8 * i) * N + n0 + c];
    __syncthreads();
#pragma unroll
    for (int i = 0; i < 4; ++i)
        dst[(size_t)(n0 + r + 8 * i) * K + k0 + c] = (__bf16)tile[c][r + 8 * i];
}

// ---------------- RMSNorm: fp32 [M][1024] -> bf16 [M][1024] -----------------
__global__ __launch_bounds__(256) void rmsnorm_kernel(
    const float* __restrict__ x, const float* __restrict__ gain,
    __bf16* __restrict__ out)
{
    const int row = blockIdx.x, t = threadIdx.x;
    const float4 v = ((const float4*)(x + (size_t)row * 1024))[t];
    float ss = v.x * v.x + v.y * v.y + v.z * v.z + v.w * v.w;
#pragma unroll
    for (int m = 1; m < 64; m <<= 1) ss += __shfl_xor(ss, m);
    __shared__ float red[4];
    const int wid = t >> 6, lane = t & 63;
    if (lane == 0) red[wid] = ss;
    __syncthreads();
    const float tot = red[0] + red[1] + red[2] + red[3];
    const float inv = rsqrtf(tot * (1.0f / 1024.0f) + 1e-5f);
    const float4 gv = ((const float4*)gain)[t];
    __bf16* o = out + (size_t)row * 1024 + t * 4;
    o[0] = (__bf16)(v.x * inv * gv.x);
    o[1] = (__bf16)(v.y * inv * gv.y);
    o[2] = (__bf16)(v.z * inv * gv.z);
    o[3] = (__bf16)(v.w * inv * gv.w);
}

// ---------------- reduce: out += p0 + p1 (fp32, float4 grid-stride) ---------
__global__ __launch_bounds__(256) void reduce_add_kernel(
    float* __restrict__ out, const float* __restrict__ p0,
    const float* __restrict__ p1, int n4)
{
    for (int i = blockIdx.x * 256 + threadIdx.x; i < n4; i += gridDim.x * 256) {
        const float4 a = ((const float4*)p0)[i];
        const float4 b = ((const float4*)p1)[i];
        float4 o = ((float4*)out)[i];
        o.x += a.x + b.x; o.y += a.y + b.y;
        o.z += a.z + b.z; o.w += a.w + b.w;
        ((float4*)out)[i] = o;
    }
}

// ---------------- C-write helper --------------------------------------------
template <int EPI>
__device__ __forceinline__ void epi_write(
    void* outp, const float* res, int N, int rowg, int colg, float v)
{
    if constexpr (EPI == 1) {
        const size_t idx = (size_t)rowg * N + colg;
        ((float*)outp)[idx] = res[idx] + v;
    } else if constexpr (EPI == 2) {
        // gelu, tanh form via exp2 (|diff vs erf-gelu| <~1e-3, << bf16 eps here)
        const size_t idx = (size_t)rowg * N + colg;
        const float u = v * (1.0f + 0.044715f * v * v) * 2.3022585093f;
        const float r = __builtin_amdgcn_rcpf(1.0f + exp2f(u));
        ((__bf16*)outp)[idx] = (__bf16)(v - v * r);
    } else {  // EPI == 4: QKV split
        __bf16* base = (__bf16*)outp;
        const int seg = colg >> 10;       // 0=Q, 1=K, 2=V
        const int cg = colg & 1023;
        if (seg < 2) {
            base[(size_t)seg * 4194304 + (size_t)rowg * 1024 + cg] = (__bf16)v;
        } else {
            // Vt[b][h][d][t'] with within-32 t-permutation: 16h+4g+j -> 8g+4h+j
            const int tt = rowg & 2047;
            const int r32 = tt & 31;
            const int p = ((r32 & 12) << 1) | ((r32 >> 2) & 4) | (r32 & 3);
            base[8388608 +
                 ((size_t)((rowg >> 11) * 16 + (cg >> 6)) * 64 + (cg & 63)) * 2048 +
                 ((tt & ~31) | p)] = (__bf16)v;
        }
    }
}

// ---------------- 8-phase 256x256 GEMM (m201 template) ----------------------
template <int EPI>
__global__ __launch_bounds__(512, 2) void gemm256(
    const __bf16* __restrict__ A, const __bf16* __restrict__ Bt,
    void* __restrict__ outp, const float* __restrict__ res,
    int M, int N, int K)
{
    __shared__ __bf16 As[2][2][128 * 64];   // [dbuf][half][row*64+elem]
    __shared__ __bf16 Bs[2][2][128 * 64];
    const int tid = threadIdx.x;

    const int gx = gridDim.x, nwg = gx * gridDim.y;
    int bid = blockIdx.y * gx + blockIdx.x;
    if ((nwg & 7) == 0) bid = (bid & 7) * (nwg >> 3) + (bid >> 3);
    const int m0 = (bid / gx) * 256, n0 = (bid % gx) * 256;

    const int lane = tid & 63, w = tid >> 6;         // 8 waves
    const int wr = w >> 2, wc = w & 3;               // 2 x 4 wave grid
    const int lr = lane & 15, g = lane >> 4;
    const int srow8 = lane >> 3, schunk = (lane & 7) ^ srow8;
    const int xk = lr & 7;
    const int wch = wc >> 1, bro = (wc & 1) * 64;    // B half / row offset

    const __bf16* Ab = A + (size_t)m0 * K;
    const __bf16* Bb = Bt + (size_t)n0 * K;

    auto STG = [&](const __bf16* gb, __bf16* lds, int kt, int half) {
        const __bf16* src = gb + (size_t)(half * 128) * K + (kt << 6);
#pragma unroll
        for (int j = 0; j < 2; ++j) {
            const int sidx = j * 8 + w;
            GLDS16(src + (size_t)(sidx * 8 + srow8) * K + schunk * 8, lds + sidx * 512);
        }
    };

    f32x4 acc[8][4] = {};
    bf16x8 af[2][4], bf[2][4];

#define LAF(BUF, QM) do {                                                       \
    _Pragma("unroll") for (int i_ = 0; i_ < 4; ++i_)                            \
    _Pragma("unroll") for (int kk_ = 0; kk_ < 2; ++kk_)                         \
        af[kk_][i_] = *(const bf16x8*)&As[BUF][wr]                              \
            [((QM) * 64 + i_ * 16 + lr) * 64 + (((kk_ * 4 + g) ^ xk) << 3)];    \
    } while (0)

#define LBF(BUF, QN) do {                                                       \
    _Pragma("unroll") for (int i_ = 0; i_ < 2; ++i_)                            \
    _Pragma("unroll") for (int kk_ = 0; kk_ < 2; ++kk_)                         \
        bf[kk_][(QN) * 2 + i_] = *(const bf16x8*)&Bs[BUF][wch]                  \
            [(bro + ((QN) * 2 + i_) * 16 + lr) * 64 + (((kk_ * 4 + g) ^ xk) << 3)]; \
    } while (0)

#define MMQ(QM, QN) do {                                                        \
    __builtin_amdgcn_s_setprio(1);                                              \
    _Pragma("unroll") for (int kk_ = 0; kk_ < 2; ++kk_)                         \
    _Pragma("unroll") for (int i_ = 0; i_ < 4; ++i_)                            \
    _Pragma("unroll") for (int n_ = 0; n_ < 2; ++n_)                            \
        acc[(QM) * 4 + i_][(QN) * 2 + n_] = MFMA_16x16x32_BF16(                 \
            af[kk_][i_], bf[kk_][(QN) * 2 + n_], acc[(QM) * 4 + i_][(QN) * 2 + n_]); \
    __builtin_amdgcn_s_setprio(0);                                              \
    } while (0)

#define BAR()  __builtin_amdgcn_s_barrier()
#define VMC(N_) asm volatile("s_waitcnt vmcnt(" #N_ ")" ::: "memory")
#define SGB0() __builtin_amdgcn_sched_barrier(0)

    const int nt = K >> 6, niter = nt >> 1;

    STG(Ab, &As[0][0][0], 0, 0); STG(Ab, &As[0][1][0], 0, 1);
    STG(Bb, &Bs[0][0][0], 0, 0); STG(Bb, &Bs[0][1][0], 0, 1);
    STG(Bb, &Bs[1][0][0], 1, 0); STG(Bb, &Bs[1][1][0], 1, 1);

    for (int i = 0; i < niter - 1; ++i) {
        const int t1 = 2 * i + 1;
        STG(Ab, &As[1][0][0], t1, 0);
        VMC(6); BAR(); SGB0();
        LAF(0, 0); LBF(0, 0); MMQ(0, 0); BAR();
        LBF(0, 1); STG(Ab, &As[1][1][0], t1, 1); BAR(); MMQ(0, 1); BAR();
        LAF(0, 1); STG(Bb, &Bs[0][0][0], t1 + 1, 0); BAR(); MMQ(1, 0); BAR();
        STG(Bb, &Bs[0][1][0], t1 + 1, 1); BAR(); MMQ(1, 1); BAR();
        STG(Ab, &As[0][0][0], t1 + 1, 0);
        VMC(6); BAR(); SGB0();
        LAF(1, 0); LBF(1, 0); MMQ(0, 0); BAR();
        LBF(1, 1); STG(Ab, &As[0][1][0], t1 + 1, 1); BAR(); MMQ(0, 1); BAR();
        LAF(1, 1); STG(Bb, &Bs[1][0][0], t1 + 2, 0); BAR(); MMQ(1, 0); BAR();
        STG(Bb, &Bs[1][1][0], t1 + 2, 1); BAR(); MMQ(1, 1); BAR();
    }
    {   // peeled last iteration
        STG(Ab, &As[1][0][0], nt - 1, 0);
        VMC(6); BAR(); SGB0();
        LAF(0, 0); LBF(0, 0); MMQ(0, 0); BAR();
        LBF(0, 1); STG(Ab, &As[1][1][0], nt - 1, 1); BAR(); MMQ(0, 1); BAR();
        LAF(0, 1); BAR(); MMQ(1, 0); BAR();
        BAR(); MMQ(1, 1); BAR();
        VMC(0); BAR(); SGB0();
        LAF(1, 0); LBF(1, 0); MMQ(0, 0); BAR();
        LBF(1, 1); BAR(); MMQ(0, 1); BAR();
        LAF(1, 1); BAR(); MMQ(1, 0); BAR();
        BAR(); MMQ(1, 1); BAR();
    }
#undef LAF
#undef LBF
#undef MMQ
#undef BAR
#undef VMC
#undef SGB0

#pragma unroll
    for (int mi = 0; mi < 8; ++mi)
#pragma unroll
        for (int ni = 0; ni < 4; ++ni) {
            const int colg = n0 + wc * 64 + ni * 16 + lr;
#pragma unroll
            for (int r = 0; r < 4; ++r) {
                const int rowg = m0 + wr * 128 + mi * 16 + 4 * g + r;
                epi_write<EPI>(outp, res, N, rowg, colg, acc[mi][ni][r]);
            }
        }
}

// ---------------- 2-phase 128xBN dbuf GEMM (split-K capable) ----------------
// EPI 5: store fp32 partial (part 0 -> outp, part 1 -> res cast).
template <int BM, int BN, int EPI>
__global__ __launch_bounds__(256) void gemm_bf16(
    const __bf16* __restrict__ A, const __bf16* __restrict__ Bt,
    void* __restrict__ outp, const float* __restrict__ res,
    int M, int N, int K, int Kld)
{
    __shared__ __bf16 As[2][BM * 64];
    __shared__ __bf16 Bs[2][BN * 64];
    const int tid = threadIdx.x;

    const int gx = gridDim.x, nwg = gx * gridDim.y;
    int bid = blockIdx.y * gx + blockIdx.x;
    if ((nwg & 7) == 0) bid = (bid & 7) * (nwg >> 3) + (bid >> 3);
    const int m0 = (bid / gx) * BM, n0 = (bid % gx) * BN;

    const int lane = tid & 63, w = tid >> 6;
    const int wm = w >> 1, wn = w & 1;
    const int lr = lane & 15, g = lane >> 4;
    const int srow = lane >> 3;
    const int scol = ((lane & 7) ^ srow) * 8;
    const int xr8 = lr & 7;

    constexpr int MI = BM / 32, NI = BN / 32;
    f32x4 acc[MI][NI] = {};

    const __bf16* Abase = A + (size_t)m0 * Kld + blockIdx.z * K;
    const __bf16* Bbase = Bt + (size_t)n0 * Kld + blockIdx.z * K;

    auto STAGE = [&](int kb, int buf) {
#pragma unroll
        for (int j = 0; j < BM / 32; ++j) {
            const int s = j * 4 + w;
            GLDS16(Abase + (size_t)(s * 8 + srow) * Kld + kb + scol, &As[buf][s * 512]);
        }
#pragma unroll
        for (int j = 0; j < BN / 32; ++j) {
            const int s = j * 4 + w;
            GLDS16(Bbase + (size_t)(s * 8 + srow) * Kld + kb + scol, &Bs[buf][s * 512]);
        }
    };

    const int nt = K >> 6;
    STAGE(0, 0);
    __syncthreads();

    for (int t = 0; t < nt; ++t) {
        const int cur = t & 1;
        if (t + 1 < nt) STAGE((t + 1) << 6, cur ^ 1);

        bf16x8 af[2][MI], bfr[2][NI];
#pragma unroll
        for (int kk = 0; kk < 2; ++kk) {
#pragma unroll
            for (int i = 0; i < MI; ++i)
                af[kk][i] = *(const bf16x8*)
                    &As[cur][(wm * (BM / 2) + i * 16 + lr) * 64 + (((kk * 4 + g) ^ xr8) << 3)];
#pragma unroll
            for (int i = 0; i < NI; ++i)
                bfr[kk][i] = *(const bf16x8*)
                    &Bs[cur][(wn * (BN / 2) + i * 16 + lr) * 64 + (((kk * 4 + g) ^ xr8) << 3)];
        }
#pragma unroll
        for (int kk = 0; kk < 2; ++kk)
#pragma unroll
            for (int mi = 0; mi < MI; ++mi)
#pragma unroll
                for (int ni = 0; ni < NI; ++ni)
                    acc[mi][ni] = MFMA_16x16x32_BF16(af[kk][mi], bfr[kk][ni], acc[mi][ni]);
        if (t + 1 < nt) __syncthreads();
    }

#pragma unroll
    for (int mi = 0; mi < MI; ++mi)
#pragma unroll
        for (int ni = 0; ni < NI; ++ni) {
            const int colg = n0 + wn * (BN / 2) + ni * 16 + lr;
#pragma unroll
            for (int r = 0; r < 4; ++r) {
                const int rowg = m0 + wm * (BM / 2) + mi * 16 + 4 * g + r;
                const float v = acc[mi][ni][r];
                if constexpr (EPI == 5) {
                    float* pout = (blockIdx.z == 0) ? (float*)outp : (float*)(void*)res;
                    pout[(size_t)rowg * N + colg] = v;
                } else {
                    epi_write<EPI>(outp, res, N, rowg, colg, v);
                }
            }
        }
}

// ---------------- Flash-style causal attention (8-wave, KVBLK=128) ----------
// Grid: 512 blocks = j*32 + bh, j in [0,16). qc = j<8 ? j : 23-j (balanced).
// Block-uniform FULL fast path for t<qc (no mask logic, all PV groups live).
__global__ __launch_bounds__(512) void attn_kernel(
    const __bf16* __restrict__ Q, const __bf16* __restrict__ Kb,
    const __bf16* __restrict__ Vt, __bf16* __restrict__ ctx)
{
    const int Dm = 1024, T = 2048;
    const int tid = threadIdx.x;
    const int w = tid >> 6, lane = tid & 63;
    const int lr = lane & 15, g = lane >> 4;
    const int bx = blockIdx.x;
    const int j = bx >> 5, bh = bx & 31, b = bh >> 4, h = bh & 15;
    const int qc = (j < 8) ? j : 23 - j;            // balanced bijection 0..15
    const int qbase = qc * 128 + w * 16;
    const size_t rowoff = (size_t)b * T;
    const __bf16* Qp = Q + rowoff * Dm + h * 64;
    const __bf16* Kp = Kb + rowoff * Dm + h * 64;
    const __bf16* Vtp = Vt + (size_t)bh * 64 * 2048;

    __shared__ __bf16 Ks[2][128 * 64];
    __shared__ __bf16 Vs[2][64 * 128];

    bf16x8 qf0 = *(const bf16x8*)&Qp[(size_t)(qbase + lr) * Dm + g * 8];
    bf16x8 qf1 = *(const bf16x8*)&Qp[(size_t)(qbase + lr) * Dm + 32 + g * 8];
    const float qsc = 0.125f * 1.44269504088896340736f;
#pragma unroll
    for (int jj = 0; jj < 8; ++jj) {
        qf0[jj] = (__bf16)((float)qf0[jj] * qsc);
        qf1[jj] = (__bf16)((float)qf1[jj] * qsc);
    }

    const int ksrow = lane >> 3;
    const int kschunk = (lane & 7) ^ ksrow;
    const int vsrow = lane >> 4;                    // 0..3

    f32x4 acc[4] = {};
    float m_s = -__builtin_inff(), l_s = 0.0f;
    const int nsteps = qc + 1;
    const f32x4 zacc = {0.0f, 0.0f, 0.0f, 0.0f};
    const int x8 = lr & 7;                          // K read chunk XOR
    const int qg = qbase + lr;

    auto STAGE = [&](int kvb, int buf) {
#pragma unroll
        for (int jj = 0; jj < 2; ++jj) {
            const int krow = w * 16 + jj * 8;
            GLDS16(Kp + (size_t)(kvb + krow + ksrow) * Dm + kschunk * 8,
                   &Ks[buf][krow * 64]);
            const int vrow = w * 8 + jj * 4;
            const int vchunk = (lane & 15) ^ ((vrow + vsrow) & 15);
            GLDS16(Vtp + (size_t)(vrow + vsrow) * T + kvb + vchunk * 8,
                   &Vs[buf][vrow * 128]);
        }
    };

    STAGE(0, 0);
    __syncthreads();

    for (int t = 0; t < nsteps; ++t) {
        const int kvb = t * 128, cur = t & 1;
        if (t + 1 < nsteps) STAGE(kvb + 128, cur ^ 1);

        float sv[8][4];
        if (t < qc) {
            // ---- FULL fast path: whole 128-kv tile live, no mask logic ----
#pragma unroll
            for (int s4 = 0; s4 < 8; ++s4) {
                const int row = s4 * 16 + lr;
                const bf16x8 kfa = *(const bf16x8*)&Ks[cur][row * 64 + ((g ^ x8) << 3)];
                const bf16x8 kfb = *(const bf16x8*)&Ks[cur][row * 64 + (((4 + g) ^ x8) << 3)];
                f32x4 st = MFMA_16x16x32_BF16(kfa, qf0, zacc);
                st = MFMA_16x16x32_BF16(kfb, qf1, st);
#pragma unroll
                for (int r = 0; r < 4; ++r) sv[s4][r] = st[r];
            }
        } else {
            // ---- diagonal step: per-subtile guards + causal mask ----
#pragma unroll
            for (int s4 = 0; s4 < 8; ++s4) {
                const int kv0 = kvb + s4 * 16;
                if (kv0 <= qbase + 15) {
                    const int row = s4 * 16 + lr;
                    const bf16x8 kfa = *(const bf16x8*)&Ks[cur][row * 64 + ((g ^ x8) << 3)];
                    const bf16x8 kfb = *(const bf16x8*)&Ks[cur][row * 64 + (((4 + g) ^ x8) << 3)];
                    f32x4 st = MFMA_16x16x32_BF16(kfa, qf0, zacc);
                    st = MFMA_16x16x32_BF16(kfb, qf1, st);
                    const bool domask = (kv0 + 15 > qbase);
#pragma unroll
                    for (int r = 0; r < 4; ++r) {
                        float x = st[r];
                        if (domask && (kv0 + 4 * g + r > qg)) x = -__builtin_inff();
                        sv[s4][r] = x;
                    }
                } else {
#pragma unroll
                    for (int r = 0; r < 4; ++r) sv[s4][r] = -__builtin_inff();
                }
            }
        }

        // ---- online softmax (log2 domain) with defer-rescale ----
        float tm = sv[0][0];
#pragma unroll
        for (int s4 = 0; s4 < 8; ++s4)
#pragma unroll
            for (int r = 0; r < 4; ++r) tm = fmaxf(tm, sv[s4][r]);
        tm = fmaxf(tm, __shfl_xor(tm, 16));
        tm = fmaxf(tm, __shfl_xor(tm, 32));

        float m_use = m_s;
        if (!__all(tm - m_s <= 11.5f)) {
            m_use = fmaxf(m_s, tm);
            const float corr = exp2f(m_s - m_use);
            l_s *= corr;
            float cr[4];
#pragma unroll
            for (int r = 0; r < 4; ++r) cr[r] = __shfl(corr, 4 * g + r);
#pragma unroll
            for (int ct = 0; ct < 4; ++ct) {
                acc[ct][0] *= cr[0]; acc[ct][1] *= cr[1];
                acc[ct][2] *= cr[2]; acc[ct][3] *= cr[3];
            }
            m_s = m_use;
        }

        float rs = 0.0f;
#pragma unroll
        for (int s4 = 0; s4 < 8; ++s4)
#pragma unroll
            for (int r = 0; r < 4; ++r) {
                sv[s4][r] = exp2f(sv[s4][r] - m_use);
                rs += sv[s4][r];
            }
        rs += __shfl_xor(rs, 16);
        rs += __shfl_xor(rs, 32);
        l_s += rs;

        // ---- PV ----
        bf16x8 pa[4];
#pragma unroll
        for (int s = 0; s < 4; ++s)
#pragma unroll
            for (int r = 0; r < 4; ++r) {
                pa[s][r] = (__bf16)sv[2 * s][r];
                pa[s][4 + r] = (__bf16)sv[2 * s + 1][r];
            }
        if (t < qc) {
#pragma unroll
            for (int ct = 0; ct < 4; ++ct) {
                const __bf16* vrow = &Vs[cur][(ct * 16 + lr) * 128];
#pragma unroll
                for (int s = 0; s < 4; ++s) {
                    const bf16x8 vf = *(const bf16x8*)&vrow[(((s * 4 + g) ^ lr) << 3)];
                    acc[ct] = MFMA_16x16x32_BF16(pa[s], vf, acc[ct]);
                }
            }
        } else {
#pragma unroll
            for (int ct = 0; ct < 4; ++ct) {
                const __bf16* vrow = &Vs[cur][(ct * 16 + lr) * 128];
#pragma unroll
                for (int s = 0; s < 4; ++s) {
                    if (kvb + s * 32 <= qbase + 15) {
                        const bf16x8 vf = *(const bf16x8*)&vrow[(((s * 4 + g) ^ lr) << 3)];
                        acc[ct] = MFMA_16x16x32_BF16(pa[s], vf, acc[ct]);
                    }
                }
            }
        }
        __syncthreads();
    }

    const float il = __builtin_amdgcn_rcpf(l_s);
    float dn[4];
#pragma unroll
    for (int r = 0; r < 4; ++r) dn[r] = __shfl(il, 4 * g + r);
#pragma unroll
    for (int ct = 0; ct < 4; ++ct)
#pragma unroll
        for (int r = 0; r < 4; ++r)
            ctx[(rowoff + qbase + 4 * g + r) * Dm + h * 64 + ct * 16 + lr] =
                (__bf16)(acc[ct][r] * dn[r]);
}

// ---------------------------------------------------------------------------
extern "C" void kernel_launch(void* const* d_in, const int* in_sizes, int n_in,
                              void* d_out, int out_size, void* d_ws, size_t ws_size,
                              hipStream_t stream)
{
    (void)in_sizes; (void)n_in; (void)out_size; (void)ws_size;
    const float* z      = (const float*)d_in[0];
    const float* W_Q    = (const float*)d_in[1];
    const float* W_K    = (const float*)d_in[2];
    const float* W_V    = (const float*)d_in[3];
    const float* W_O    = (const float*)d_in[4];
    const float* W_fc   = (const float*)d_in[5];
    const float* W_proj = (const float*)d_in[6];
    const float* g1     = (const float*)d_in[7];
    const float* g2     = (const float*)d_in[8];
    float* out = (float*)d_out;

    char* ws = (char*)d_ws;
    const size_t MB = (size_t)1 << 20;
    __bf16* WtQKV  = (__bf16*)(ws + 0 * MB);   // [3072][1024]
    __bf16* WtO    = (__bf16*)(ws + 6 * MB);
    __bf16* Wtfc   = (__bf16*)(ws + 8 * MB);
    __bf16* Wtproj = (__bf16*)(ws + 16 * MB);
    __bf16* zn     = (__bf16*)(ws + 24 * MB);  // reused as ctx
    __bf16* Qb     = (__bf16*)(ws + 32 * MB);  // QKV out base; reused as h
    __bf16* Kbuf   = (__bf16*)(ws + 40 * MB);
    __bf16* Vtb    = (__bf16*)(ws + 48 * MB);
    __bf16* ffn1   = (__bf16*)(ws + 40 * MB);  // overlaps K,Vt (dead post-attn)
    float*  part0  = (float*)(ws + 0 * MB);    // 16MB: over dead WtQKV/WtO/Wtfc
    float*  part1  = (float*)(ws + 24 * MB);   // 16MB: over dead ctx + h
    __bf16* ctx    = zn;
    __bf16* hb     = Qb;

    const int Tt = 2048, Dm = 1024, Bb = 2, M = Bb * Tt, DFF = 4096;
    const dim3 blk256(256), blk512(512);

    // fused: weight transposes + rmsnorm(z, g1) -> zn
    fused_head_kernel<<<16384, blk256, 0, stream>>>(
        W_Q, W_K, W_V, W_O, W_fc, W_proj, WtQKV, WtO, Wtfc, Wtproj, z, g1, zn);

    // Fused QKV (2-phase 128x128, 768 blocks): [4096][3072]
    gemm_bf16<128, 128, 4><<<dim3(24, 32), blk256, 0, stream>>>(
        zn, WtQKV, Qb, nullptr, M, 3072, Dm, Dm);

    // attention -> ctx (8-wave blocks, KVBLK=128, fast path)
    attn_kernel<<<512, blk512, 0, stream>>>(Qb, Kbuf, Vtb, ctx);

    // z2 = z + ctx @ W_O  -> d_out (fp32)
    gemm_bf16<128, 64, 1><<<dim3(16, 32), blk256, 0, stream>>>(
        ctx, WtO, out, z, M, Dm, Dm, Dm);

    // h = rmsnorm(z2, g2)
    rmsnorm_kernel<<<M, blk256, 0, stream>>>(out, g2, hb);

    // ffn1 = gelu(h @ W_fc) (8-phase 256^2, 256 blocks = 1/CU exactly)
    gemm256<2><<<dim3(16, 16), blk512, 0, stream>>>(
        hb, Wtfc, ffn1, nullptr, M, DFF, Dm);

    // proj split-K=2 (128x128, 512 blocks): fp32 partials p0/p1
    gemm_bf16<128, 128, 5><<<dim3(8, 32, 2), blk256, 0, stream>>>(
        ffn1, Wtproj, part0, (const float*)part1, M, Dm, DFF / 2, DFF);

    // d_out += p0 + p1
    reduce_add_kernel<<<2048, blk256, 0, stream>>>(out, part0, part1, M * Dm / 4);
}

// Round 14
// 234.977 us; speedup vs baseline: 1.3441x; 1.0123x over previous
//
#include <hip/hip_runtime.h>
#include <hip/hip_bf16.h>
#include <math.h>

// ---------------------------------------------------------------------------
// GPT block on MI355X (gfx950). bf16 MFMA compute, fp32 accumulate.
// Workspace layout (MB = 1<<20), total 72 MB:
//   [ 0, 6)  WtQKV  bf16 [3072][1024]   -- dead after QKV; reused as partial0
//   [ 6, 8)  WtO    bf16 [1024][1024]   -- dead after O-proj  (part of p0)
//   [ 8,16)  Wtfc   bf16 [4096][1024]   -- dead after fc      (part of p0)
//   [16,24)  Wtproj bf16 [1024][4096]
//   [24,32)  zn / ctx   bf16            -- dead after O-proj; partial1
//   [32,40)  Q / h      bf16            -- dead after fc      (part of p1)
//   [40,48)  K          bf16
//   [48,56)  Vt         bf16 [32][64][2048]  (V transposed, kv-permuted)
//   [40,72)  ffn1       bf16 [4096][4096]  (overlaps K,Vt — dead after attn)
// fc: 8-phase 256^2 + 2D XCD regions. proj: split-K=2 partials + reduce.
// QKV: 2-phase 128^2 + 2D XCD regions (8m x 12n per XCD -> 5MB L2 set).
// attn: 8-wave KVBLK=128, FULL fast path, fully-deferred softmax reduces.
// ---------------------------------------------------------------------------

typedef __bf16 bf16x8 __attribute__((ext_vector_type(8)));
typedef float  f32x4  __attribute__((ext_vector_type(4)));

#define MFMA_16x16x32_BF16(A, B, C) __builtin_amdgcn_mfma_f32_16x16x32_bf16((A), (B), (C), 0, 0, 0)

#define GLDS16(g, l) __builtin_amdgcn_global_load_lds( \
    (const __attribute__((address_space(1))) void*)(g), \
    (__attribute__((address_space(3))) void*)(l), 16, 0, 0)

// ---------------- fused head: 6 weight transposes + rmsnorm(z,g1) -----------
__global__ __launch_bounds__(256) void fused_head_kernel(
    const float* __restrict__ W_Q, const float* __restrict__ W_K,
    const float* __restrict__ W_V, const float* __restrict__ W_O,
    const float* __restrict__ W_fc, const float* __restrict__ W_proj,
    __bf16* __restrict__ WtQKV, __bf16* __restrict__ WtO,
    __bf16* __restrict__ Wtfc, __bf16* __restrict__ Wtproj,
    const float* __restrict__ z, const float* __restrict__ g1,
    __bf16* __restrict__ zn)
{
    const int id = blockIdx.x;
    if (id >= 12288) {
        const int row = id - 12288, t = threadIdx.x;
        const float4 v = ((const float4*)(z + (size_t)row * 1024))[t];
        float ss = v.x * v.x + v.y * v.y + v.z * v.z + v.w * v.w;
#pragma unroll
        for (int m = 1; m < 64; m <<= 1) ss += __shfl_xor(ss, m);
        __shared__ float red[4];
        const int wid = t >> 6, lane = t & 63;
        if (lane == 0) red[wid] = ss;
        __syncthreads();
        const float tot = red[0] + red[1] + red[2] + red[3];
        const float inv = rsqrtf(tot * (1.0f / 1024.0f) + 1e-5f);
        const float4 gv = ((const float4*)g1)[t];
        __bf16* o = zn + (size_t)row * 1024 + t * 4;
        o[0] = (__bf16)(v.x * inv * gv.x);
        o[1] = (__bf16)(v.y * inv * gv.y);
        o[2] = (__bf16)(v.z * inv * gv.z);
        o[3] = (__bf16)(v.w * inv * gv.w);
        return;
    }
    const float* src;
    __bf16* dst;
    int K, N, nx, t;
    if (id < 4096) {
        const int wsel = id >> 10;
        t = id & 1023;
        src = (wsel == 0) ? W_Q : (wsel == 1) ? W_K : (wsel == 2) ? W_V : W_O;
        dst = (wsel < 3) ? (WtQKV + (size_t)wsel * 1048576) : WtO;
        K = 1024; N = 1024; nx = 32;
    } else if (id < 8192) {
        t = id - 4096; src = W_fc; dst = Wtfc; K = 1024; N = 4096; nx = 128;
    } else {
        t = id - 8192; src = W_proj; dst = Wtproj; K = 4096; N = 1024; nx = 32;
    }
    const int n0 = (t % nx) * 32, k0 = (t / nx) * 32;

    __shared__ float tile[32][33];
    const int c = threadIdx.x & 31, r = threadIdx.x >> 5;
#pragma unroll
    for (int i = 0; i < 4; ++i)
        tile[r + 8 * i][c] = src[(size_t)(k0 + r + 8 * i) * N + n0 + c];
    __syncthreads();
#pragma unroll
    for (int i = 0; i < 4; ++i)
        dst[(size_t)(n0 + r + 8 * i) * K + k0 + c] = (__bf16)tile[c][r + 8 * i];
}

// ---------------- RMSNorm: fp32 [M][1024] -> bf16 [M][1024] -----------------
__global__ __launch_bounds__(256) void rmsnorm_kernel(
    const float* __restrict__ x, const float* __restrict__ gain,
    __bf16* __restrict__ out)
{
    const int row = blockIdx.x, t = threadIdx.x;
    const float4 v = ((const float4*)(x + (size_t)row * 1024))[t];
    float ss = v.x * v.x + v.y * v.y + v.z * v.z + v.w * v.w;
#pragma unroll
    for (int m = 1; m < 64; m <<= 1) ss += __shfl_xor(ss, m);
    __shared__ float red[4];
    const int wid = t >> 6, lane = t & 63;
    if (lane == 0) red[wid] = ss;
    __syncthreads();
    const float tot = red[0] + red[1] + red[2] + red[3];
    const float inv = rsqrtf(tot * (1.0f / 1024.0f) + 1e-5f);
    const float4 gv = ((const float4*)gain)[t];
    __bf16* o = out + (size_t)row * 1024 + t * 4;
    o[0] = (__bf16)(v.x * inv * gv.x);
    o[1] = (__bf16)(v.y * inv * gv.y);
    o[2] = (__bf16)(v.z * inv * gv.z);
    o[3] = (__bf16)(v.w * inv * gv.w);
}

// ---------------- reduce: out += p0 + p1 (fp32, float4 grid-stride) ---------
__global__ __launch_bounds__(256) void reduce_add_kernel(
    float* __restrict__ out, const float* __restrict__ p0,
    const float* __restrict__ p1, int n4)
{
    for (int i = blockIdx.x * 256 + threadIdx.x; i < n4; i += gridDim.x * 256) {
        const float4 a = ((const float4*)p0)[i];
        const float4 b = ((const float4*)p1)[i];
        float4 o = ((float4*)out)[i];
        o.x += a.x + b.x; o.y += a.y + b.y;
        o.z += a.z + b.z; o.w += a.w + b.w;
        ((float4*)out)[i] = o;
    }
}

// ---------------- C-write helper --------------------------------------------
template <int EPI>
__device__ __forceinline__ void epi_write(
    void* outp, const float* res, int N, int rowg, int colg, float v)
{
    if constexpr (EPI == 1) {
        const size_t idx = (size_t)rowg * N + colg;
        ((float*)outp)[idx] = res[idx] + v;
    } else if constexpr (EPI == 2) {
        // gelu, tanh form via exp2 (|diff vs erf-gelu| <~1e-3, << bf16 eps here)
        const size_t idx = (size_t)rowg * N + colg;
        const float u = v * (1.0f + 0.044715f * v * v) * 2.3022585093f;
        const float r = __builtin_amdgcn_rcpf(1.0f + exp2f(u));
        ((__bf16*)outp)[idx] = (__bf16)(v - v * r);
    } else {  // EPI == 4: QKV split
        __bf16* base = (__bf16*)outp;
        const int seg = colg >> 10;       // 0=Q, 1=K, 2=V
        const int cg = colg & 1023;
        if (seg < 2) {
            base[(size_t)seg * 4194304 + (size_t)rowg * 1024 + cg] = (__bf16)v;
        } else {
            // Vt[b][h][d][t'] with within-32 t-permutation: 16h+4g+j -> 8g+4h+j
            const int tt = rowg & 2047;
            const int r32 = tt & 31;
            const int p = ((r32 & 12) << 1) | ((r32 >> 2) & 4) | (r32 & 3);
            base[8388608 +
                 ((size_t)((rowg >> 11) * 16 + (cg >> 6)) * 64 + (cg & 63)) * 2048 +
                 ((tt & ~31) | p)] = (__bf16)v;
        }
    }
}

// ---------------- 8-phase 256x256 GEMM (m201 template) ----------------------
// 2D XCD regions for the fc geometry (16x16 grid): each XCD owns a 4m x 8n
// region -> per-XCD L2 working set 6MB (was 2m-row x 16n = 9MB).
template <int EPI>
__global__ __launch_bounds__(512, 2) void gemm256(
    const __bf16* __restrict__ A, const __bf16* __restrict__ Bt,
    void* __restrict__ outp, const float* __restrict__ res,
    int M, int N, int K)
{
    __shared__ __bf16 As[2][2][128 * 64];   // [dbuf][half][row*64+elem]
    __shared__ __bf16 Bs[2][2][128 * 64];
    const int tid = threadIdx.x;

    const int gx = gridDim.x, nwg = gx * gridDim.y;
    int bid = blockIdx.y * gx + blockIdx.x;
    int m0, n0;
    if (gx == 16 && gridDim.y == 16) {
        const int xcd = bid & 7, c = bid >> 3;   // c in [0,32)
        const int rm = xcd >> 1, rn = xcd & 1;   // 4 x 2 regions
        m0 = (rm * 4 + (c >> 3)) * 256;
        n0 = (rn * 8 + (c & 7)) * 256;
    } else {
        if ((nwg & 7) == 0) bid = (bid & 7) * (nwg >> 3) + (bid >> 3);
        m0 = (bid / gx) * 256; n0 = (bid % gx) * 256;
    }

    const int lane = tid & 63, w = tid >> 6;         // 8 waves
    const int wr = w >> 2, wc = w & 3;               // 2 x 4 wave grid
    const int lr = lane & 15, g = lane >> 4;
    const int srow8 = lane >> 3, schunk = (lane & 7) ^ srow8;
    const int xk = lr & 7;
    const int wch = wc >> 1, bro = (wc & 1) * 64;    // B half / row offset

    const __bf16* Ab = A + (size_t)m0 * K;
    const __bf16* Bb = Bt + (size_t)n0 * K;

    auto STG = [&](const __bf16* gb, __bf16* lds, int kt, int half) {
        const __bf16* src = gb + (size_t)(half * 128) * K + (kt << 6);
#pragma unroll
        for (int j = 0; j < 2; ++j) {
            const int sidx = j * 8 + w;
            GLDS16(src + (size_t)(sidx * 8 + srow8) * K + schunk * 8, lds + sidx * 512);
        }
    };

    f32x4 acc[8][4] = {};
    bf16x8 af[2][4], bf[2][4];

#define LAF(BUF, QM) do {                                                       \
    _Pragma("unroll") for (int i_ = 0; i_ < 4; ++i_)                            \
    _Pragma("unroll") for (int kk_ = 0; kk_ < 2; ++kk_)                         \
        af[kk_][i_] = *(const bf16x8*)&As[BUF][wr]                              \
            [((QM) * 64 + i_ * 16 + lr) * 64 + (((kk_ * 4 + g) ^ xk) << 3)];    \
    } while (0)

#define LBF(BUF, QN) do {                                                       \
    _Pragma("unroll") for (int i_ = 0; i_ < 2; ++i_)                            \
    _Pragma("unroll") for (int kk_ = 0; kk_ < 2; ++kk_)                         \
        bf[kk_][(QN) * 2 + i_] = *(const bf16x8*)&Bs[BUF][wch]                  \
            [(bro + ((QN) * 2 + i_) * 16 + lr) * 64 + (((kk_ * 4 + g) ^ xk) << 3)]; \
    } while (0)

#define MMQ(QM, QN) do {                                                        \
    __builtin_amdgcn_s_setprio(1);                                              \
    _Pragma("unroll") for (int kk_ = 0; kk_ < 2; ++kk_)                         \
    _Pragma("unroll") for (int i_ = 0; i_ < 4; ++i_)                            \
    _Pragma("unroll") for (int n_ = 0; n_ < 2; ++n_)                            \
        acc[(QM) * 4 + i_][(QN) * 2 + n_] = MFMA_16x16x32_BF16(                 \
            af[kk_][i_], bf[kk_][(QN) * 2 + n_], acc[(QM) * 4 + i_][(QN) * 2 + n_]); \
    __builtin_amdgcn_s_setprio(0);                                              \
    } while (0)

#define BAR()  __builtin_amdgcn_s_barrier()
#define VMC(N_) asm volatile("s_waitcnt vmcnt(" #N_ ")" ::: "memory")
#define SGB0() __builtin_amdgcn_sched_barrier(0)

    const int nt = K >> 6, niter = nt >> 1;

    STG(Ab, &As[0][0][0], 0, 0); STG(Ab, &As[0][1][0], 0, 1);
    STG(Bb, &Bs[0][0][0], 0, 0); STG(Bb, &Bs[0][1][0], 0, 1);
    STG(Bb, &Bs[1][0][0], 1, 0); STG(Bb, &Bs[1][1][0], 1, 1);

    for (int i = 0; i < niter - 1; ++i) {
        const int t1 = 2 * i + 1;
        STG(Ab, &As[1][0][0], t1, 0);
        VMC(6); BAR(); SGB0();
        LAF(0, 0); LBF(0, 0); MMQ(0, 0); BAR();
        LBF(0, 1); STG(Ab, &As[1][1][0], t1, 1); BAR(); MMQ(0, 1); BAR();
        LAF(0, 1); STG(Bb, &Bs[0][0][0], t1 + 1, 0); BAR(); MMQ(1, 0); BAR();
        STG(Bb, &Bs[0][1][0], t1 + 1, 1); BAR(); MMQ(1, 1); BAR();
        STG(Ab, &As[0][0][0], t1 + 1, 0);
        VMC(6); BAR(); SGB0();
        LAF(1, 0); LBF(1, 0); MMQ(0, 0); BAR();
        LBF(1, 1); STG(Ab, &As[0][1][0], t1 + 1, 1); BAR(); MMQ(0, 1); BAR();
        LAF(1, 1); STG(Bb, &Bs[1][0][0], t1 + 2, 0); BAR(); MMQ(1, 0); BAR();
        STG(Bb, &Bs[1][1][0], t1 + 2, 1); BAR(); MMQ(1, 1); BAR();
    }
    {   // peeled last iteration
        STG(Ab, &As[1][0][0], nt - 1, 0);
        VMC(6); BAR(); SGB0();
        LAF(0, 0); LBF(0, 0); MMQ(0, 0); BAR();
        LBF(0, 1); STG(Ab, &As[1][1][0], nt - 1, 1); BAR(); MMQ(0, 1); BAR();
        LAF(0, 1); BAR(); MMQ(1, 0); BAR();
        BAR(); MMQ(1, 1); BAR();
        VMC(0); BAR(); SGB0();
        LAF(1, 0); LBF(1, 0); MMQ(0, 0); BAR();
        LBF(1, 1); BAR(); MMQ(0, 1); BAR();
        LAF(1, 1); BAR(); MMQ(1, 0); BAR();
        BAR(); MMQ(1, 1); BAR();
    }
#undef LAF
#undef LBF
#undef MMQ
#undef BAR
#undef VMC
#undef SGB0

#pragma unroll
    for (int mi = 0; mi < 8; ++mi)
#pragma unroll
        for (int ni = 0; ni < 4; ++ni) {
            const int colg = n0 + wc * 64 + ni * 16 + lr;
#pragma unroll
            for (int r = 0; r < 4; ++r) {
                const int rowg = m0 + wr * 128 + mi * 16 + 4 * g + r;
                epi_write<EPI>(outp, res, N, rowg, colg, acc[mi][ni][r]);
            }
        }
}

// ---------------- 2-phase 128xBN dbuf GEMM (split-K capable) ----------------
// EPI 5: store fp32 partial (part 0 -> outp, part 1 -> res cast).
// EPI 4 (QKV, 24x32 grid): 2D XCD regions, 8m x 12n per XCD (5MB L2 set).
template <int BM, int BN, int EPI>
__global__ __launch_bounds__(256) void gemm_bf16(
    const __bf16* __restrict__ A, const __bf16* __restrict__ Bt,
    void* __restrict__ outp, const float* __restrict__ res,
    int M, int N, int K, int Kld)
{
    __shared__ __bf16 As[2][BM * 64];
    __shared__ __bf16 Bs[2][BN * 64];
    const int tid = threadIdx.x;

    const int gx = gridDim.x, nwg = gx * gridDim.y;
    int bid = blockIdx.y * gx + blockIdx.x;
    int m0, n0;
    if constexpr (EPI == 4) {
        // gx = 24, gy = 32: regions of 8m x 12n per XCD
        const int xcd = bid & 7, c = bid >> 3;   // c in [0,96)
        const int rm = xcd >> 1, rn = xcd & 1;   // 4 x 2 regions
        m0 = (rm * 8 + c / 12) * BM;
        n0 = (rn * 12 + c % 12) * BN;
    } else {
        if ((nwg & 7) == 0) bid = (bid & 7) * (nwg >> 3) + (bid >> 3);
        m0 = (bid / gx) * BM; n0 = (bid % gx) * BN;
    }

    const int lane = tid & 63, w = tid >> 6;
    const int wm = w >> 1, wn = w & 1;
    const int lr = lane & 15, g = lane >> 4;
    const int srow = lane >> 3;
    const int scol = ((lane & 7) ^ srow) * 8;
    const int xr8 = lr & 7;

    constexpr int MI = BM / 32, NI = BN / 32;
    f32x4 acc[MI][NI] = {};

    const __bf16* Abase = A + (size_t)m0 * Kld + blockIdx.z * K;
    const __bf16* Bbase = Bt + (size_t)n0 * Kld + blockIdx.z * K;

    auto STAGE = [&](int kb, int buf) {
#pragma unroll
        for (int j = 0; j < BM / 32; ++j) {
            const int s = j * 4 + w;
            GLDS16(Abase + (size_t)(s * 8 + srow) * Kld + kb + scol, &As[buf][s * 512]);
        }
#pragma unroll
        for (int j = 0; j < BN / 32; ++j) {
            const int s = j * 4 + w;
            GLDS16(Bbase + (size_t)(s * 8 + srow) * Kld + kb + scol, &Bs[buf][s * 512]);
        }
    };

    const int nt = K >> 6;
    STAGE(0, 0);
    __syncthreads();

    for (int t = 0; t < nt; ++t) {
        const int cur = t & 1;
        if (t + 1 < nt) STAGE((t + 1) << 6, cur ^ 1);

        bf16x8 af[2][MI], bfr[2][NI];
#pragma unroll
        for (int kk = 0; kk < 2; ++kk) {
#pragma unroll
            for (int i = 0; i < MI; ++i)
                af[kk][i] = *(const bf16x8*)
                    &As[cur][(wm * (BM / 2) + i * 16 + lr) * 64 + (((kk * 4 + g) ^ xr8) << 3)];
#pragma unroll
            for (int i = 0; i < NI; ++i)
                bfr[kk][i] = *(const bf16x8*)
                    &Bs[cur][(wn * (BN / 2) + i * 16 + lr) * 64 + (((kk * 4 + g) ^ xr8) << 3)];
        }
#pragma unroll
        for (int kk = 0; kk < 2; ++kk)
#pragma unroll
            for (int mi = 0; mi < MI; ++mi)
#pragma unroll
                for (int ni = 0; ni < NI; ++ni)
                    acc[mi][ni] = MFMA_16x16x32_BF16(af[kk][mi], bfr[kk][ni], acc[mi][ni]);
        if (t + 1 < nt) __syncthreads();
    }

#pragma unroll
    for (int mi = 0; mi < MI; ++mi)
#pragma unroll
        for (int ni = 0; ni < NI; ++ni) {
            const int colg = n0 + wn * (BN / 2) + ni * 16 + lr;
#pragma unroll
            for (int r = 0; r < 4; ++r) {
                const int rowg = m0 + wm * (BM / 2) + mi * 16 + 4 * g + r;
                const float v = acc[mi][ni][r];
                if constexpr (EPI == 5) {
                    float* pout = (blockIdx.z == 0) ? (float*)outp : (float*)(void*)res;
                    pout[(size_t)rowg * N + colg] = v;
                } else {
                    epi_write<EPI>(outp, res, N, rowg, colg, v);
                }
            }
        }
}

// ---------------- Flash-style causal attention (8-wave, KVBLK=128) ----------
// Grid: 512 blocks = j*32 + bh, j in [0,16). qc = j<8 ? j : 23-j (balanced).
// Block-uniform FULL fast path for t<qc. Softmax reductions fully deferred:
// per-lane max check + per-lane partial sum; cross-lane reduces only on
// (rare) rescale events and once at the end.
__global__ __launch_bounds__(512) void attn_kernel(
    const __bf16* __restrict__ Q, const __bf16* __restrict__ Kb,
    const __bf16* __restrict__ Vt, __bf16* __restrict__ ctx)
{
    const int Dm = 1024, T = 2048;
    const int tid = threadIdx.x;
    const int w = tid >> 6, lane = tid & 63;
    const int lr = lane & 15, g = lane >> 4;
    const int bx = blockIdx.x;
    const int j = bx >> 5, bh = bx & 31, b = bh >> 4, h = bh & 15;
    const int qc = (j < 8) ? j : 23 - j;            // balanced bijection 0..15
    const int qbase = qc * 128 + w * 16;
    const size_t rowoff = (size_t)b * T;
    const __bf16* Qp = Q + rowoff * Dm + h * 64;
    const __bf16* Kp = Kb + rowoff * Dm + h * 64;
    const __bf16* Vtp = Vt + (size_t)bh * 64 * 2048;

    __shared__ __bf16 Ks[2][128 * 64];
    __shared__ __bf16 Vs[2][64 * 128];

    bf16x8 qf0 = *(const bf16x8*)&Qp[(size_t)(qbase + lr) * Dm + g * 8];
    bf16x8 qf1 = *(const bf16x8*)&Qp[(size_t)(qbase + lr) * Dm + 32 + g * 8];
    const float qsc = 0.125f * 1.44269504088896340736f;
#pragma unroll
    for (int jj = 0; jj < 8; ++jj) {
        qf0[jj] = (__bf16)((float)qf0[jj] * qsc);
        qf1[jj] = (__bf16)((float)qf1[jj] * qsc);
    }

    const int ksrow = lane >> 3;
    const int kschunk = (lane & 7) ^ ksrow;
    const int vsrow = lane >> 4;                    // 0..3

    f32x4 acc[4] = {};
    float m_s = -__builtin_inff(), lpart = 0.0f;    // lane-local partial sum
    const int nsteps = qc + 1;
    const f32x4 zacc = {0.0f, 0.0f, 0.0f, 0.0f};
    const int x8 = lr & 7;                          // K read chunk XOR
    const int qg = qbase + lr;

    auto STAGE = [&](int kvb, int buf) {
#pragma unroll
        for (int jj = 0; jj < 2; ++jj) {
            const int krow = w * 16 + jj * 8;
            GLDS16(Kp + (size_t)(kvb + krow + ksrow) * Dm + kschunk * 8,
                   &Ks[buf][krow * 64]);
            const int vrow = w * 8 + jj * 4;
            const int vchunk = (lane & 15) ^ ((vrow + vsrow) & 15);
            GLDS16(Vtp + (size_t)(vrow + vsrow) * T + kvb + vchunk * 8,
                   &Vs[buf][vrow * 128]);
        }
    };

    STAGE(0, 0);
    __syncthreads();

    for (int t = 0; t < nsteps; ++t) {
        const int kvb = t * 128, cur = t & 1;
        if (t + 1 < nsteps) STAGE(kvb + 128, cur ^ 1);

        float sv[8][4];
        if (t < qc) {
            // ---- FULL fast path: whole 128-kv tile live, no mask logic ----
#pragma unroll
            for (int s4 = 0; s4 < 8; ++s4) {
                const int row = s4 * 16 + lr;
                const bf16x8 kfa = *(const bf16x8*)&Ks[cur][row * 64 + ((g ^ x8) << 3)];
                const bf16x8 kfb = *(const bf16x8*)&Ks[cur][row * 64 + (((4 + g) ^ x8) << 3)];
                f32x4 st = MFMA_16x16x32_BF16(kfa, qf0, zacc);
                st = MFMA_16x16x32_BF16(kfb, qf1, st);
#pragma unroll
                for (int r = 0; r < 4; ++r) sv[s4][r] = st[r];
            }
        } else {
            // ---- diagonal step: per-subtile guards + causal mask ----
#pragma unroll
            for (int s4 = 0; s4 < 8; ++s4) {
                const int kv0 = kvb + s4 * 16;
                if (kv0 <= qbase + 15) {
                    const int row = s4 * 16 + lr;
                    const bf16x8 kfa = *(const bf16x8*)&Ks[cur][row * 64 + ((g ^ x8) << 3)];
                    const bf16x8 kfb = *(const bf16x8*)&Ks[cur][row * 64 + (((4 + g) ^ x8) << 3)];
                    f32x4 st = MFMA_16x16x32_BF16(kfa, qf0, zacc);
                    st = MFMA_16x16x32_BF16(kfb, qf1, st);
                    const bool domask = (kv0 + 15 > qbase);
#pragma unroll
                    for (int r = 0; r < 4; ++r) {
                        float x = st[r];
                        if (domask && (kv0 + 4 * g + r > qg)) x = -__builtin_inff();
                        sv[s4][r] = x;
                    }
                } else {
#pragma unroll
                    for (int r = 0; r < 4; ++r) sv[s4][r] = -__builtin_inff();
                }
            }
        }

        // ---- deferred online softmax (log2 domain) ----
        // lane-local max; __all over 64 lanes == row-max check
        float tml = sv[0][0];
#pragma unroll
        for (int s4 = 0; s4 < 8; ++s4)
#pragma unroll
            for (int r = 0; r < 4; ++r) tml = fmaxf(tml, sv[s4][r]);

        if (!__all(tml - m_s <= 11.5f)) {
            float tm = fmaxf(tml, __shfl_xor(tml, 16));
            tm = fmaxf(tm, __shfl_xor(tm, 32));
            const float m_new = fmaxf(m_s, tm);
            const float corr = exp2f(m_s - m_new);
            lpart *= corr;
            float cr[4];
#pragma unroll
            for (int r = 0; r < 4; ++r) cr[r] = __shfl(corr, 4 * g + r);
#pragma unroll
            for (int ct = 0; ct < 4; ++ct) {
                acc[ct][0] *= cr[0]; acc[ct][1] *= cr[1];
                acc[ct][2] *= cr[2]; acc[ct][3] *= cr[3];
            }
            m_s = m_new;
        }

        float rsl = 0.0f;
#pragma unroll
        for (int s4 = 0; s4 < 8; ++s4)
#pragma unroll
            for (int r = 0; r < 4; ++r) {
                sv[s4][r] = exp2f(sv[s4][r] - m_s);
                rsl += sv[s4][r];
            }
        lpart += rsl;

        // ---- PV ----
        bf16x8 pa[4];
#pragma unroll
        for (int s = 0; s < 4; ++s)
#pragma unroll
            for (int r = 0; r < 4; ++r) {
                pa[s][r] = (__bf16)sv[2 * s][r];
                pa[s][4 + r] = (__bf16)sv[2 * s + 1][r];
            }
        if (t < qc) {
#pragma unroll
            for (int ct = 0; ct < 4; ++ct) {
                const __bf16* vrow = &Vs[cur][(ct * 16 + lr) * 128];
#pragma unroll
                for (int s = 0; s < 4; ++s) {
                    const bf16x8 vf = *(const bf16x8*)&vrow[(((s * 4 + g) ^ lr) << 3)];
                    acc[ct] = MFMA_16x16x32_BF16(pa[s], vf, acc[ct]);
                }
            }
        } else {
#pragma unroll
            for (int ct = 0; ct < 4; ++ct) {
                const __bf16* vrow = &Vs[cur][(ct * 16 + lr) * 128];
#pragma unroll
                for (int s = 0; s < 4; ++s) {
                    if (kvb + s * 32 <= qbase + 15) {
                        const bf16x8 vf = *(const bf16x8*)&vrow[(((s * 4 + g) ^ lr) << 3)];
                        acc[ct] = MFMA_16x16x32_BF16(pa[s], vf, acc[ct]);
                    }
                }
            }
        }
        __syncthreads();
    }

    // final row-sum reduce (once)
    lpart += __shfl_xor(lpart, 16);
    lpart += __shfl_xor(lpart, 32);
    const float il = __builtin_amdgcn_rcpf(lpart);
    float dn[4];
#pragma unroll
    for (int r = 0; r < 4; ++r) dn[r] = __shfl(il, 4 * g + r);
#pragma unroll
    for (int ct = 0; ct < 4; ++ct)
#pragma unroll
        for (int r = 0; r < 4; ++r)
            ctx[(rowoff + qbase + 4 * g + r) * Dm + h * 64 + ct * 16 + lr] =
                (__bf16)(acc[ct][r] * dn[r]);
}

// ---------------------------------------------------------------------------
extern "C" void kernel_launch(void* const* d_in, const int* in_sizes, int n_in,
                              void* d_out, int out_size, void* d_ws, size_t ws_size,
                              hipStream_t stream)
{
    (void)in_sizes; (void)n_in; (void)out_size; (void)ws_size;
    const float* z      = (const float*)d_in[0];
    const float* W_Q    = (const float*)d_in[1];
    const float* W_K    = (const float*)d_in[2];
    const float* W_V    = (const float*)d_in[3];
    const float* W_O    = (const float*)d_in[4];
    const float* W_fc   = (const float*)d_in[5];
    const float* W_proj = (const float*)d_in[6];
    const float* g1     = (const float*)d_in[7];
    const float* g2     = (const float*)d_in[8];
    float* out = (float*)d_out;

    char* ws = (char*)d_ws;
    const size_t MB = (size_t)1 << 20;
    __bf16* WtQKV  = (__bf16*)(ws + 0 * MB);   // [3072][1024]
    __bf16* WtO    = (__bf16*)(ws + 6 * MB);
    __bf16* Wtfc   = (__bf16*)(ws + 8 * MB);
    __bf16* Wtproj = (__bf16*)(ws + 16 * MB);
    __bf16* zn     = (__bf16*)(ws + 24 * MB);  // reused as ctx
    __bf16* Qb     = (__bf16*)(ws + 32 * MB);  // QKV out base; reused as h
    __bf16* Kbuf   = (__bf16*)(ws + 40 * MB);
    __bf16* Vtb    = (__bf16*)(ws + 48 * MB);
    __bf16* ffn1   = (__bf16*)(ws + 40 * MB);  // overlaps K,Vt (dead post-attn)
    float*  part0  = (float*)(ws + 0 * MB);    // 16MB: over dead WtQKV/WtO/Wtfc
    float*  part1  = (float*)(ws + 24 * MB);   // 16MB: over dead ctx + h
    __bf16* ctx    = zn;
    __bf16* hb     = Qb;

    const int Tt = 2048, Dm = 1024, Bb = 2, M = Bb * Tt, DFF = 4096;
    const dim3 blk256(256), blk512(512);

    // fused: weight transposes + rmsnorm(z, g1) -> zn
    fused_head_kernel<<<16384, blk256, 0, stream>>>(
        W_Q, W_K, W_V, W_O, W_fc, W_proj, WtQKV, WtO, Wtfc, Wtproj, z, g1, zn);

    // Fused QKV (2-phase 128x128, 768 blocks, 2D XCD regions): [4096][3072]
    gemm_bf16<128, 128, 4><<<dim3(24, 32), blk256, 0, stream>>>(
        zn, WtQKV, Qb, nullptr, M, 3072, Dm, Dm);

    // attention -> ctx (8-wave blocks, KVBLK=128, deferred softmax reduces)
    attn_kernel<<<512, blk512, 0, stream>>>(Qb, Kbuf, Vtb, ctx);

    // z2 = z + ctx @ W_O  -> d_out (fp32)
    gemm_bf16<128, 64, 1><<<dim3(16, 32), blk256, 0, stream>>>(
        ctx, WtO, out, z, M, Dm, Dm, Dm);

    // h = rmsnorm(z2, g2)
    rmsnorm_kernel<<<M, blk256, 0, stream>>>(out, g2, hb);

    // ffn1 = gelu(h @ W_fc) (8-phase 256^2, 2D XCD regions)
    gemm256<2><<<dim3(16, 16), blk512, 0, stream>>>(
        hb, Wtfc, ffn1, nullptr, M, DFF, Dm);

    // proj split-K=2 (128x128, 512 blocks): fp32 partials p0/p1
    gemm_bf16<128, 128, 5><<<dim3(8, 32, 2), blk256, 0, stream>>>(
        ffn1, Wtproj, part0, (const float*)part1, M, Dm, DFF / 2, DFF);

    // d_out += p0 + p1
    reduce_add_kernel<<<2048, blk256, 0, stream>>>(out, part0, part1, M * Dm / 4);
}

// Round 15
// 232.821 us; speedup vs baseline: 1.3565x; 1.0093x over previous
//
#include <hip/hip_runtime.h>
#include <hip/hip_bf16.h>
#include <math.h>

// ---------------------------------------------------------------------------
// GPT block on MI355X (gfx950). bf16 MFMA compute, fp32 accumulate.
// Workspace layout (MB = 1<<20), total 72 MB:
//   [ 0, 6)  WtQKV  bf16 [3072][1024]   -- dead after QKV; partial0 (bf16 8MB)
//   [ 6, 8)  WtO    bf16 [1024][1024]   -- dead after O-proj  (part of p0)
//   [ 8,16)  Wtfc   bf16 [4096][1024]
//   [16,24)  Wtproj bf16 [1024][4096]
//   [24,32)  zn / ctx   bf16            -- dead after O-proj; partial1 (bf16)
//   [32,40)  Q / h      bf16
//   [40,48)  K          bf16
//   [48,56)  Vt         bf16 [32][64][2048]  (V transposed, kv-permuted)
//   [40,72)  ffn1       bf16 [4096][4096]  (overlaps K,Vt — dead after attn)
// QKV: 2-phase 128x96, grid 32x32 = 1024 blocks = exactly 2 full residency
// waves at 2 blocks/CU (56KB LDS) -- fixes the 1.5-wave tail of 128x128.
// fc: 8-phase 256^2 + 2D XCD regions. proj: split-K=2 bf16 partials + reduce.
// attn: 8-wave KVBLK=128, FULL fast path, fully-deferred softmax reduces.
// ---------------------------------------------------------------------------

typedef __bf16 bf16x8 __attribute__((ext_vector_type(8)));
typedef float  f32x4  __attribute__((ext_vector_type(4)));

#define MFMA_16x16x32_BF16(A, B, C) __builtin_amdgcn_mfma_f32_16x16x32_bf16((A), (B), (C), 0, 0, 0)

#define GLDS16(g, l) __builtin_amdgcn_global_load_lds( \
    (const __attribute__((address_space(1))) void*)(g), \
    (__attribute__((address_space(3))) void*)(l), 16, 0, 0)

// ---------------- fused head: 6 weight transposes + rmsnorm(z,g1) -----------
__global__ __launch_bounds__(256) void fused_head_kernel(
    const float* __restrict__ W_Q, const float* __restrict__ W_K,
    const float* __restrict__ W_V, const float* __restrict__ W_O,
    const float* __restrict__ W_fc, const float* __restrict__ W_proj,
    __bf16* __restrict__ WtQKV, __bf16* __restrict__ WtO,
    __bf16* __restrict__ Wtfc, __bf16* __restrict__ Wtproj,
    const float* __restrict__ z, const float* __restrict__ g1,
    __bf16* __restrict__ zn)
{
    const int id = blockIdx.x;
    if (id >= 12288) {
        const int row = id - 12288, t = threadIdx.x;
        const float4 v = ((const float4*)(z + (size_t)row * 1024))[t];
        float ss = v.x * v.x + v.y * v.y + v.z * v.z + v.w * v.w;
#pragma unroll
        for (int m = 1; m < 64; m <<= 1) ss += __shfl_xor(ss, m);
        __shared__ float red[4];
        const int wid = t >> 6, lane = t & 63;
        if (lane == 0) red[wid] = ss;
        __syncthreads();
        const float tot = red[0] + red[1] + red[2] + red[3];
        const float inv = rsqrtf(tot * (1.0f / 1024.0f) + 1e-5f);
        const float4 gv = ((const float4*)g1)[t];
        __bf16* o = zn + (size_t)row * 1024 + t * 4;
        o[0] = (__bf16)(v.x * inv * gv.x);
        o[1] = (__bf16)(v.y * inv * gv.y);
        o[2] = (__bf16)(v.z * inv * gv.z);
        o[3] = (__bf16)(v.w * inv * gv.w);
        return;
    }
    const float* src;
    __bf16* dst;
    int K, N, nx, t;
    if (id < 4096) {
        const int wsel = id >> 10;
        t = id & 1023;
        src = (wsel == 0) ? W_Q : (wsel == 1) ? W_K : (wsel == 2) ? W_V : W_O;
        dst = (wsel < 3) ? (WtQKV + (size_t)wsel * 1048576) : WtO;
        K = 1024; N = 1024; nx = 32;
    } else if (id < 8192) {
        t = id - 4096; src = W_fc; dst = Wtfc; K = 1024; N = 4096; nx = 128;
    } else {
        t = id - 8192; src = W_proj; dst = Wtproj; K = 4096; N = 1024; nx = 32;
    }
    const int n0 = (t % nx) * 32, k0 = (t / nx) * 32;

    __shared__ float tile[32][33];
    const int c = threadIdx.x & 31, r = threadIdx.x >> 5;
#pragma unroll
    for (int i = 0; i < 4; ++i)
        tile[r + 8 * i][c] = src[(size_t)(k0 + r + 8 * i) * N + n0 + c];
    __syncthreads();
#pragma unroll
    for (int i = 0; i < 4; ++i)
        dst[(size_t)(n0 + r + 8 * i) * K + k0 + c] = (__bf16)tile[c][r + 8 * i];
}

// ---------------- RMSNorm: fp32 [M][1024] -> bf16 [M][1024] -----------------
__global__ __launch_bounds__(256) void rmsnorm_kernel(
    const float* __restrict__ x, const float* __restrict__ gain,
    __bf16* __restrict__ out)
{
    const int row = blockIdx.x, t = threadIdx.x;
    const float4 v = ((const float4*)(x + (size_t)row * 1024))[t];
    float ss = v.x * v.x + v.y * v.y + v.z * v.z + v.w * v.w;
#pragma unroll
    for (int m = 1; m < 64; m <<= 1) ss += __shfl_xor(ss, m);
    __shared__ float red[4];
    const int wid = t >> 6, lane = t & 63;
    if (lane == 0) red[wid] = ss;
    __syncthreads();
    const float tot = red[0] + red[1] + red[2] + red[3];
    const float inv = rsqrtf(tot * (1.0f / 1024.0f) + 1e-5f);
    const float4 gv = ((const float4*)gain)[t];
    __bf16* o = out + (size_t)row * 1024 + t * 4;
    o[0] = (__bf16)(v.x * inv * gv.x);
    o[1] = (__bf16)(v.y * inv * gv.y);
    o[2] = (__bf16)(v.z * inv * gv.z);
    o[3] = (__bf16)(v.w * inv * gv.w);
}

// ---------------- reduce: out += p0 + p1 (bf16 partials, 8/thread) ----------
__global__ __launch_bounds__(256) void reduce_add_kernel(
    float* __restrict__ out, const __bf16* __restrict__ p0,
    const __bf16* __restrict__ p1, int n8)
{
    for (int i = blockIdx.x * 256 + threadIdx.x; i < n8; i += gridDim.x * 256) {
        const bf16x8 a = ((const bf16x8*)p0)[i];
        const bf16x8 b = ((const bf16x8*)p1)[i];
        float4 o0 = ((float4*)out)[2 * i];
        float4 o1 = ((float4*)out)[2 * i + 1];
        o0.x += (float)a[0] + (float)b[0]; o0.y += (float)a[1] + (float)b[1];
        o0.z += (float)a[2] + (float)b[2]; o0.w += (float)a[3] + (float)b[3];
        o1.x += (float)a[4] + (float)b[4]; o1.y += (float)a[5] + (float)b[5];
        o1.z += (float)a[6] + (float)b[6]; o1.w += (float)a[7] + (float)b[7];
        ((float4*)out)[2 * i] = o0;
        ((float4*)out)[2 * i + 1] = o1;
    }
}

// ---------------- C-write helper --------------------------------------------
template <int EPI>
__device__ __forceinline__ void epi_write(
    void* outp, const float* res, int N, int rowg, int colg, float v)
{
    if constexpr (EPI == 1) {
        const size_t idx = (size_t)rowg * N + colg;
        ((float*)outp)[idx] = res[idx] + v;
    } else if constexpr (EPI == 2) {
        // gelu, tanh form via exp2 (|diff vs erf-gelu| <~1e-3, << bf16 eps here)
        const size_t idx = (size_t)rowg * N + colg;
        const float u = v * (1.0f + 0.044715f * v * v) * 2.3022585093f;
        const float r = __builtin_amdgcn_rcpf(1.0f + exp2f(u));
        ((__bf16*)outp)[idx] = (__bf16)(v - v * r);
    } else {  // EPI == 4: QKV split
        __bf16* base = (__bf16*)outp;
        const int seg = colg >> 10;       // 0=Q, 1=K, 2=V
        const int cg = colg & 1023;
        if (seg < 2) {
            base[(size_t)seg * 4194304 + (size_t)rowg * 1024 + cg] = (__bf16)v;
        } else {
            // Vt[b][h][d][t'] with within-32 t-permutation: 16h+4g+j -> 8g+4h+j
            const int tt = rowg & 2047;
            const int r32 = tt & 31;
            const int p = ((r32 & 12) << 1) | ((r32 >> 2) & 4) | (r32 & 3);
            base[8388608 +
                 ((size_t)((rowg >> 11) * 16 + (cg >> 6)) * 64 + (cg & 63)) * 2048 +
                 ((tt & ~31) | p)] = (__bf16)v;
        }
    }
}

// ---------------- 8-phase 256x256 GEMM (m201 template) ----------------------
// 2D XCD regions for the fc geometry (16x16 grid): 4m x 8n region per XCD.
template <int EPI>
__global__ __launch_bounds__(512, 2) void gemm256(
    const __bf16* __restrict__ A, const __bf16* __restrict__ Bt,
    void* __restrict__ outp, const float* __restrict__ res,
    int M, int N, int K)
{
    __shared__ __bf16 As[2][2][128 * 64];   // [dbuf][half][row*64+elem]
    __shared__ __bf16 Bs[2][2][128 * 64];
    const int tid = threadIdx.x;

    const int gx = gridDim.x, nwg = gx * gridDim.y;
    int bid = blockIdx.y * gx + blockIdx.x;
    int m0, n0;
    if (gx == 16 && gridDim.y == 16) {
        const int xcd = bid & 7, c = bid >> 3;   // c in [0,32)
        const int rm = xcd >> 1, rn = xcd & 1;   // 4 x 2 regions
        m0 = (rm * 4 + (c >> 3)) * 256;
        n0 = (rn * 8 + (c & 7)) * 256;
    } else {
        if ((nwg & 7) == 0) bid = (bid & 7) * (nwg >> 3) + (bid >> 3);
        m0 = (bid / gx) * 256; n0 = (bid % gx) * 256;
    }

    const int lane = tid & 63, w = tid >> 6;         // 8 waves
    const int wr = w >> 2, wc = w & 3;               // 2 x 4 wave grid
    const int lr = lane & 15, g = lane >> 4;
    const int srow8 = lane >> 3, schunk = (lane & 7) ^ srow8;
    const int xk = lr & 7;
    const int wch = wc >> 1, bro = (wc & 1) * 64;    // B half / row offset

    const __bf16* Ab = A + (size_t)m0 * K;
    const __bf16* Bb = Bt + (size_t)n0 * K;

    auto STG = [&](const __bf16* gb, __bf16* lds, int kt, int half) {
        const __bf16* src = gb + (size_t)(half * 128) * K + (kt << 6);
#pragma unroll
        for (int j = 0; j < 2; ++j) {
            const int sidx = j * 8 + w;
            GLDS16(src + (size_t)(sidx * 8 + srow8) * K + schunk * 8, lds + sidx * 512);
        }
    };

    f32x4 acc[8][4] = {};
    bf16x8 af[2][4], bf[2][4];

#define LAF(BUF, QM) do {                                                       \
    _Pragma("unroll") for (int i_ = 0; i_ < 4; ++i_)                            \
    _Pragma("unroll") for (int kk_ = 0; kk_ < 2; ++kk_)                         \
        af[kk_][i_] = *(const bf16x8*)&As[BUF][wr]                              \
            [((QM) * 64 + i_ * 16 + lr) * 64 + (((kk_ * 4 + g) ^ xk) << 3)];    \
    } while (0)

#define LBF(BUF, QN) do {                                                       \
    _Pragma("unroll") for (int i_ = 0; i_ < 2; ++i_)                            \
    _Pragma("unroll") for (int kk_ = 0; kk_ < 2; ++kk_)                         \
        bf[kk_][(QN) * 2 + i_] = *(const bf16x8*)&Bs[BUF][wch]                  \
            [(bro + ((QN) * 2 + i_) * 16 + lr) * 64 + (((kk_ * 4 + g) ^ xk) << 3)]; \
    } while (0)

#define MMQ(QM, QN) do {                                                        \
    __builtin_amdgcn_s_setprio(1);                                              \
    _Pragma("unroll") for (int kk_ = 0; kk_ < 2; ++kk_)                         \
    _Pragma("unroll") for (int i_ = 0; i_ < 4; ++i_)                            \
    _Pragma("unroll") for (int n_ = 0; n_ < 2; ++n_)                            \
        acc[(QM) * 4 + i_][(QN) * 2 + n_] = MFMA_16x16x32_BF16(                 \
            af[kk_][i_], bf[kk_][(QN) * 2 + n_], acc[(QM) * 4 + i_][(QN) * 2 + n_]); \
    __builtin_amdgcn_s_setprio(0);                                              \
    } while (0)

#define BAR()  __builtin_amdgcn_s_barrier()
#define VMC(N_) asm volatile("s_waitcnt vmcnt(" #N_ ")" ::: "memory")
#define SGB0() __builtin_amdgcn_sched_barrier(0)

    const int nt = K >> 6, niter = nt >> 1;

    STG(Ab, &As[0][0][0], 0, 0); STG(Ab, &As[0][1][0], 0, 1);
    STG(Bb, &Bs[0][0][0], 0, 0); STG(Bb, &Bs[0][1][0], 0, 1);
    STG(Bb, &Bs[1][0][0], 1, 0); STG(Bb, &Bs[1][1][0], 1, 1);

    for (int i = 0; i < niter - 1; ++i) {
        const int t1 = 2 * i + 1;
        STG(Ab, &As[1][0][0], t1, 0);
        VMC(6); BAR(); SGB0();
        LAF(0, 0); LBF(0, 0); MMQ(0, 0); BAR();
        LBF(0, 1); STG(Ab, &As[1][1][0], t1, 1); BAR(); MMQ(0, 1); BAR();
        LAF(0, 1); STG(Bb, &Bs[0][0][0], t1 + 1, 0); BAR(); MMQ(1, 0); BAR();
        STG(Bb, &Bs[0][1][0], t1 + 1, 1); BAR(); MMQ(1, 1); BAR();
        STG(Ab, &As[0][0][0], t1 + 1, 0);
        VMC(6); BAR(); SGB0();
        LAF(1, 0); LBF(1, 0); MMQ(0, 0); BAR();
        LBF(1, 1); STG(Ab, &As[0][1][0], t1 + 1, 1); BAR(); MMQ(0, 1); BAR();
        LAF(1, 1); STG(Bb, &Bs[1][0][0], t1 + 2, 0); BAR(); MMQ(1, 0); BAR();
        STG(Bb, &Bs[1][1][0], t1 + 2, 1); BAR(); MMQ(1, 1); BAR();
    }
    {   // peeled last iteration
        STG(Ab, &As[1][0][0], nt - 1, 0);
        VMC(6); BAR(); SGB0();
        LAF(0, 0); LBF(0, 0); MMQ(0, 0); BAR();
        LBF(0, 1); STG(Ab, &As[1][1][0], nt - 1, 1); BAR(); MMQ(0, 1); BAR();
        LAF(0, 1); BAR(); MMQ(1, 0); BAR();
        BAR(); MMQ(1, 1); BAR();
        VMC(0); BAR(); SGB0();
        LAF(1, 0); LBF(1, 0); MMQ(0, 0); BAR();
        LBF(1, 1); BAR(); MMQ(0, 1); BAR();
        LAF(1, 1); BAR(); MMQ(1, 0); BAR();
        BAR(); MMQ(1, 1); BAR();
    }
#undef LAF
#undef LBF
#undef MMQ
#undef BAR
#undef VMC
#undef SGB0

#pragma unroll
    for (int mi = 0; mi < 8; ++mi)
#pragma unroll
        for (int ni = 0; ni < 4; ++ni) {
            const int colg = n0 + wc * 64 + ni * 16 + lr;
#pragma unroll
            for (int r = 0; r < 4; ++r) {
                const int rowg = m0 + wr * 128 + mi * 16 + 4 * g + r;
                epi_write<EPI>(outp, res, N, rowg, colg, acc[mi][ni][r]);
            }
        }
}

// ---------------- 2-phase 128xBN dbuf GEMM (split-K capable) ----------------
// EPI 5: store bf16 partial (part 0 -> outp, part 1 -> res cast).
// EPI 4 (QKV, 32x32 grid of 128x96): 2D XCD regions, 8m x 16n per XCD.
template <int BM, int BN, int EPI>
__global__ __launch_bounds__(256) void gemm_bf16(
    const __bf16* __restrict__ A, const __bf16* __restrict__ Bt,
    void* __restrict__ outp, const float* __restrict__ res,
    int M, int N, int K, int Kld)
{
    __shared__ __bf16 As[2][BM * 64];
    __shared__ __bf16 Bs[2][BN * 64];
    const int tid = threadIdx.x;

    const int gx = gridDim.x, nwg = gx * gridDim.y;
    int bid = blockIdx.y * gx + blockIdx.x;
    int m0, n0;
    if constexpr (EPI == 4) {
        // gx = 32, gy = 32: 2D regions of 8m x 16n per XCD
        const int xcd = bid & 7, c = bid >> 3;   // c in [0,128)
        const int rm = xcd >> 1, rn = xcd & 1;   // 4 x 2 regions
        m0 = (rm * 8 + (c >> 4)) * BM;
        n0 = (rn * 16 + (c & 15)) * BN;
    } else {
        if ((nwg & 7) == 0) bid = (bid & 7) * (nwg >> 3) + (bid >> 3);
        m0 = (bid / gx) * BM; n0 = (bid % gx) * BN;
    }

    const int lane = tid & 63, w = tid >> 6;
    const int wm = w >> 1, wn = w & 1;
    const int lr = lane & 15, g = lane >> 4;
    const int srow = lane >> 3;
    const int scol = ((lane & 7) ^ srow) * 8;
    const int xr8 = lr & 7;

    constexpr int MI = BM / 32, NI = BN / 32;
    f32x4 acc[MI][NI] = {};

    const __bf16* Abase = A + (size_t)m0 * Kld + blockIdx.z * K;
    const __bf16* Bbase = Bt + (size_t)n0 * Kld + blockIdx.z * K;

    auto STAGE = [&](int kb, int buf) {
#pragma unroll
        for (int j = 0; j < BM / 32; ++j) {
            const int s = j * 4 + w;
            GLDS16(Abase + (size_t)(s * 8 + srow) * Kld + kb + scol, &As[buf][s * 512]);
        }
#pragma unroll
        for (int j = 0; j < BN / 32; ++j) {
            const int s = j * 4 + w;
            GLDS16(Bbase + (size_t)(s * 8 + srow) * Kld + kb + scol, &Bs[buf][s * 512]);
        }
    };

    const int nt = K >> 6;
    STAGE(0, 0);
    __syncthreads();

    for (int t = 0; t < nt; ++t) {
        const int cur = t & 1;
        if (t + 1 < nt) STAGE((t + 1) << 6, cur ^ 1);

        bf16x8 af[2][MI], bfr[2][NI];
#pragma unroll
        for (int kk = 0; kk < 2; ++kk) {
#pragma unroll
            for (int i = 0; i < MI; ++i)
                af[kk][i] = *(const bf16x8*)
                    &As[cur][(wm * (BM / 2) + i * 16 + lr) * 64 + (((kk * 4 + g) ^ xr8) << 3)];
#pragma unroll
            for (int i = 0; i < NI; ++i)
                bfr[kk][i] = *(const bf16x8*)
                    &Bs[cur][(wn * (BN / 2) + i * 16 + lr) * 64 + (((kk * 4 + g) ^ xr8) << 3)];
        }
#pragma unroll
        for (int kk = 0; kk < 2; ++kk)
#pragma unroll
            for (int mi = 0; mi < MI; ++mi)
#pragma unroll
                for (int ni = 0; ni < NI; ++ni)
                    acc[mi][ni] = MFMA_16x16x32_BF16(af[kk][mi], bfr[kk][ni], acc[mi][ni]);
        if (t + 1 < nt) __syncthreads();
    }

#pragma unroll
    for (int mi = 0; mi < MI; ++mi)
#pragma unroll
        for (int ni = 0; ni < NI; ++ni) {
            const int colg = n0 + wn * (BN / 2) + ni * 16 + lr;
#pragma unroll
            for (int r = 0; r < 4; ++r) {
                const int rowg = m0 + wm * (BM / 2) + mi * 16 + 4 * g + r;
                const float v = acc[mi][ni][r];
                if constexpr (EPI == 5) {
                    __bf16* pout = (blockIdx.z == 0) ? (__bf16*)outp
                                                     : (__bf16*)(void*)res;
                    pout[(size_t)rowg * N + colg] = (__bf16)v;
                } else {
                    epi_write<EPI>(outp, res, N, rowg, colg, v);
                }
            }
        }
}

// ---------------- Flash-style causal attention (8-wave, KVBLK=128) ----------
// Grid: 512 blocks = j*32 + bh, j in [0,16). qc = j<8 ? j : 23-j (balanced).
// Block-uniform FULL fast path for t<qc; fully-deferred softmax reductions.
__global__ __launch_bounds__(512) void attn_kernel(
    const __bf16* __restrict__ Q, const __bf16* __restrict__ Kb,
    const __bf16* __restrict__ Vt, __bf16* __restrict__ ctx)
{
    const int Dm = 1024, T = 2048;
    const int tid = threadIdx.x;
    const int w = tid >> 6, lane = tid & 63;
    const int lr = lane & 15, g = lane >> 4;
    const int bx = blockIdx.x;
    const int j = bx >> 5, bh = bx & 31, b = bh >> 4, h = bh & 15;
    const int qc = (j < 8) ? j : 23 - j;            // balanced bijection 0..15
    const int qbase = qc * 128 + w * 16;
    const size_t rowoff = (size_t)b * T;
    const __bf16* Qp = Q + rowoff * Dm + h * 64;
    const __bf16* Kp = Kb + rowoff * Dm + h * 64;
    const __bf16* Vtp = Vt + (size_t)bh * 64 * 2048;

    __shared__ __bf16 Ks[2][128 * 64];
    __shared__ __bf16 Vs[2][64 * 128];

    bf16x8 qf0 = *(const bf16x8*)&Qp[(size_t)(qbase + lr) * Dm + g * 8];
    bf16x8 qf1 = *(const bf16x8*)&Qp[(size_t)(qbase + lr) * Dm + 32 + g * 8];
    const float qsc = 0.125f * 1.44269504088896340736f;
#pragma unroll
    for (int jj = 0; jj < 8; ++jj) {
        qf0[jj] = (__bf16)((float)qf0[jj] * qsc);
        qf1[jj] = (__bf16)((float)qf1[jj] * qsc);
    }

    const int ksrow = lane >> 3;
    const int kschunk = (lane & 7) ^ ksrow;
    const int vsrow = lane >> 4;                    // 0..3

    f32x4 acc[4] = {};
    float m_s = -__builtin_inff(), lpart = 0.0f;    // lane-local partial sum
    const int nsteps = qc + 1;
    const f32x4 zacc = {0.0f, 0.0f, 0.0f, 0.0f};
    const int x8 = lr & 7;                          // K read chunk XOR
    const int qg = qbase + lr;

    auto STAGE = [&](int kvb, int buf) {
#pragma unroll
        for (int jj = 0; jj < 2; ++jj) {
            const int krow = w * 16 + jj * 8;
            GLDS16(Kp + (size_t)(kvb + krow + ksrow) * Dm + kschunk * 8,
                   &Ks[buf][krow * 64]);
            const int vrow = w * 8 + jj * 4;
            const int vchunk = (lane & 15) ^ ((vrow + vsrow) & 15);
            GLDS16(Vtp + (size_t)(vrow + vsrow) * T + kvb + vchunk * 8,
                   &Vs[buf][vrow * 128]);
        }
    };

    STAGE(0, 0);
    __syncthreads();

    for (int t = 0; t < nsteps; ++t) {
        const int kvb = t * 128, cur = t & 1;
        if (t + 1 < nsteps) STAGE(kvb + 128, cur ^ 1);

        float sv[8][4];
        if (t < qc) {
            // ---- FULL fast path: whole 128-kv tile live, no mask logic ----
#pragma unroll
            for (int s4 = 0; s4 < 8; ++s4) {
                const int row = s4 * 16 + lr;
                const bf16x8 kfa = *(const bf16x8*)&Ks[cur][row * 64 + ((g ^ x8) << 3)];
                const bf16x8 kfb = *(const bf16x8*)&Ks[cur][row * 64 + (((4 + g) ^ x8) << 3)];
                f32x4 st = MFMA_16x16x32_BF16(kfa, qf0, zacc);
                st = MFMA_16x16x32_BF16(kfb, qf1, st);
#pragma unroll
                for (int r = 0; r < 4; ++r) sv[s4][r] = st[r];
            }
        } else {
            // ---- diagonal step: per-subtile guards + causal mask ----
#pragma unroll
            for (int s4 = 0; s4 < 8; ++s4) {
                const int kv0 = kvb + s4 * 16;
                if (kv0 <= qbase + 15) {
                    const int row = s4 * 16 + lr;
                    const bf16x8 kfa = *(const bf16x8*)&Ks[cur][row * 64 + ((g ^ x8) << 3)];
                    const bf16x8 kfb = *(const bf16x8*)&Ks[cur][row * 64 + (((4 + g) ^ x8) << 3)];
                    f32x4 st = MFMA_16x16x32_BF16(kfa, qf0, zacc);
                    st = MFMA_16x16x32_BF16(kfb, qf1, st);
                    const bool domask = (kv0 + 15 > qbase);
#pragma unroll
                    for (int r = 0; r < 4; ++r) {
                        float x = st[r];
                        if (domask && (kv0 + 4 * g + r > qg)) x = -__builtin_inff();
                        sv[s4][r] = x;
                    }
                } else {
#pragma unroll
                    for (int r = 0; r < 4; ++r) sv[s4][r] = -__builtin_inff();
                }
            }
        }

        // ---- deferred online softmax (log2 domain) ----
        float tml = sv[0][0];
#pragma unroll
        for (int s4 = 0; s4 < 8; ++s4)
#pragma unroll
            for (int r = 0; r < 4; ++r) tml = fmaxf(tml, sv[s4][r]);

        if (!__all(tml - m_s <= 11.5f)) {
            float tm = fmaxf(tml, __shfl_xor(tml, 16));
            tm = fmaxf(tm, __shfl_xor(tm, 32));
            const float m_new = fmaxf(m_s, tm);
            const float corr = exp2f(m_s - m_new);
            lpart *= corr;
            float cr[4];
#pragma unroll
            for (int r = 0; r < 4; ++r) cr[r] = __shfl(corr, 4 * g + r);
#pragma unroll
            for (int ct = 0; ct < 4; ++ct) {
                acc[ct][0] *= cr[0]; acc[ct][1] *= cr[1];
                acc[ct][2] *= cr[2]; acc[ct][3] *= cr[3];
            }
            m_s = m_new;
        }

        float rsl = 0.0f;
#pragma unroll
        for (int s4 = 0; s4 < 8; ++s4)
#pragma unroll
            for (int r = 0; r < 4; ++r) {
                sv[s4][r] = exp2f(sv[s4][r] - m_s);
                rsl += sv[s4][r];
            }
        lpart += rsl;

        // ---- PV ----
        bf16x8 pa[4];
#pragma unroll
        for (int s = 0; s < 4; ++s)
#pragma unroll
            for (int r = 0; r < 4; ++r) {
                pa[s][r] = (__bf16)sv[2 * s][r];
                pa[s][4 + r] = (__bf16)sv[2 * s + 1][r];
            }
        if (t < qc) {
#pragma unroll
            for (int ct = 0; ct < 4; ++ct) {
                const __bf16* vrow = &Vs[cur][(ct * 16 + lr) * 128];
#pragma unroll
                for (int s = 0; s < 4; ++s) {
                    const bf16x8 vf = *(const bf16x8*)&vrow[(((s * 4 + g) ^ lr) << 3)];
                    acc[ct] = MFMA_16x16x32_BF16(pa[s], vf, acc[ct]);
                }
            }
        } else {
#pragma unroll
            for (int ct = 0; ct < 4; ++ct) {
                const __bf16* vrow = &Vs[cur][(ct * 16 + lr) * 128];
#pragma unroll
                for (int s = 0; s < 4; ++s) {
                    if (kvb + s * 32 <= qbase + 15) {
                        const bf16x8 vf = *(const bf16x8*)&vrow[(((s * 4 + g) ^ lr) << 3)];
                        acc[ct] = MFMA_16x16x32_BF16(pa[s], vf, acc[ct]);
                    }
                }
            }
        }
        __syncthreads();
    }

    // final row-sum reduce (once)
    lpart += __shfl_xor(lpart, 16);
    lpart += __shfl_xor(lpart, 32);
    const float il = __builtin_amdgcn_rcpf(lpart);
    float dn[4];
#pragma unroll
    for (int r = 0; r < 4; ++r) dn[r] = __shfl(il, 4 * g + r);
#pragma unroll
    for (int ct = 0; ct < 4; ++ct)
#pragma unroll
        for (int r = 0; r < 4; ++r)
            ctx[(rowoff + qbase + 4 * g + r) * Dm + h * 64 + ct * 16 + lr] =
                (__bf16)(acc[ct][r] * dn[r]);
}

// ---------------------------------------------------------------------------
extern "C" void kernel_launch(void* const* d_in, const int* in_sizes, int n_in,
                              void* d_out, int out_size, void* d_ws, size_t ws_size,
                              hipStream_t stream)
{
    (void)in_sizes; (void)n_in; (void)out_size; (void)ws_size;
    const float* z      = (const float*)d_in[0];
    const float* W_Q    = (const float*)d_in[1];
    const float* W_K    = (const float*)d_in[2];
    const float* W_V    = (const float*)d_in[3];
    const float* W_O    = (const float*)d_in[4];
    const float* W_fc   = (const float*)d_in[5];
    const float* W_proj = (const float*)d_in[6];
    const float* g1     = (const float*)d_in[7];
    const float* g2     = (const float*)d_in[8];
    float* out = (float*)d_out;

    char* ws = (char*)d_ws;
    const size_t MB = (size_t)1 << 20;
    __bf16* WtQKV  = (__bf16*)(ws + 0 * MB);   // [3072][1024]
    __bf16* WtO    = (__bf16*)(ws + 6 * MB);
    __bf16* Wtfc   = (__bf16*)(ws + 8 * MB);
    __bf16* Wtproj = (__bf16*)(ws + 16 * MB);
    __bf16* zn     = (__bf16*)(ws + 24 * MB);  // reused as ctx
    __bf16* Qb     = (__bf16*)(ws + 32 * MB);  // QKV out base; reused as h
    __bf16* Kbuf   = (__bf16*)(ws + 40 * MB);
    __bf16* Vtb    = (__bf16*)(ws + 48 * MB);
    __bf16* ffn1   = (__bf16*)(ws + 40 * MB);  // overlaps K,Vt (dead post-attn)
    __bf16* part0  = (__bf16*)(ws + 0 * MB);   // 8MB bf16: dead WtQKV/WtO
    __bf16* part1  = (__bf16*)(ws + 24 * MB);  // 8MB bf16: dead zn/ctx
    __bf16* ctx    = zn;
    __bf16* hb     = Qb;

    const int Tt = 2048, Dm = 1024, Bb = 2, M = Bb * Tt, DFF = 4096;
    const dim3 blk256(256), blk512(512);

    // fused: weight transposes + rmsnorm(z, g1) -> zn
    fused_head_kernel<<<16384, blk256, 0, stream>>>(
        W_Q, W_K, W_V, W_O, W_fc, W_proj, WtQKV, WtO, Wtfc, Wtproj, z, g1, zn);

    // Fused QKV (2-phase 128x96, 1024 blocks = exactly 2 residency waves)
    gemm_bf16<128, 96, 4><<<dim3(32, 32), blk256, 0, stream>>>(
        zn, WtQKV, Qb, nullptr, M, 3072, Dm, Dm);

    // attention -> ctx (8-wave blocks, KVBLK=128, deferred softmax reduces)
    attn_kernel<<<512, blk512, 0, stream>>>(Qb, Kbuf, Vtb, ctx);

    // z2 = z + ctx @ W_O  -> d_out (fp32)
    gemm_bf16<128, 64, 1><<<dim3(16, 32), blk256, 0, stream>>>(
        ctx, WtO, out, z, M, Dm, Dm, Dm);

    // h = rmsnorm(z2, g2)
    rmsnorm_kernel<<<M, blk256, 0, stream>>>(out, g2, hb);

    // ffn1 = gelu(h @ W_fc) (8-phase 256^2, 2D XCD regions)
    gemm256<2><<<dim3(16, 16), blk512, 0, stream>>>(
        hb, Wtfc, ffn1, nullptr, M, DFF, Dm);

    // proj split-K=2 (128x128, 512 blocks): bf16 partials p0/p1
    gemm_bf16<128, 128, 5><<<dim3(8, 32, 2), blk256, 0, stream>>>(
        ffn1, Wtproj, part0, (const float*)part1, M, Dm, DFF / 2, DFF);

    // d_out += p0 + p1  (bf16 partials, 8 elems/thread)
    reduce_add_kernel<<<2048, blk256, 0, stream>>>(out, part0, part1, M * Dm / 8);
}

// Round 16
// 224.013 us; speedup vs baseline: 1.4099x; 1.0393x over previous
//
#include <hip/hip_runtime.h>
#include <hip/hip_bf16.h>
#include <math.h>

// ---------------------------------------------------------------------------
// GPT block on MI355X (gfx950). bf16 MFMA compute, fp32 accumulate.
// Workspace layout (MB = 1<<20), total 72 MB:
//   [ 0, 6)  WtQKV  bf16 [3072][1024]   -- dead after QKV; partial0 (bf16 8MB)
//   [ 6, 8)  WtO    bf16 [1024][1024]
//   [ 8,16)  Wtfc   bf16 [4096][1024]
//   [16,24)  Wtproj bf16 [1024][4096]
//   [24,32)  zn / ctx   bf16            -- dead after O-proj; partial1 (bf16)
//   [32,40)  Q / h      bf16
//   [40,48)  K          bf16
//   [48,56)  Vt         bf16 [32][64][2048]  (V transposed, kv-permuted)
//   [40,72)  ffn1       bf16 [4096][4096]  (overlaps K,Vt — dead after attn)
// QKV: 2-phase 128x96; V epilogue now goes through an LDS transpose tile so
// Vt stores are coalesced bf16x8 (was 2B scatters -- the r13-r15 QKV wall).
// fc: 8-phase 256^2 + 2D XCD regions. proj: split-K=2 bf16 partials + reduce.
// attn: 8-wave KVBLK=128, FULL fast path, fully-deferred softmax reduces.
// ---------------------------------------------------------------------------

typedef __bf16 bf16x8 __attribute__((ext_vector_type(8)));
typedef float  f32x4  __attribute__((ext_vector_type(4)));

#define MFMA_16x16x32_BF16(A, B, C) __builtin_amdgcn_mfma_f32_16x16x32_bf16((A), (B), (C), 0, 0, 0)

#define GLDS16(g, l) __builtin_amdgcn_global_load_lds( \
    (const __attribute__((address_space(1))) void*)(g), \
    (__attribute__((address_space(3))) void*)(l), 16, 0, 0)

// ---------------- fused head: 6 weight transposes + rmsnorm(z,g1) -----------
__global__ __launch_bounds__(256) void fused_head_kernel(
    const float* __restrict__ W_Q, const float* __restrict__ W_K,
    const float* __restrict__ W_V, const float* __restrict__ W_O,
    const float* __restrict__ W_fc, const float* __restrict__ W_proj,
    __bf16* __restrict__ WtQKV, __bf16* __restrict__ WtO,
    __bf16* __restrict__ Wtfc, __bf16* __restrict__ Wtproj,
    const float* __restrict__ z, const float* __restrict__ g1,
    __bf16* __restrict__ zn)
{
    const int id = blockIdx.x;
    if (id >= 12288) {
        const int row = id - 12288, t = threadIdx.x;
        const float4 v = ((const float4*)(z + (size_t)row * 1024))[t];
        float ss = v.x * v.x + v.y * v.y + v.z * v.z + v.w * v.w;
#pragma unroll
        for (int m = 1; m < 64; m <<= 1) ss += __shfl_xor(ss, m);
        __shared__ float red[4];
        const int wid = t >> 6, lane = t & 63;
        if (lane == 0) red[wid] = ss;
        __syncthreads();
        const float tot = red[0] + red[1] + red[2] + red[3];
        const float inv = rsqrtf(tot * (1.0f / 1024.0f) + 1e-5f);
        const float4 gv = ((const float4*)g1)[t];
        __bf16* o = zn + (size_t)row * 1024 + t * 4;
        o[0] = (__bf16)(v.x * inv * gv.x);
        o[1] = (__bf16)(v.y * inv * gv.y);
        o[2] = (__bf16)(v.z * inv * gv.z);
        o[3] = (__bf16)(v.w * inv * gv.w);
        return;
    }
    const float* src;
    __bf16* dst;
    int K, N, nx, t;
    if (id < 4096) {
        const int wsel = id >> 10;
        t = id & 1023;
        src = (wsel == 0) ? W_Q : (wsel == 1) ? W_K : (wsel == 2) ? W_V : W_O;
        dst = (wsel < 3) ? (WtQKV + (size_t)wsel * 1048576) : WtO;
        K = 1024; N = 1024; nx = 32;
    } else if (id < 8192) {
        t = id - 4096; src = W_fc; dst = Wtfc; K = 1024; N = 4096; nx = 128;
    } else {
        t = id - 8192; src = W_proj; dst = Wtproj; K = 4096; N = 1024; nx = 32;
    }
    const int n0 = (t % nx) * 32, k0 = (t / nx) * 32;

    __shared__ float tile[32][33];
    const int c = threadIdx.x & 31, r = threadIdx.x >> 5;
#pragma unroll
    for (int i = 0; i < 4; ++i)
        tile[r + 8 * i][c] = src[(size_t)(k0 + r + 8 * i) * N + n0 + c];
    __syncthreads();
#pragma unroll
    for (int i = 0; i < 4; ++i)
        dst[(size_t)(n0 + r + 8 * i) * K + k0 + c] = (__bf16)tile[c][r + 8 * i];
}

// ---------------- RMSNorm: fp32 [M][1024] -> bf16 [M][1024] -----------------
__global__ __launch_bounds__(256) void rmsnorm_kernel(
    const float* __restrict__ x, const float* __restrict__ gain,
    __bf16* __restrict__ out)
{
    const int row = blockIdx.x, t = threadIdx.x;
    const float4 v = ((const float4*)(x + (size_t)row * 1024))[t];
    float ss = v.x * v.x + v.y * v.y + v.z * v.z + v.w * v.w;
#pragma unroll
    for (int m = 1; m < 64; m <<= 1) ss += __shfl_xor(ss, m);
    __shared__ float red[4];
    const int wid = t >> 6, lane = t & 63;
    if (lane == 0) red[wid] = ss;
    __syncthreads();
    const float tot = red[0] + red[1] + red[2] + red[3];
    const float inv = rsqrtf(tot * (1.0f / 1024.0f) + 1e-5f);
    const float4 gv = ((const float4*)gain)[t];
    __bf16* o = out + (size_t)row * 1024 + t * 4;
    o[0] = (__bf16)(v.x * inv * gv.x);
    o[1] = (__bf16)(v.y * inv * gv.y);
    o[2] = (__bf16)(v.z * inv * gv.z);
    o[3] = (__bf16)(v.w * inv * gv.w);
}

// ---------------- reduce: out += p0 + p1 (bf16 partials, 8/thread) ----------
__global__ __launch_bounds__(256) void reduce_add_kernel(
    float* __restrict__ out, const __bf16* __restrict__ p0,
    const __bf16* __restrict__ p1, int n8)
{
    for (int i = blockIdx.x * 256 + threadIdx.x; i < n8; i += gridDim.x * 256) {
        const bf16x8 a = ((const bf16x8*)p0)[i];
        const bf16x8 b = ((const bf16x8*)p1)[i];
        float4 o0 = ((float4*)out)[2 * i];
        float4 o1 = ((float4*)out)[2 * i + 1];
        o0.x += (float)a[0] + (float)b[0]; o0.y += (float)a[1] + (float)b[1];
        o0.z += (float)a[2] + (float)b[2]; o0.w += (float)a[3] + (float)b[3];
        o1.x += (float)a[4] + (float)b[4]; o1.y += (float)a[5] + (float)b[5];
        o1.z += (float)a[6] + (float)b[6]; o1.w += (float)a[7] + (float)b[7];
        ((float4*)out)[2 * i] = o0;
        ((float4*)out)[2 * i + 1] = o1;
    }
}

// ---------------- C-write helper --------------------------------------------
template <int EPI>
__device__ __forceinline__ void epi_write(
    void* outp, const float* res, int N, int rowg, int colg, float v)
{
    if constexpr (EPI == 1) {
        const size_t idx = (size_t)rowg * N + colg;
        ((float*)outp)[idx] = res[idx] + v;
    } else if constexpr (EPI == 2) {
        // gelu, tanh form via exp2 (|diff vs erf-gelu| <~1e-3, << bf16 eps here)
        const size_t idx = (size_t)rowg * N + colg;
        const float u = v * (1.0f + 0.044715f * v * v) * 2.3022585093f;
        const float r = __builtin_amdgcn_rcpf(1.0f + exp2f(u));
        ((__bf16*)outp)[idx] = (__bf16)(v - v * r);
    }
}

// ---------------- 8-phase 256x256 GEMM (m201 template) ----------------------
// 2D XCD regions for the fc geometry (16x16 grid): 4m x 8n region per XCD.
template <int EPI>
__global__ __launch_bounds__(512, 2) void gemm256(
    const __bf16* __restrict__ A, const __bf16* __restrict__ Bt,
    void* __restrict__ outp, const float* __restrict__ res,
    int M, int N, int K)
{
    __shared__ __bf16 As[2][2][128 * 64];   // [dbuf][half][row*64+elem]
    __shared__ __bf16 Bs[2][2][128 * 64];
    const int tid = threadIdx.x;

    const int gx = gridDim.x, nwg = gx * gridDim.y;
    int bid = blockIdx.y * gx + blockIdx.x;
    int m0, n0;
    if (gx == 16 && gridDim.y == 16) {
        const int xcd = bid & 7, c = bid >> 3;   // c in [0,32)
        const int rm = xcd >> 1, rn = xcd & 1;   // 4 x 2 regions
        m0 = (rm * 4 + (c >> 3)) * 256;
        n0 = (rn * 8 + (c & 7)) * 256;
    } else {
        if ((nwg & 7) == 0) bid = (bid & 7) * (nwg >> 3) + (bid >> 3);
        m0 = (bid / gx) * 256; n0 = (bid % gx) * 256;
    }

    const int lane = tid & 63, w = tid >> 6;         // 8 waves
    const int wr = w >> 2, wc = w & 3;               // 2 x 4 wave grid
    const int lr = lane & 15, g = lane >> 4;
    const int srow8 = lane >> 3, schunk = (lane & 7) ^ srow8;
    const int xk = lr & 7;
    const int wch = wc >> 1, bro = (wc & 1) * 64;    // B half / row offset

    const __bf16* Ab = A + (size_t)m0 * K;
    const __bf16* Bb = Bt + (size_t)n0 * K;

    auto STG = [&](const __bf16* gb, __bf16* lds, int kt, int half) {
        const __bf16* src = gb + (size_t)(half * 128) * K + (kt << 6);
#pragma unroll
        for (int j = 0; j < 2; ++j) {
            const int sidx = j * 8 + w;
            GLDS16(src + (size_t)(sidx * 8 + srow8) * K + schunk * 8, lds + sidx * 512);
        }
    };

    f32x4 acc[8][4] = {};
    bf16x8 af[2][4], bf[2][4];

#define LAF(BUF, QM) do {                                                       \
    _Pragma("unroll") for (int i_ = 0; i_ < 4; ++i_)                            \
    _Pragma("unroll") for (int kk_ = 0; kk_ < 2; ++kk_)                         \
        af[kk_][i_] = *(const bf16x8*)&As[BUF][wr]                              \
            [((QM) * 64 + i_ * 16 + lr) * 64 + (((kk_ * 4 + g) ^ xk) << 3)];    \
    } while (0)

#define LBF(BUF, QN) do {                                                       \
    _Pragma("unroll") for (int i_ = 0; i_ < 2; ++i_)                            \
    _Pragma("unroll") for (int kk_ = 0; kk_ < 2; ++kk_)                         \
        bf[kk_][(QN) * 2 + i_] = *(const bf16x8*)&Bs[BUF][wch]                  \
            [(bro + ((QN) * 2 + i_) * 16 + lr) * 64 + (((kk_ * 4 + g) ^ xk) << 3)]; \
    } while (0)

#define MMQ(QM, QN) do {                                                        \
    __builtin_amdgcn_s_setprio(1);                                              \
    _Pragma("unroll") for (int kk_ = 0; kk_ < 2; ++kk_)                         \
    _Pragma("unroll") for (int i_ = 0; i_ < 4; ++i_)                            \
    _Pragma("unroll") for (int n_ = 0; n_ < 2; ++n_)                            \
        acc[(QM) * 4 + i_][(QN) * 2 + n_] = MFMA_16x16x32_BF16(                 \
            af[kk_][i_], bf[kk_][(QN) * 2 + n_], acc[(QM) * 4 + i_][(QN) * 2 + n_]); \
    __builtin_amdgcn_s_setprio(0);                                              \
    } while (0)

#define BAR()  __builtin_amdgcn_s_barrier()
#define VMC(N_) asm volatile("s_waitcnt vmcnt(" #N_ ")" ::: "memory")
#define SGB0() __builtin_amdgcn_sched_barrier(0)

    const int nt = K >> 6, niter = nt >> 1;

    STG(Ab, &As[0][0][0], 0, 0); STG(Ab, &As[0][1][0], 0, 1);
    STG(Bb, &Bs[0][0][0], 0, 0); STG(Bb, &Bs[0][1][0], 0, 1);
    STG(Bb, &Bs[1][0][0], 1, 0); STG(Bb, &Bs[1][1][0], 1, 1);

    for (int i = 0; i < niter - 1; ++i) {
        const int t1 = 2 * i + 1;
        STG(Ab, &As[1][0][0], t1, 0);
        VMC(6); BAR(); SGB0();
        LAF(0, 0); LBF(0, 0); MMQ(0, 0); BAR();
        LBF(0, 1); STG(Ab, &As[1][1][0], t1, 1); BAR(); MMQ(0, 1); BAR();
        LAF(0, 1); STG(Bb, &Bs[0][0][0], t1 + 1, 0); BAR(); MMQ(1, 0); BAR();
        STG(Bb, &Bs[0][1][0], t1 + 1, 1); BAR(); MMQ(1, 1); BAR();
        STG(Ab, &As[0][0][0], t1 + 1, 0);
        VMC(6); BAR(); SGB0();
        LAF(1, 0); LBF(1, 0); MMQ(0, 0); BAR();
        LBF(1, 1); STG(Ab, &As[0][1][0], t1 + 1, 1); BAR(); MMQ(0, 1); BAR();
        LAF(1, 1); STG(Bb, &Bs[1][0][0], t1 + 2, 0); BAR(); MMQ(1, 0); BAR();
        STG(Bb, &Bs[1][1][0], t1 + 2, 1); BAR(); MMQ(1, 1); BAR();
    }
    {   // peeled last iteration
        STG(Ab, &As[1][0][0], nt - 1, 0);
        VMC(6); BAR(); SGB0();
        LAF(0, 0); LBF(0, 0); MMQ(0, 0); BAR();
        LBF(0, 1); STG(Ab, &As[1][1][0], nt - 1, 1); BAR(); MMQ(0, 1); BAR();
        LAF(0, 1); BAR(); MMQ(1, 0); BAR();
        BAR(); MMQ(1, 1); BAR();
        VMC(0); BAR(); SGB0();
        LAF(1, 0); LBF(1, 0); MMQ(0, 0); BAR();
        LBF(1, 1); BAR(); MMQ(0, 1); BAR();
        LAF(1, 1); BAR(); MMQ(1, 0); BAR();
        BAR(); MMQ(1, 1); BAR();
    }
#undef LAF
#undef LBF
#undef MMQ
#undef BAR
#undef VMC
#undef SGB0

#pragma unroll
    for (int mi = 0; mi < 8; ++mi)
#pragma unroll
        for (int ni = 0; ni < 4; ++ni) {
            const int colg = n0 + wc * 64 + ni * 16 + lr;
#pragma unroll
            for (int r = 0; r < 4; ++r) {
                const int rowg = m0 + wr * 128 + mi * 16 + 4 * g + r;
                epi_write<EPI>(outp, res, N, rowg, colg, acc[mi][ni][r]);
            }
        }
}

// ---------------- 2-phase 128xBN dbuf GEMM (split-K capable) ----------------
// EPI 4 (QKV): Q/K written direct (coalesced rows); V staged through a 24KB
//   LDS transpose tile (reusing As) then bulk-stored as coalesced bf16x8.
// EPI 5: store bf16 partial (part 0 -> outp, part 1 -> res cast).
template <int BM, int BN, int EPI>
__global__ __launch_bounds__(256) void gemm_bf16(
    const __bf16* __restrict__ A, const __bf16* __restrict__ Bt,
    void* __restrict__ outp, const float* __restrict__ res,
    int M, int N, int K, int Kld)
{
    __shared__ __bf16 As[2][BM * 64];
    __shared__ __bf16 Bs[2][BN * 64];
    const int tid = threadIdx.x;

    const int gx = gridDim.x, nwg = gx * gridDim.y;
    int bid = blockIdx.y * gx + blockIdx.x;
    int m0, n0;
    if constexpr (EPI == 4) {
        // gx = 32, gy = 32: 2D regions of 8m x 16n per XCD
        const int xcd = bid & 7, c = bid >> 3;   // c in [0,128)
        const int rm = xcd >> 1, rn = xcd & 1;   // 4 x 2 regions
        m0 = (rm * 8 + (c >> 4)) * BM;
        n0 = (rn * 16 + (c & 15)) * BN;
    } else {
        if ((nwg & 7) == 0) bid = (bid & 7) * (nwg >> 3) + (bid >> 3);
        m0 = (bid / gx) * BM; n0 = (bid % gx) * BN;
    }

    const int lane = tid & 63, w = tid >> 6;
    const int wm = w >> 1, wn = w & 1;
    const int lr = lane & 15, g = lane >> 4;
    const int srow = lane >> 3;
    const int scol = ((lane & 7) ^ srow) * 8;
    const int xr8 = lr & 7;

    constexpr int MI = BM / 32, NI = BN / 32;
    f32x4 acc[MI][NI] = {};

    const __bf16* Abase = A + (size_t)m0 * Kld + blockIdx.z * K;
    const __bf16* Bbase = Bt + (size_t)n0 * Kld + blockIdx.z * K;

    auto STAGE = [&](int kb, int buf) {
#pragma unroll
        for (int j = 0; j < BM / 32; ++j) {
            const int s = j * 4 + w;
            GLDS16(Abase + (size_t)(s * 8 + srow) * Kld + kb + scol, &As[buf][s * 512]);
        }
#pragma unroll
        for (int j = 0; j < BN / 32; ++j) {
            const int s = j * 4 + w;
            GLDS16(Bbase + (size_t)(s * 8 + srow) * Kld + kb + scol, &Bs[buf][s * 512]);
        }
    };

    const int nt = K >> 6;
    STAGE(0, 0);
    __syncthreads();

    for (int t = 0; t < nt; ++t) {
        const int cur = t & 1;
        if (t + 1 < nt) STAGE((t + 1) << 6, cur ^ 1);

        bf16x8 af[2][MI], bfr[2][NI];
#pragma unroll
        for (int kk = 0; kk < 2; ++kk) {
#pragma unroll
            for (int i = 0; i < MI; ++i)
                af[kk][i] = *(const bf16x8*)
                    &As[cur][(wm * (BM / 2) + i * 16 + lr) * 64 + (((kk * 4 + g) ^ xr8) << 3)];
#pragma unroll
            for (int i = 0; i < NI; ++i)
                bfr[kk][i] = *(const bf16x8*)
                    &Bs[cur][(wn * (BN / 2) + i * 16 + lr) * 64 + (((kk * 4 + g) ^ xr8) << 3)];
        }
#pragma unroll
        for (int kk = 0; kk < 2; ++kk)
#pragma unroll
            for (int mi = 0; mi < MI; ++mi)
#pragma unroll
                for (int ni = 0; ni < NI; ++ni)
                    acc[mi][ni] = MFMA_16x16x32_BF16(af[kk][mi], bfr[kk][ni], acc[mi][ni]);
        if (t + 1 < nt) __syncthreads();
    }

    if constexpr (EPI == 4) {
        __bf16* vtile = (__bf16*)As;                 // 32KB >= BN*128*2B
        const bool hasV = (n0 + BN > 2048);
        if (hasV) __syncthreads();                   // As free for reuse
#pragma unroll
        for (int mi = 0; mi < MI; ++mi)
#pragma unroll
            for (int ni = 0; ni < NI; ++ni) {
                const int colg = n0 + wn * (BN / 2) + ni * 16 + lr;
#pragma unroll
                for (int r = 0; r < 4; ++r) {
                    const int rowg = m0 + wm * (BM / 2) + mi * 16 + 4 * g + r;
                    const float v = acc[mi][ni][r];
                    if (colg < 2048) {
                        ((__bf16*)outp)[(size_t)(colg >> 10) * 4194304 +
                                        (size_t)rowg * 1024 + (colg & 1023)] = (__bf16)v;
                    } else {
                        // stage into LDS, pre-permuted: trow 16h+4g'+j -> 8g'+4h+j
                        const int trow = rowg - m0;
                        const int r32 = trow & 31;
                        const int p = ((r32 & 12) << 1) | ((r32 >> 2) & 4) | (r32 & 3);
                        vtile[(colg - n0) * 128 + (trow & ~31) + p] = (__bf16)v;
                    }
                }
            }
        if (hasV) {
            __syncthreads();
            const int vstart = (2048 > n0) ? (2048 - n0) : 0;
            const int nvec = (BN - vstart) * 16;     // bf16x8 vectors
            __bf16* base = (__bf16*)outp;
            const size_t vt0 = 8388608 + (size_t)((m0 >> 11) * 16) * 64 * 2048 +
                               (m0 & 2047);
            for (int v = tid; v < nvec; v += 256) {
                const int vc = vstart + (v >> 4);
                const int t8 = (v & 15) << 3;
                const int cg = (n0 + vc) & 1023;
                const size_t idx = vt0 + ((size_t)(cg >> 6) * 64 + (cg & 63)) * 2048 + t8;
                *(bf16x8*)&base[idx] = *(const bf16x8*)&vtile[vc * 128 + t8];
            }
        }
    } else {
#pragma unroll
        for (int mi = 0; mi < MI; ++mi)
#pragma unroll
            for (int ni = 0; ni < NI; ++ni) {
                const int colg = n0 + wn * (BN / 2) + ni * 16 + lr;
#pragma unroll
                for (int r = 0; r < 4; ++r) {
                    const int rowg = m0 + wm * (BM / 2) + mi * 16 + 4 * g + r;
                    const float v = acc[mi][ni][r];
                    if constexpr (EPI == 5) {
                        __bf16* pout = (blockIdx.z == 0) ? (__bf16*)outp
                                                         : (__bf16*)(void*)res;
                        pout[(size_t)rowg * N + colg] = (__bf16)v;
                    } else {
                        epi_write<EPI>(outp, res, N, rowg, colg, v);
                    }
                }
            }
    }
}

// ---------------- Flash-style causal attention (8-wave, KVBLK=128) ----------
// Grid: 512 blocks = j*32 + bh, j in [0,16). qc = j<8 ? j : 23-j (balanced).
// Block-uniform FULL fast path for t<qc; fully-deferred softmax reductions.
__global__ __launch_bounds__(512) void attn_kernel(
    const __bf16* __restrict__ Q, const __bf16* __restrict__ Kb,
    const __bf16* __restrict__ Vt, __bf16* __restrict__ ctx)
{
    const int Dm = 1024, T = 2048;
    const int tid = threadIdx.x;
    const int w = tid >> 6, lane = tid & 63;
    const int lr = lane & 15, g = lane >> 4;
    const int bx = blockIdx.x;
    const int j = bx >> 5, bh = bx & 31, b = bh >> 4, h = bh & 15;
    const int qc = (j < 8) ? j : 23 - j;            // balanced bijection 0..15
    const int qbase = qc * 128 + w * 16;
    const size_t rowoff = (size_t)b * T;
    const __bf16* Qp = Q + rowoff * Dm + h * 64;
    const __bf16* Kp = Kb + rowoff * Dm + h * 64;
    const __bf16* Vtp = Vt + (size_t)bh * 64 * 2048;

    __shared__ __bf16 Ks[2][128 * 64];
    __shared__ __bf16 Vs[2][64 * 128];

    bf16x8 qf0 = *(const bf16x8*)&Qp[(size_t)(qbase + lr) * Dm + g * 8];
    bf16x8 qf1 = *(const bf16x8*)&Qp[(size_t)(qbase + lr) * Dm + 32 + g * 8];
    const float qsc = 0.125f * 1.44269504088896340736f;
#pragma unroll
    for (int jj = 0; jj < 8; ++jj) {
        qf0[jj] = (__bf16)((float)qf0[jj] * qsc);
        qf1[jj] = (__bf16)((float)qf1[jj] * qsc);
    }

    const int ksrow = lane >> 3;
    const int kschunk = (lane & 7) ^ ksrow;
    const int vsrow = lane >> 4;                    // 0..3

    f32x4 acc[4] = {};
    float m_s = -__builtin_inff(), lpart = 0.0f;    // lane-local partial sum
    const int nsteps = qc + 1;
    const f32x4 zacc = {0.0f, 0.0f, 0.0f, 0.0f};
    const int x8 = lr & 7;                          // K read chunk XOR
    const int qg = qbase + lr;

    auto STAGE = [&](int kvb, int buf) {
#pragma unroll
        for (int jj = 0; jj < 2; ++jj) {
            const int krow = w * 16 + jj * 8;
            GLDS16(Kp + (size_t)(kvb + krow + ksrow) * Dm + kschunk * 8,
                   &Ks[buf][krow * 64]);
            const int vrow = w * 8 + jj * 4;
            const int vchunk = (lane & 15) ^ ((vrow + vsrow) & 15);
            GLDS16(Vtp + (size_t)(vrow + vsrow) * T + kvb + vchunk * 8,
                   &Vs[buf][vrow * 128]);
        }
    };

    STAGE(0, 0);
    __syncthreads();

    for (int t = 0; t < nsteps; ++t) {
        const int kvb = t * 128, cur = t & 1;
        if (t + 1 < nsteps) STAGE(kvb + 128, cur ^ 1);

        float sv[8][4];
        if (t < qc) {
            // ---- FULL fast path: whole 128-kv tile live, no mask logic ----
#pragma unroll
            for (int s4 = 0; s4 < 8; ++s4) {
                const int row = s4 * 16 + lr;
                const bf16x8 kfa = *(const bf16x8*)&Ks[cur][row * 64 + ((g ^ x8) << 3)];
                const bf16x8 kfb = *(const bf16x8*)&Ks[cur][row * 64 + (((4 + g) ^ x8) << 3)];
                f32x4 st = MFMA_16x16x32_BF16(kfa, qf0, zacc);
                st = MFMA_16x16x32_BF16(kfb, qf1, st);
#pragma unroll
                for (int r = 0; r < 4; ++r) sv[s4][r] = st[r];
            }
        } else {
            // ---- diagonal step: per-subtile guards + causal mask ----
#pragma unroll
            for (int s4 = 0; s4 < 8; ++s4) {
                const int kv0 = kvb + s4 * 16;
                if (kv0 <= qbase + 15) {
                    const int row = s4 * 16 + lr;
                    const bf16x8 kfa = *(const bf16x8*)&Ks[cur][row * 64 + ((g ^ x8) << 3)];
                    const bf16x8 kfb = *(const bf16x8*)&Ks[cur][row * 64 + (((4 + g) ^ x8) << 3)];
                    f32x4 st = MFMA_16x16x32_BF16(kfa, qf0, zacc);
                    st = MFMA_16x16x32_BF16(kfb, qf1, st);
                    const bool domask = (kv0 + 15 > qbase);
#pragma unroll
                    for (int r = 0; r < 4; ++r) {
                        float x = st[r];
                        if (domask && (kv0 + 4 * g + r > qg)) x = -__builtin_inff();
                        sv[s4][r] = x;
                    }
                } else {
#pragma unroll
                    for (int r = 0; r < 4; ++r) sv[s4][r] = -__builtin_inff();
                }
            }
        }

        // ---- deferred online softmax (log2 domain) ----
        float tml = sv[0][0];
#pragma unroll
        for (int s4 = 0; s4 < 8; ++s4)
#pragma unroll
            for (int r = 0; r < 4; ++r) tml = fmaxf(tml, sv[s4][r]);

        if (!__all(tml - m_s <= 11.5f)) {
            float tm = fmaxf(tml, __shfl_xor(tml, 16));
            tm = fmaxf(tm, __shfl_xor(tm, 32));
            const float m_new = fmaxf(m_s, tm);
            const float corr = exp2f(m_s - m_new);
            lpart *= corr;
            float cr[4];
#pragma unroll
            for (int r = 0; r < 4; ++r) cr[r] = __shfl(corr, 4 * g + r);
#pragma unroll
            for (int ct = 0; ct < 4; ++ct) {
                acc[ct][0] *= cr[0]; acc[ct][1] *= cr[1];
                acc[ct][2] *= cr[2]; acc[ct][3] *= cr[3];
            }
            m_s = m_new;
        }

        float rsl = 0.0f;
#pragma unroll
        for (int s4 = 0; s4 < 8; ++s4)
#pragma unroll
            for (int r = 0; r < 4; ++r) {
                sv[s4][r] = exp2f(sv[s4][r] - m_s);
                rsl += sv[s4][r];
            }
        lpart += rsl;

        // ---- PV ----
        bf16x8 pa[4];
#pragma unroll
        for (int s = 0; s < 4; ++s)
#pragma unroll
            for (int r = 0; r < 4; ++r) {
                pa[s][r] = (__bf16)sv[2 * s][r];
                pa[s][4 + r] = (__bf16)sv[2 * s + 1][r];
            }
        if (t < qc) {
#pragma unroll
            for (int ct = 0; ct < 4; ++ct) {
                const __bf16* vrow = &Vs[cur][(ct * 16 + lr) * 128];
#pragma unroll
                for (int s = 0; s < 4; ++s) {
                    const bf16x8 vf = *(const bf16x8*)&vrow[(((s * 4 + g) ^ lr) << 3)];
                    acc[ct] = MFMA_16x16x32_BF16(pa[s], vf, acc[ct]);
                }
            }
        } else {
#pragma unroll
            for (int ct = 0; ct < 4; ++ct) {
                const __bf16* vrow = &Vs[cur][(ct * 16 + lr) * 128];
#pragma unroll
                for (int s = 0; s < 4; ++s) {
                    if (kvb + s * 32 <= qbase + 15) {
                        const bf16x8 vf = *(const bf16x8*)&vrow[(((s * 4 + g) ^ lr) << 3)];
                        acc[ct] = MFMA_16x16x32_BF16(pa[s], vf, acc[ct]);
                    }
                }
            }
        }
        __syncthreads();
    }

    // final row-sum reduce (once)
    lpart += __shfl_xor(lpart, 16);
    lpart += __shfl_xor(lpart, 32);
    const float il = __builtin_amdgcn_rcpf(lpart);
    float dn[4];
#pragma unroll
    for (int r = 0; r < 4; ++r) dn[r] = __shfl(il, 4 * g + r);
#pragma unroll
    for (int ct = 0; ct < 4; ++ct)
#pragma unroll
        for (int r = 0; r < 4; ++r)
            ctx[(rowoff + qbase + 4 * g + r) * Dm + h * 64 + ct * 16 + lr] =
                (__bf16)(acc[ct][r] * dn[r]);
}

// ---------------------------------------------------------------------------
extern "C" void kernel_launch(void* const* d_in, const int* in_sizes, int n_in,
                              void* d_out, int out_size, void* d_ws, size_t ws_size,
                              hipStream_t stream)
{
    (void)in_sizes; (void)n_in; (void)out_size; (void)ws_size;
    const float* z      = (const float*)d_in[0];
    const float* W_Q    = (const float*)d_in[1];
    const float* W_K    = (const float*)d_in[2];
    const float* W_V    = (const float*)d_in[3];
    const float* W_O    = (const float*)d_in[4];
    const float* W_fc   = (const float*)d_in[5];
    const float* W_proj = (const float*)d_in[6];
    const float* g1     = (const float*)d_in[7];
    const float* g2     = (const float*)d_in[8];
    float* out = (float*)d_out;

    char* ws = (char*)d_ws;
    const size_t MB = (size_t)1 << 20;
    __bf16* WtQKV  = (__bf16*)(ws + 0 * MB);   // [3072][1024]
    __bf16* WtO    = (__bf16*)(ws + 6 * MB);
    __bf16* Wtfc   = (__bf16*)(ws + 8 * MB);
    __bf16* Wtproj = (__bf16*)(ws + 16 * MB);
    __bf16* zn     = (__bf16*)(ws + 24 * MB);  // reused as ctx
    __bf16* Qb     = (__bf16*)(ws + 32 * MB);  // QKV out base; reused as h
    __bf16* Kbuf   = (__bf16*)(ws + 40 * MB);
    __bf16* Vtb    = (__bf16*)(ws + 48 * MB);
    __bf16* ffn1   = (__bf16*)(ws + 40 * MB);  // overlaps K,Vt (dead post-attn)
    __bf16* part0  = (__bf16*)(ws + 0 * MB);   // 8MB bf16: dead WtQKV/WtO
    __bf16* part1  = (__bf16*)(ws + 24 * MB);  // 8MB bf16: dead zn/ctx
    __bf16* ctx    = zn;
    __bf16* hb     = Qb;

    const int Tt = 2048, Dm = 1024, Bb = 2, M = Bb * Tt, DFF = 4096;
    const dim3 blk256(256), blk512(512);

    // fused: weight transposes + rmsnorm(z, g1) -> zn
    fused_head_kernel<<<16384, blk256, 0, stream>>>(
        W_Q, W_K, W_V, W_O, W_fc, W_proj, WtQKV, WtO, Wtfc, Wtproj, z, g1, zn);

    // Fused QKV (2-phase 128x96, 1024 blocks, LDS-transposed V epilogue)
    gemm_bf16<128, 96, 4><<<dim3(32, 32), blk256, 0, stream>>>(
        zn, WtQKV, Qb, nullptr, M, 3072, Dm, Dm);

    // attention -> ctx (8-wave blocks, KVBLK=128, deferred softmax reduces)
    attn_kernel<<<512, blk512, 0, stream>>>(Qb, Kbuf, Vtb, ctx);

    // z2 = z + ctx @ W_O  -> d_out (fp32)
    gemm_bf16<128, 64, 1><<<dim3(16, 32), blk256, 0, stream>>>(
        ctx, WtO, out, z, M, Dm, Dm, Dm);

    // h = rmsnorm(z2, g2)
    rmsnorm_kernel<<<M, blk256, 0, stream>>>(out, g2, hb);

    // ffn1 = gelu(h @ W_fc) (8-phase 256^2, 2D XCD regions)
    gemm256<2><<<dim3(16, 16), blk512, 0, stream>>>(
        hb, Wtfc, ffn1, nullptr, M, DFF, Dm);

    // proj split-K=2 (128x128, 512 blocks): bf16 partials p0/p1
    gemm_bf16<128, 128, 5><<<dim3(8, 32, 2), blk256, 0, stream>>>(
        ffn1, Wtproj, part0, (const float*)part1, M, Dm, DFF / 2, DFF);

    // d_out += p0 + p1  (bf16 partials, 8 elems/thread)
    reduce_add_kernel<<<2048, blk256, 0, stream>>>(out, part0, part1, M * Dm / 8);
}